// Round 3
// baseline (3746.701 us; speedup 1.0000x reference)
//
#include <hip/hip_runtime.h>
#include <math.h>

#define ENC_K 49152
#define KSEG 8
#define KLEN (ENC_K / KSEG)   // 6144

// ---------------- alpha_bar per batch ----------------
__global__ void k_alpha(const int* __restrict__ t, float* __restrict__ sab, float* __restrict__ snab) {
    int b = threadIdx.x;
    if (b < 64) {
        int tb = t[b];
        const float step = (0.02f - 1e-4f) / 999.0f;
        float ab = 1.0f;
        for (int i = 0; i <= tb; ++i) {
            float beta = 1e-4f + step * (float)i;
            ab *= (1.0f - beta);
        }
        sab[b] = sqrtf(ab);
        snab[b] = sqrtf(1.0f - ab);
    }
}

// ---------------- encoder GEMM: x0 = cond @ W^T (K-split partials) ----------------
__global__ void k_enc_gemm(const float* __restrict__ cond, const float* __restrict__ w,
                           float* __restrict__ partial) {
    __shared__ float As[16][65];
    __shared__ float Ws[16][65];
    int tid = threadIdx.x;
    int j = tid & 15, i = tid >> 4;
    int d0 = blockIdx.x * 16, b0 = blockIdx.y * 16;
    int k0 = blockIdx.z * KLEN;
    float acc = 0.f;
    for (int kk = 0; kk < KLEN; kk += 64) {
        for (int idx = tid; idx < 1024; idx += 256) {
            int r = idx >> 6, c = idx & 63;
            As[r][c] = cond[(size_t)(b0 + r) * ENC_K + k0 + kk + c];
            Ws[r][c] = w[(size_t)(d0 + r) * ENC_K + k0 + kk + c];
        }
        __syncthreads();
#pragma unroll
        for (int k = 0; k < 64; ++k)
            acc += As[i][k] * Ws[j][k];
        __syncthreads();
    }
    partial[((size_t)blockIdx.z * 64 + b0 + i) * 128 + d0 + j] = acc;
}

__global__ void k_enc_reduce(const float* __restrict__ partial, const float* __restrict__ bias,
                             float* __restrict__ x0) {
    int idx = blockIdx.x * 256 + threadIdx.x;  // 8192 total
    float s = bias[idx & 127];
    for (int ks = 0; ks < KSEG; ++ks) s += partial[(size_t)ks * 8192 + idx];
    x0[idx] = s;
}

// ---------------- transformer encoder (2 layers, seq_len 1) ----------------
__device__ float block_ln(float y, float* rbuf, int d, float g, float bb) {
    rbuf[d] = y;
    __syncthreads();
    for (int s = 64; s > 0; s >>= 1) { if (d < s) rbuf[d] += rbuf[d + s]; __syncthreads(); }
    float mean = rbuf[0] / 128.f;
    __syncthreads();
    float c = y - mean;
    rbuf[d] = c * c;
    __syncthreads();
    for (int s = 64; s > 0; s >>= 1) { if (d < s) rbuf[d] += rbuf[d + s]; __syncthreads(); }
    float var = rbuf[0] / 128.f;
    __syncthreads();
    return c * rsqrtf(var + 1e-5f) * g + bb;
}

__device__ inline float dot4(const float4 a, const float4 b) {
    return a.x * b.x + a.y * b.y + a.z * b.z + a.w * b.w;
}

__global__ void k_tf(const float* __restrict__ x0, float* __restrict__ xe,
                     const float* __restrict__ in_w, const float* __restrict__ in_b,
                     const float* __restrict__ out_w, const float* __restrict__ out_b,
                     const float* __restrict__ ff1_w, const float* __restrict__ ff1_b,
                     const float* __restrict__ ff2_w, const float* __restrict__ ff2_b,
                     const float* __restrict__ ln1_g, const float* __restrict__ ln1_b,
                     const float* __restrict__ ln2_g, const float* __restrict__ ln2_b) {
    __shared__ float xs[128], vs[128], f1[2048], rbuf[128];
    int b = blockIdx.x, d = threadIdx.x;
    xs[d] = x0[b * 128 + d];
    __syncthreads();
    const float4* xv = (const float4*)xs;
    const float4* vv = (const float4*)vs;
    const float4* fv = (const float4*)f1;
    for (int L = 0; L < 2; ++L) {
        const float* iw = in_w + (size_t)L * 384 * 128 + 256 * 128;
        const float* ibv = in_b + L * 384 + 256;
        float s = ibv[d];
        const float4* wv = (const float4*)(iw + d * 128);
#pragma unroll 8
        for (int k = 0; k < 32; ++k) s += dot4(xv[k], wv[k]);
        vs[d] = s;
        __syncthreads();
        float a = out_b[L * 128 + d];
        const float4* ov = (const float4*)(out_w + (size_t)L * 128 * 128 + d * 128);
#pragma unroll 8
        for (int k = 0; k < 32; ++k) a += dot4(vv[k], ov[k]);
        float y = xs[d] + a;
        y = block_ln(y, rbuf, d, ln1_g[L * 128 + d], ln1_b[L * 128 + d]);
        xs[d] = y;
        __syncthreads();
        for (int j = d; j < 2048; j += 128) {
            float f = ff1_b[L * 2048 + j];
            const float4* w1 = (const float4*)(ff1_w + (size_t)L * 2048 * 128 + (size_t)j * 128);
#pragma unroll 8
            for (int k = 0; k < 32; ++k) f += dot4(xv[k], w1[k]);
            f1[j] = fmaxf(f, 0.f);
        }
        __syncthreads();
        float f2 = ff2_b[L * 128 + d];
        const float4* w2 = (const float4*)(ff2_w + (size_t)L * 128 * 2048 + (size_t)d * 2048);
#pragma unroll 8
        for (int k = 0; k < 512; ++k) f2 += dot4(fv[k], w2[k]);
        float y2 = xs[d] + f2;
        y2 = block_ln(y2, rbuf, d, ln2_g[L * 128 + d], ln2_b[L * 128 + d]);
        xs[d] = y2;
        __syncthreads();
    }
    xe[b * 128 + d] = xs[d];
}

// ---------------- mid projection ----------------
__global__ void k_mid(const float* __restrict__ xe, const float* __restrict__ mid_w,
                      const float* __restrict__ mid_b, float* __restrict__ mid) {
    int b = blockIdx.x, c = threadIdx.x;  // 64 threads
    float s = mid_b[c];
    const float* xr = xe + b * 128;
    const float* wr = mid_w + c * 128;
    for (int k = 0; k < 128; ++k) s += xr[k] * wr[k];
    mid[b * 64 + c] = s;
}

// ---------------- direct 3x3 SAME conv, 32x32 spatial tiles, 4 px/thread ----------------
// MIN: 0 = read `in` (chunk-local); 1 = fused q_sample from tgt/noise (global batch idx)
// MOUT: 0 = bias; 1 = relu; 2 = relu+mid; 3 = bias + fused MSE partial (COUT==3)
template <int CIN, int COUT, int CC, int COT, int MIN, int MOUT>
__global__ __launch_bounds__(256, 4) void k_conv(
    const float* __restrict__ in, const float* __restrict__ tgt,
    const float* __restrict__ noise, const float* __restrict__ sab,
    const float* __restrict__ snab, const float* __restrict__ wgt,
    const float* __restrict__ bias, const float* __restrict__ mid,
    float* __restrict__ out, float* __restrict__ partial, int b0) {
    __shared__ float it[CC][34][34];
    __shared__ float wt[COT][CC][9];
    __shared__ float rs[256];
    int tid = threadIdx.x;
    int tx = tid & 7, ty = tid >> 3;     // tx: group of 4 px, ty: row 0..31
    int bx = blockIdx.x, by = blockIdx.y;
    const int GROUPS = COUT / COT;
    int bl = blockIdx.z / GROUPS;        // chunk-local batch (ws buffers)
    int g = blockIdx.z % GROUPS;
    int bg = b0 + bl;                    // global batch (tgt/noise/sab/mid/mse)
    int co0 = g * COT;

    float acc[COT][4];
#pragma unroll
    for (int co = 0; co < COT; ++co)
#pragma unroll
        for (int p = 0; p < 4; ++p) acc[co][p] = 0.f;
    float za = 0.f, zb = 0.f;
    if (MIN == 1) { za = sab[bg]; zb = snab[bg]; }

    for (int c0 = 0; c0 < CIN; c0 += CC) {
        for (int idx = tid; idx < CC * 34 * 34; idx += 256) {
            int c = idx / (34 * 34), rem = idx % (34 * 34);
            int yy = rem / 34, xx = rem % 34;
            int gy = by * 32 + yy - 1, gx = bx * 32 + xx - 1;
            float v = 0.f;
            if (gy >= 0 && gy < 128 && gx >= 0 && gx < 128) {
                if (MIN == 1) {
                    size_t off = (((size_t)bg * CIN + c0 + c) * 128 + gy) * 128 + gx;
                    v = za * tgt[off] + zb * noise[off];
                } else {
                    size_t off = (((size_t)bl * CIN + c0 + c) * 128 + gy) * 128 + gx;
                    v = in[off];
                }
            }
            it[c][yy][xx] = v;
        }
        for (int idx = tid; idx < COT * CC * 9; idx += 256) {
            int co = idx / (CC * 9), rem = idx % (CC * 9);
            int c = rem / 9, k = rem % 9;
            wt[co][c][k] = wgt[((size_t)(co0 + co) * CIN + c0 + c) * 9 + k];
        }
        __syncthreads();
#pragma unroll 1
        for (int c = 0; c < CC; ++c) {
#pragma unroll
            for (int ky = 0; ky < 3; ++ky) {
                float win[6];
#pragma unroll
                for (int i = 0; i < 6; ++i) win[i] = it[c][ty + ky][tx * 4 + i];
#pragma unroll
                for (int kx = 0; kx < 3; ++kx) {
#pragma unroll
                    for (int co = 0; co < COT; ++co) {
                        float w = wt[co][c][ky * 3 + kx];
#pragma unroll
                        for (int p = 0; p < 4; ++p)
                            acc[co][p] += win[kx + p] * w;
                    }
                }
            }
        }
        __syncthreads();
    }

    int gy = by * 32 + ty;
    int gx0 = bx * 32 + tx * 4;
    if (MOUT == 3) {
        float ss = 0.f;
#pragma unroll
        for (int co = 0; co < COT; ++co) {
#pragma unroll
            for (int p = 0; p < 4; ++p) {
                float v = acc[co][p] + bias[co0 + co];
                size_t off = (((size_t)bg * COUT + co) * 128 + gy) * 128 + gx0 + p;
                float diff = v - noise[off];
                ss += diff * diff;
            }
        }
        rs[tid] = ss;
        __syncthreads();
        for (int s = 128; s > 0; s >>= 1) { if (tid < s) rs[tid] += rs[tid + s]; __syncthreads(); }
        if (tid == 0) partial[(((size_t)bg * GROUPS + g) * 4 + by) * 4 + bx] = rs[0];
    } else {
#pragma unroll
        for (int co = 0; co < COT; ++co) {
            float bsum = bias[co0 + co];
            float4 v4;
            float* vp = (float*)&v4;
#pragma unroll
            for (int p = 0; p < 4; ++p) {
                float v = acc[co][p] + bsum;
                if (MOUT >= 1) v = fmaxf(v, 0.f);
                if (MOUT == 2) v += mid[bg * 64 + co0 + co];
                vp[p] = v;
            }
            *(float4*)&out[(((size_t)bl * COUT + co0 + co) * 128 + gy) * 128 + gx0] = v4;
        }
    }
}

// ---------------- final MSE reduction ----------------
__global__ void k_final(const float* __restrict__ partial, float* __restrict__ out) {
    __shared__ float rs[256];
    int tid = threadIdx.x;
    float s = 0.f;
    for (int i = tid; i < 1024; i += 256) s += partial[i];
    rs[tid] = s;
    __syncthreads();
    for (int st = 128; st > 0; st >>= 1) { if (tid < st) rs[tid] += rs[tid + st]; __syncthreads(); }
    if (tid == 0) out[0] = rs[0] / 3145728.0f;
}

extern "C" void kernel_launch(void* const* d_in, const int* in_sizes, int n_in,
                              void* d_out, int out_size, void* d_ws, size_t ws_size,
                              hipStream_t stream) {
    const float* cond   = (const float*)d_in[0];
    const float* tgt    = (const float*)d_in[1];
    const float* noise  = (const float*)d_in[2];
    const int*   t      = (const int*)d_in[3];
    const float* enc_w  = (const float*)d_in[4];
    const float* enc_b  = (const float*)d_in[5];
    const float* in_w   = (const float*)d_in[6];
    const float* in_b   = (const float*)d_in[7];
    const float* out_w  = (const float*)d_in[8];
    const float* out_b  = (const float*)d_in[9];
    const float* ff1_w  = (const float*)d_in[10];
    const float* ff1_b  = (const float*)d_in[11];
    const float* ff2_w  = (const float*)d_in[12];
    const float* ff2_b  = (const float*)d_in[13];
    const float* ln1_g  = (const float*)d_in[14];
    const float* ln1_b  = (const float*)d_in[15];
    const float* ln2_g  = (const float*)d_in[16];
    const float* ln2_b  = (const float*)d_in[17];
    const float* d1_w   = (const float*)d_in[18];
    const float* d1_b   = (const float*)d_in[19];
    const float* d2_w   = (const float*)d_in[20];
    const float* d2_b   = (const float*)d_in[21];
    const float* mid_w  = (const float*)d_in[22];
    const float* mid_b  = (const float*)d_in[23];
    const float* u1_w   = (const float*)d_in[24];
    const float* u1_b   = (const float*)d_in[25];
    const float* u2_w   = (const float*)d_in[26];
    const float* u2_b   = (const float*)d_in[27];

    float* ws = (float*)d_ws;
    // control region: 131072 floats
    float* sab     = ws;                    // 64
    float* snab    = ws + 64;               // 64
    float* x0      = ws + 128;              // 8192
    float* xe      = ws + 8320;             // 8192
    float* mid     = ws + 16512;            // 4096
    float* encpart = ws + 20608;            // 65536
    float* msepart = ws + 86144;            // 4096

    // ws-adaptive batch chunk: NB images of h1(32ch)+h2(64ch)+h3(32ch) = NB*2097152 floats
    const size_t SMALL = 131072;
    size_t avail = (ws_size / 4 > SMALL) ? (ws_size / 4 - SMALL) : 0;
    int NB = 1;
    const int cands[7] = {64, 32, 16, 8, 4, 2, 1};
    for (int ci = 0; ci < 7; ++ci) {
        if ((size_t)cands[ci] * 2097152ull <= avail) { NB = cands[ci]; break; }
    }
    float* h1 = ws + SMALL;                                  // NB*32*128*128
    float* h2 = h1 + (size_t)NB * 524288ull;                 // NB*64*128*128
    float* h3 = h2 + (size_t)NB * 1048576ull;                // NB*32*128*128

    k_alpha<<<1, 64, 0, stream>>>(t, sab, snab);
    k_enc_gemm<<<dim3(8, 4, KSEG), 256, 0, stream>>>(cond, enc_w, encpart);
    k_enc_reduce<<<32, 256, 0, stream>>>(encpart, enc_b, x0);
    k_tf<<<64, 128, 0, stream>>>(x0, xe, in_w, in_b, out_w, out_b,
                                 ff1_w, ff1_b, ff2_w, ff2_b,
                                 ln1_g, ln1_b, ln2_g, ln2_b);
    k_mid<<<64, 64, 0, stream>>>(xe, mid_w, mid_b, mid);

    for (int cb = 0; cb < 64; cb += NB) {
        // conv1: 3->32, fused q_sample, relu
        k_conv<3, 32, 3, 16, 1, 1><<<dim3(4, 4, NB * 2), 256, 0, stream>>>(
            nullptr, tgt, noise, sab, snab, d1_w, d1_b, nullptr, h1, nullptr, cb);
        // conv2: 32->64, relu + mid add
        k_conv<32, 64, 4, 16, 0, 2><<<dim3(4, 4, NB * 4), 256, 0, stream>>>(
            h1, nullptr, nullptr, nullptr, nullptr, d2_w, d2_b, mid, h2, nullptr, cb);
        // u1: 64->32, relu
        k_conv<64, 32, 4, 16, 0, 1><<<dim3(4, 4, NB * 2), 256, 0, stream>>>(
            h2, nullptr, nullptr, nullptr, nullptr, u1_w, u1_b, nullptr, h3, nullptr, cb);
        // u2: 32->3, fused MSE partials
        k_conv<32, 3, 4, 3, 0, 3><<<dim3(4, 4, NB * 1), 256, 0, stream>>>(
            h3, nullptr, noise, nullptr, nullptr, u2_w, u2_b, nullptr, nullptr, msepart, cb);
    }

    k_final<<<1, 256, 0, stream>>>(msepart, (float*)d_out);
}

// Round 4
// 2255.561 us; speedup vs baseline: 1.6611x; 1.6611x over previous
//
#include <hip/hip_runtime.h>
#include <math.h>

#define ENC_K 49152
#define KSEG 8
#define KLEN (ENC_K / KSEG)   // 6144

// ---------------- alpha_bar per batch ----------------
__global__ void k_alpha(const int* __restrict__ t, float* __restrict__ sab, float* __restrict__ snab) {
    int b = threadIdx.x;
    if (b < 64) {
        int tb = t[b];
        const float step = (0.02f - 1e-4f) / 999.0f;
        float ab = 1.0f;
        for (int i = 0; i <= tb; ++i) {
            float beta = 1e-4f + step * (float)i;
            ab *= (1.0f - beta);
        }
        sab[b] = sqrtf(ab);
        snab[b] = sqrtf(1.0f - ab);
    }
}

// ---------------- encoder GEMM: x0 = cond @ W^T (K-split partials) ----------------
__global__ void k_enc_gemm(const float* __restrict__ cond, const float* __restrict__ w,
                           float* __restrict__ partial) {
    __shared__ float As[16][65];
    __shared__ float Ws[16][65];
    int tid = threadIdx.x;
    int j = tid & 15, i = tid >> 4;
    int d0 = blockIdx.x * 16, b0 = blockIdx.y * 16;
    int k0 = blockIdx.z * KLEN;
    float acc = 0.f;
    for (int kk = 0; kk < KLEN; kk += 64) {
        for (int idx = tid; idx < 1024; idx += 256) {
            int r = idx >> 6, c = idx & 63;
            As[r][c] = cond[(size_t)(b0 + r) * ENC_K + k0 + kk + c];
            Ws[r][c] = w[(size_t)(d0 + r) * ENC_K + k0 + kk + c];
        }
        __syncthreads();
#pragma unroll
        for (int k = 0; k < 64; ++k)
            acc += As[i][k] * Ws[j][k];
        __syncthreads();
    }
    partial[((size_t)blockIdx.z * 64 + b0 + i) * 128 + d0 + j] = acc;
}

__global__ void k_enc_reduce(const float* __restrict__ partial, const float* __restrict__ bias,
                             float* __restrict__ x0) {
    int idx = blockIdx.x * 256 + threadIdx.x;  // 8192 total
    float s = bias[idx & 127];
    for (int ks = 0; ks < KSEG; ++ks) s += partial[(size_t)ks * 8192 + idx];
    x0[idx] = s;
}

// ---------------- transformer encoder (2 layers, seq_len 1) ----------------
__device__ float block_ln(float y, float* rbuf, int d, float g, float bb) {
    rbuf[d] = y;
    __syncthreads();
    for (int s = 64; s > 0; s >>= 1) { if (d < s) rbuf[d] += rbuf[d + s]; __syncthreads(); }
    float mean = rbuf[0] / 128.f;
    __syncthreads();
    float c = y - mean;
    rbuf[d] = c * c;
    __syncthreads();
    for (int s = 64; s > 0; s >>= 1) { if (d < s) rbuf[d] += rbuf[d + s]; __syncthreads(); }
    float var = rbuf[0] / 128.f;
    __syncthreads();
    return c * rsqrtf(var + 1e-5f) * g + bb;
}

__device__ inline float dot4(const float4 a, const float4 b) {
    return a.x * b.x + a.y * b.y + a.z * b.z + a.w * b.w;
}

__global__ void k_tf(const float* __restrict__ x0, float* __restrict__ xe,
                     const float* __restrict__ in_w, const float* __restrict__ in_b,
                     const float* __restrict__ out_w, const float* __restrict__ out_b,
                     const float* __restrict__ ff1_w, const float* __restrict__ ff1_b,
                     const float* __restrict__ ff2_w, const float* __restrict__ ff2_b,
                     const float* __restrict__ ln1_g, const float* __restrict__ ln1_b,
                     const float* __restrict__ ln2_g, const float* __restrict__ ln2_b) {
    __shared__ float xs[128], vs[128], f1[2048], rbuf[128];
    int b = blockIdx.x, d = threadIdx.x;
    xs[d] = x0[b * 128 + d];
    __syncthreads();
    const float4* xv = (const float4*)xs;
    const float4* vv = (const float4*)vs;
    const float4* fv = (const float4*)f1;
    for (int L = 0; L < 2; ++L) {
        const float* iw = in_w + (size_t)L * 384 * 128 + 256 * 128;
        const float* ibv = in_b + L * 384 + 256;
        float s = ibv[d];
        const float4* wv = (const float4*)(iw + d * 128);
#pragma unroll 8
        for (int k = 0; k < 32; ++k) s += dot4(xv[k], wv[k]);
        vs[d] = s;
        __syncthreads();
        float a = out_b[L * 128 + d];
        const float4* ov = (const float4*)(out_w + (size_t)L * 128 * 128 + d * 128);
#pragma unroll 8
        for (int k = 0; k < 32; ++k) a += dot4(vv[k], ov[k]);
        float y = xs[d] + a;
        y = block_ln(y, rbuf, d, ln1_g[L * 128 + d], ln1_b[L * 128 + d]);
        xs[d] = y;
        __syncthreads();
        for (int j = d; j < 2048; j += 128) {
            float f = ff1_b[L * 2048 + j];
            const float4* w1 = (const float4*)(ff1_w + (size_t)L * 2048 * 128 + (size_t)j * 128);
#pragma unroll 8
            for (int k = 0; k < 32; ++k) f += dot4(xv[k], w1[k]);
            f1[j] = fmaxf(f, 0.f);
        }
        __syncthreads();
        float f2 = ff2_b[L * 128 + d];
        const float4* w2 = (const float4*)(ff2_w + (size_t)L * 128 * 2048 + (size_t)d * 2048);
#pragma unroll 8
        for (int k = 0; k < 512; ++k) f2 += dot4(fv[k], w2[k]);
        float y2 = xs[d] + f2;
        y2 = block_ln(y2, rbuf, d, ln2_g[L * 128 + d], ln2_b[L * 128 + d]);
        xs[d] = y2;
        __syncthreads();
    }
    xe[b * 128 + d] = xs[d];
}

// ---------------- mid projection ----------------
__global__ void k_mid(const float* __restrict__ xe, const float* __restrict__ mid_w,
                      const float* __restrict__ mid_b, float* __restrict__ mid) {
    int b = blockIdx.x, c = threadIdx.x;  // 64 threads
    float s = mid_b[c];
    const float* xr = xe + b * 128;
    const float* wr = mid_w + c * 128;
    for (int k = 0; k < 128; ++k) s += xr[k] * wr[k];
    mid[b * 64 + c] = s;
}

// ---------------- direct 3x3 SAME conv ----------------
// Tile: TH x 32 spatial (TH = 8*PX), 256 threads, PX pixels/thread, COT out-chans/thread.
// acc = COT*PX registers (keep <= 32 to avoid spill; VGPR cap 128 via launch_bounds).
// MIN: 0 = read `in` (chunk-local); 1 = fused q_sample from tgt/noise (global batch idx)
// MOUT: 0 = bias; 1 = relu; 2 = relu+mid; 3 = bias + fused MSE partial
template <int CIN, int COUT, int CC, int COT, int PX, int MIN, int MOUT>
__global__ __launch_bounds__(256, 4) void k_conv(
    const float* __restrict__ in, const float* __restrict__ tgt,
    const float* __restrict__ noise, const float* __restrict__ sab,
    const float* __restrict__ snab, const float* __restrict__ wgt,
    const float* __restrict__ bias, const float* __restrict__ mid,
    float* __restrict__ out, float* __restrict__ partial, int b0) {
    const int TH = 8 * PX;          // tile height (32 for PX=4, 16 for PX=2)
    const int NG = 32 / PX;         // col groups per row
    __shared__ float it[CC][TH + 2][35];
    __shared__ float wt[COT][CC][9];
    __shared__ float rs[256];
    int tid = threadIdx.x;
    int tx = tid % NG, ty = tid / NG;   // tx: col group, ty: row in tile
    int bx = blockIdx.x, by = blockIdx.y;
    const int GROUPS = COUT / COT;
    int bl = blockIdx.z / GROUPS;       // chunk-local batch (ws buffers)
    int g = blockIdx.z % GROUPS;
    int bg = b0 + bl;                   // global batch (tgt/noise/sab/mid/mse)
    int co0 = g * COT;

    float acc[COT][PX];
#pragma unroll
    for (int co = 0; co < COT; ++co)
#pragma unroll
        for (int p = 0; p < PX; ++p) acc[co][p] = 0.f;
    float za = 0.f, zb = 0.f;
    if (MIN == 1) { za = sab[bg]; zb = snab[bg]; }

    for (int c0 = 0; c0 < CIN; c0 += CC) {
        for (int idx = tid; idx < CC * (TH + 2) * 34; idx += 256) {
            int c = idx / ((TH + 2) * 34), rem = idx % ((TH + 2) * 34);
            int yy = rem / 34, xx = rem % 34;
            int gy = by * TH + yy - 1, gx = bx * 32 + xx - 1;
            float v = 0.f;
            if (gy >= 0 && gy < 128 && gx >= 0 && gx < 128) {
                if (MIN == 1) {
                    size_t off = (((size_t)bg * CIN + c0 + c) * 128 + gy) * 128 + gx;
                    v = za * tgt[off] + zb * noise[off];
                } else {
                    size_t off = (((size_t)bl * CIN + c0 + c) * 128 + gy) * 128 + gx;
                    v = in[off];
                }
            }
            it[c][yy][xx] = v;
        }
        for (int idx = tid; idx < COT * CC * 9; idx += 256) {
            int co = idx / (CC * 9), rem = idx % (CC * 9);
            int c = rem / 9, k = rem % 9;
            wt[co][c][k] = wgt[((size_t)(co0 + co) * CIN + c0 + c) * 9 + k];
        }
        __syncthreads();
#pragma unroll 2
        for (int c = 0; c < CC; ++c) {
#pragma unroll
            for (int ky = 0; ky < 3; ++ky) {
                float win[PX + 2];
#pragma unroll
                for (int i = 0; i < PX + 2; ++i) win[i] = it[c][ty + ky][tx * PX + i];
#pragma unroll
                for (int kx = 0; kx < 3; ++kx) {
#pragma unroll
                    for (int co = 0; co < COT; ++co) {
                        float w = wt[co][c][ky * 3 + kx];
#pragma unroll
                        for (int p = 0; p < PX; ++p)
                            acc[co][p] += win[kx + p] * w;
                    }
                }
            }
        }
        __syncthreads();
    }

    int gy = by * TH + ty;
    int gx0 = bx * 32 + tx * PX;
    if (MOUT == 3) {
        float ss = 0.f;
#pragma unroll
        for (int co = 0; co < COT; ++co) {
#pragma unroll
            for (int p = 0; p < PX; ++p) {
                float v = acc[co][p] + bias[co0 + co];
                size_t off = (((size_t)bg * COUT + co) * 128 + gy) * 128 + gx0 + p;
                float diff = v - noise[off];
                ss += diff * diff;
            }
        }
        rs[tid] = ss;
        __syncthreads();
        for (int s = 128; s > 0; s >>= 1) { if (tid < s) rs[tid] += rs[tid + s]; __syncthreads(); }
        if (tid == 0) partial[(((size_t)bg * GROUPS + g) * (128 / TH) + by) * 4 + bx] = rs[0];
    } else {
#pragma unroll
        for (int co = 0; co < COT; ++co) {
            float bsum = bias[co0 + co];
            float vals[PX];
#pragma unroll
            for (int p = 0; p < PX; ++p) {
                float v = acc[co][p] + bsum;
                if (MOUT >= 1) v = fmaxf(v, 0.f);
                if (MOUT == 2) v += mid[bg * 64 + co0 + co];
                vals[p] = v;
            }
            float* dst = &out[(((size_t)bl * COUT + co0 + co) * 128 + gy) * 128 + gx0];
            if (PX == 4) {
                float4 v4 = make_float4(vals[0], vals[1], vals[2], vals[PX - 1]);
                *(float4*)dst = v4;
            } else {
#pragma unroll
                for (int p = 0; p < PX; ++p) dst[p] = vals[p];
            }
        }
    }
}

// ---------------- final MSE reduction ----------------
__global__ void k_final(const float* __restrict__ partial, float* __restrict__ out) {
    __shared__ float rs[256];
    int tid = threadIdx.x;
    float s = 0.f;
    for (int i = tid; i < 2048; i += 256) s += partial[i];
    rs[tid] = s;
    __syncthreads();
    for (int st = 128; st > 0; st >>= 1) { if (tid < st) rs[tid] += rs[tid + st]; __syncthreads(); }
    if (tid == 0) out[0] = rs[0] / 3145728.0f;
}

extern "C" void kernel_launch(void* const* d_in, const int* in_sizes, int n_in,
                              void* d_out, int out_size, void* d_ws, size_t ws_size,
                              hipStream_t stream) {
    const float* cond   = (const float*)d_in[0];
    const float* tgt    = (const float*)d_in[1];
    const float* noise  = (const float*)d_in[2];
    const int*   t      = (const int*)d_in[3];
    const float* enc_w  = (const float*)d_in[4];
    const float* enc_b  = (const float*)d_in[5];
    const float* in_w   = (const float*)d_in[6];
    const float* in_b   = (const float*)d_in[7];
    const float* out_w  = (const float*)d_in[8];
    const float* out_b  = (const float*)d_in[9];
    const float* ff1_w  = (const float*)d_in[10];
    const float* ff1_b  = (const float*)d_in[11];
    const float* ff2_w  = (const float*)d_in[12];
    const float* ff2_b  = (const float*)d_in[13];
    const float* ln1_g  = (const float*)d_in[14];
    const float* ln1_b  = (const float*)d_in[15];
    const float* ln2_g  = (const float*)d_in[16];
    const float* ln2_b  = (const float*)d_in[17];
    const float* d1_w   = (const float*)d_in[18];
    const float* d1_b   = (const float*)d_in[19];
    const float* d2_w   = (const float*)d_in[20];
    const float* d2_b   = (const float*)d_in[21];
    const float* mid_w  = (const float*)d_in[22];
    const float* mid_b  = (const float*)d_in[23];
    const float* u1_w   = (const float*)d_in[24];
    const float* u1_b   = (const float*)d_in[25];
    const float* u2_w   = (const float*)d_in[26];
    const float* u2_b   = (const float*)d_in[27];

    float* ws = (float*)d_ws;
    // control region: 131072 floats
    float* sab     = ws;                    // 64
    float* snab    = ws + 64;               // 64
    float* x0      = ws + 128;              // 8192
    float* xe      = ws + 8320;             // 8192
    float* mid     = ws + 16512;            // 4096
    float* encpart = ws + 20608;            // 65536
    float* msepart = ws + 86144;            // 2048 (room for 4096)

    // ws-adaptive batch chunk: NB images of h1(32ch)+h2(64ch)+h3(32ch) = NB*2097152 floats
    const size_t SMALL = 131072;
    size_t avail = (ws_size / 4 > SMALL) ? (ws_size / 4 - SMALL) : 0;
    int NB = 1;
    const int cands[7] = {64, 32, 16, 8, 4, 2, 1};
    for (int ci = 0; ci < 7; ++ci) {
        if ((size_t)cands[ci] * 2097152ull <= avail) { NB = cands[ci]; break; }
    }
    float* h1 = ws + SMALL;                                  // NB*32*128*128
    float* h2 = h1 + (size_t)NB * 524288ull;                 // NB*64*128*128
    float* h3 = h2 + (size_t)NB * 1048576ull;                // NB*32*128*128

    k_alpha<<<1, 64, 0, stream>>>(t, sab, snab);
    k_enc_gemm<<<dim3(8, 4, KSEG), 256, 0, stream>>>(cond, enc_w, encpart);
    k_enc_reduce<<<32, 256, 0, stream>>>(encpart, enc_b, x0);
    k_tf<<<64, 128, 0, stream>>>(x0, xe, in_w, in_b, out_w, out_b,
                                 ff1_w, ff1_b, ff2_w, ff2_b,
                                 ln1_g, ln1_b, ln2_g, ln2_b);
    k_mid<<<64, 64, 0, stream>>>(xe, mid_w, mid_b, mid);

    for (int cb = 0; cb < 64; cb += NB) {
        // conv1: 3->32, fused q_sample, relu.  COT=8 -> 4 groups
        k_conv<3, 32, 3, 8, 4, 1, 1><<<dim3(4, 4, NB * 4), 256, 0, stream>>>(
            nullptr, tgt, noise, sab, snab, d1_w, d1_b, nullptr, h1, nullptr, cb);
        // conv2: 32->64, relu + mid add.  COT=8 -> 8 groups
        k_conv<32, 64, 4, 8, 4, 0, 2><<<dim3(4, 4, NB * 8), 256, 0, stream>>>(
            h1, nullptr, nullptr, nullptr, nullptr, d2_w, d2_b, mid, h2, nullptr, cb);
        // u1: 64->32, relu.  COT=8 -> 4 groups
        k_conv<64, 32, 4, 8, 4, 0, 1><<<dim3(4, 4, NB * 4), 256, 0, stream>>>(
            h2, nullptr, nullptr, nullptr, nullptr, u1_w, u1_b, nullptr, h3, nullptr, cb);
        // u2: 32->3, fused MSE partials.  PX=2 tile 16x32 -> by 0..7
        k_conv<32, 3, 4, 3, 2, 0, 3><<<dim3(4, 8, NB), 256, 0, stream>>>(
            h3, nullptr, noise, nullptr, nullptr, u2_w, u2_b, nullptr, nullptr, msepart, cb);
    }

    k_final<<<1, 256, 0, stream>>>(msepart, (float*)d_out);
}

// Round 5
// 1338.429 us; speedup vs baseline: 2.7993x; 1.6852x over previous
//
#include <hip/hip_runtime.h>
#include <math.h>

#define ENC_K 49152
#define KSEG 8
#define KLEN (ENC_K / KSEG)   // 6144

typedef __attribute__((ext_vector_type(8))) short bf16x8;
typedef __attribute__((ext_vector_type(4))) float f32x4;

__device__ inline unsigned short f2bf(float f) {
    unsigned int u = __builtin_bit_cast(unsigned int, f);
    unsigned int r = u + 0x7fffu + ((u >> 16) & 1u);
    return (unsigned short)(r >> 16);
}
__device__ inline float bf2f(unsigned short h) {
    return __builtin_bit_cast(float, ((unsigned int)h) << 16);
}
__device__ inline float dot4(const float4 a, const float4 b) {
    return a.x * b.x + a.y * b.y + a.z * b.z + a.w * b.w;
}

// ---------------- alpha_bar per batch ----------------
__global__ void k_alpha(const int* __restrict__ t, float* __restrict__ sab, float* __restrict__ snab) {
    int b = threadIdx.x;
    if (b < 64) {
        int tb = t[b];
        const float step = (0.02f - 1e-4f) / 999.0f;
        float ab = 1.0f;
        for (int i = 0; i <= tb; ++i) {
            float beta = 1e-4f + step * (float)i;
            ab *= (1.0f - beta);
        }
        sab[b] = sqrtf(ab);
        snab[b] = sqrtf(1.0f - ab);
    }
}

// ---------------- conv weight prep: f32 [CO][CI][3][3] -> bf16 [tap][CO][CI] ----------------
__global__ void k_prep_cw(const float* __restrict__ w, unsigned short* __restrict__ out, int CO, int CI) {
    int idx = blockIdx.x * 256 + threadIdx.x;
    int total = CO * CI * 9;
    if (idx < total) {
        int tap = idx / (CO * CI);
        int rem = idx % (CO * CI);
        int co = rem / CI, ci = rem % CI;
        out[idx] = f2bf(w[((size_t)co * CI + ci) * 9 + tap]);
    }
}

// ---------------- encoder GEMM: x0 = cond @ W^T (K-split partials) ----------------
__global__ void k_enc_gemm(const float* __restrict__ cond, const float* __restrict__ w,
                           float* __restrict__ partial) {
    __shared__ float As[16][68];
    __shared__ float Ws[16][68];
    int tid = threadIdx.x;
    int j = tid & 15, i = tid >> 4;
    int d0 = blockIdx.x * 16, b0 = blockIdx.y * 16;
    int k0 = blockIdx.z * KLEN;
    float acc = 0.f;
    for (int kk = 0; kk < KLEN; kk += 64) {
        for (int idx = tid; idx < 1024; idx += 256) {
            int r = idx >> 6, c = idx & 63;
            As[r][c] = cond[(size_t)(b0 + r) * ENC_K + k0 + kk + c];
            Ws[r][c] = w[(size_t)(d0 + r) * ENC_K + k0 + kk + c];
        }
        __syncthreads();
        const float4* a4 = (const float4*)&As[i][0];
        const float4* w4 = (const float4*)&Ws[j][0];
#pragma unroll
        for (int k = 0; k < 16; ++k) acc += dot4(a4[k], w4[k]);
        __syncthreads();
    }
    partial[((size_t)blockIdx.z * 64 + b0 + i) * 128 + d0 + j] = acc;
}

__global__ void k_enc_reduce(const float* __restrict__ partial, const float* __restrict__ bias,
                             float* __restrict__ x0) {
    int idx = blockIdx.x * 256 + threadIdx.x;  // 8192 total
    float s = bias[idx & 127];
    for (int ks = 0; ks < KSEG; ++ks) s += partial[(size_t)ks * 8192 + idx];
    x0[idx] = s;
}

// ---------------- transformer layer (seq_len 1), one block per batch row ----------------
__device__ float sum128(float v, int tid, float* red) {
    if (tid < 128) red[tid] = v;
    __syncthreads();
    if (tid < 64) red[tid] += red[tid + 64]; __syncthreads();
    if (tid < 32) red[tid] += red[tid + 32]; __syncthreads();
    if (tid < 16) red[tid] += red[tid + 16]; __syncthreads();
    if (tid < 8)  red[tid] += red[tid + 8];  __syncthreads();
    if (tid < 4)  red[tid] += red[tid + 4];  __syncthreads();
    if (tid < 2)  red[tid] += red[tid + 2];  __syncthreads();
    if (tid < 1)  red[tid] += red[tid + 1];  __syncthreads();
    float s = red[0];
    __syncthreads();
    return s;
}

__global__ __launch_bounds__(1024) void k_tf_layer(
    float* __restrict__ xs,
    const float* __restrict__ in_w, const float* __restrict__ in_b,
    const float* __restrict__ out_w, const float* __restrict__ out_b,
    const float* __restrict__ ff1_w, const float* __restrict__ ff1_b,
    const float* __restrict__ ff2_w, const float* __restrict__ ff2_b,
    const float* __restrict__ ln1_g, const float* __restrict__ ln1_b,
    const float* __restrict__ ln2_g, const float* __restrict__ ln2_b, int L) {
    __shared__ float xr[128], vr[128], tp[8][128], f1s[2048], red[128];
    int b = blockIdx.x, tid = threadIdx.x;
    if (tid < 128) xr[tid] = xs[b * 128 + tid];
    __syncthreads();
    // v = x @ Wv^T + bv (4-way segmented dot)
    if (tid < 512) {
        int d = tid & 127, s = tid >> 7;
        const float4* w = (const float4*)(in_w + ((size_t)L * 384 + 256 + d) * 128) + s * 8;
        const float4* x4 = (const float4*)xr + s * 8;
        float p = 0.f;
#pragma unroll
        for (int k = 0; k < 8; ++k) p += dot4(x4[k], w[k]);
        tp[s][d] = p;
    }
    __syncthreads();
    if (tid < 128) vr[tid] = in_b[L * 384 + 256 + tid] + tp[0][tid] + tp[1][tid] + tp[2][tid] + tp[3][tid];
    __syncthreads();
    // a = v @ Wo^T + bo
    if (tid < 512) {
        int d = tid & 127, s = tid >> 7;
        const float4* w = (const float4*)(out_w + ((size_t)L * 128 + d) * 128) + s * 8;
        const float4* v4 = (const float4*)vr + s * 8;
        float p = 0.f;
#pragma unroll
        for (int k = 0; k < 8; ++k) p += dot4(v4[k], w[k]);
        tp[s][d] = p;
    }
    __syncthreads();
    // ln1(x + a)
    float y = 0.f;
    if (tid < 128) y = xr[tid] + out_b[L * 128 + tid] + tp[0][tid] + tp[1][tid] + tp[2][tid] + tp[3][tid];
    float m1 = sum128(y, tid, red) * (1.f / 128.f);
    float c1 = y - m1;
    float v1 = sum128(c1 * c1, tid, red) * (1.f / 128.f);
    __syncthreads();  // before overwriting xr (readers done)
    if (tid < 128) xr[tid] = c1 * rsqrtf(v1 + 1e-5f) * ln1_g[L * 128 + tid] + ln1_b[L * 128 + tid];
    __syncthreads();
    // f1 = relu(x @ W1^T + b1): 2 neurons per thread
    {
        const float4* x4 = (const float4*)xr;
#pragma unroll
        for (int jj = 0; jj < 2; ++jj) {
            int j = tid + jj * 1024;
            const float4* w = (const float4*)(ff1_w + ((size_t)L * 2048 + j) * 128);
            float p = ff1_b[L * 2048 + j];
#pragma unroll 8
            for (int k = 0; k < 32; ++k) p += dot4(x4[k], w[k]);
            f1s[j] = fmaxf(p, 0.f);
        }
    }
    __syncthreads();
    // f2 = f1 @ W2^T + b2: 8-way segmented dot
    {
        int d = tid & 127, s = tid >> 7;
        const float4* w = (const float4*)(ff2_w + ((size_t)L * 128 + d) * 2048 + s * 256);
        const float4* f4 = (const float4*)f1s + s * 64;
        float p = 0.f;
#pragma unroll 8
        for (int k = 0; k < 64; ++k) p += dot4(f4[k], w[k]);
        tp[s][d] = p;
    }
    __syncthreads();
    float y2 = 0.f;
    if (tid < 128) {
        y2 = xr[tid] + ff2_b[L * 128 + tid];
#pragma unroll
        for (int s = 0; s < 8; ++s) y2 += tp[s][tid];
    }
    float m2 = sum128(y2, tid, red) * (1.f / 128.f);
    float c2 = y2 - m2;
    float v2 = sum128(c2 * c2, tid, red) * (1.f / 128.f);
    if (tid < 128) xs[b * 128 + tid] = c2 * rsqrtf(v2 + 1e-5f) * ln2_g[L * 128 + tid] + ln2_b[L * 128 + tid];
}

// ---------------- mid projection ----------------
__global__ void k_mid(const float* __restrict__ xe, const float* __restrict__ mid_w,
                      const float* __restrict__ mid_b, float* __restrict__ mid) {
    int b = blockIdx.x, c = threadIdx.x;  // 64 threads
    float s = mid_b[c];
    const float* xr = xe + b * 128;
    const float* wr = mid_w + c * 128;
    for (int k = 0; k < 128; ++k) s += xr[k] * wr[k];
    mid[b * 64 + c] = s;
}

// ---------------- conv1: 3->32 direct f32, fused q_sample, relu, out bf16 NHWC ----------------
__global__ __launch_bounds__(256, 4) void k_conv1(
    const float* __restrict__ tgt, const float* __restrict__ noise,
    const float* __restrict__ sab, const float* __restrict__ snab,
    const float* __restrict__ wgt, const float* __restrict__ bias,
    unsigned short* __restrict__ h1, int b0) {
    __shared__ float it[3][34][35];
    __shared__ float wt[8][3][9];
    int tid = threadIdx.x;
    int tx = tid & 7, ty = tid >> 3;
    int bx = blockIdx.x, by = blockIdx.y;
    int bl = blockIdx.z >> 2, g = blockIdx.z & 3;
    int bg = b0 + bl, co0 = g * 8;
    float za = sab[bg], zb = snab[bg];
    for (int idx = tid; idx < 3 * 34 * 34; idx += 256) {
        int c = idx / 1156, rem = idx % 1156;
        int yy = rem / 34, xx = rem % 34;
        int gy = by * 32 + yy - 1, gx = bx * 32 + xx - 1;
        float v = 0.f;
        if (gy >= 0 && gy < 128 && gx >= 0 && gx < 128) {
            size_t off = (((size_t)bg * 3 + c) * 128 + gy) * 128 + gx;
            v = za * tgt[off] + zb * noise[off];
        }
        it[c][yy][xx] = v;
    }
    for (int idx = tid; idx < 8 * 27; idx += 256) {
        int co = idx / 27, rem = idx % 27;
        wt[co][rem / 9][rem % 9] = wgt[(size_t)(co0 + co) * 27 + rem];
    }
    __syncthreads();
    float acc[8][4];
#pragma unroll
    for (int co = 0; co < 8; ++co)
#pragma unroll
        for (int p = 0; p < 4; ++p) acc[co][p] = 0.f;
#pragma unroll
    for (int c = 0; c < 3; ++c)
#pragma unroll
        for (int ky = 0; ky < 3; ++ky) {
            float win[6];
#pragma unroll
            for (int i = 0; i < 6; ++i) win[i] = it[c][ty + ky][tx * 4 + i];
#pragma unroll
            for (int kx = 0; kx < 3; ++kx)
#pragma unroll
                for (int co = 0; co < 8; ++co) {
                    float w = wt[co][c][ky * 3 + kx];
#pragma unroll
                    for (int p = 0; p < 4; ++p) acc[co][p] += win[kx + p] * w;
                }
        }
    int gy = by * 32 + ty, gx0 = bx * 32 + tx * 4;
#pragma unroll
    for (int p = 0; p < 4; ++p) {
        ushort4 oa, ob;
#pragma unroll
        for (int co = 0; co < 4; ++co)
            ((unsigned short*)&oa)[co] = f2bf(fmaxf(acc[co][p] + bias[co0 + co], 0.f));
#pragma unroll
        for (int co = 0; co < 4; ++co)
            ((unsigned short*)&ob)[co] = f2bf(fmaxf(acc[co + 4][p] + bias[co0 + co + 4], 0.f));
        size_t o = (((size_t)bl * 128 + gy) * 128 + gx0 + p) * 32 + co0;
        *(ushort4*)(h1 + o) = oa;
        *(ushort4*)(h1 + o + 4) = ob;
    }
}

// ---------------- MFMA 3x3 conv: bf16 NHWC in/out, f32 accum ----------------
// Block: 32x x 8y output pixels, 32 output channels (group g). 256 thr = 4 waves.
// Wave wv: rows {2wv, 2wv+1}; per tap: A = W[16co x 32ci], B = In[32ci x 16px].
// MOUT: 1 = relu; 2 = relu then +mid
template <int CIN, int COUT, int MOUT>
__global__ __launch_bounds__(256, 2) void k_convM(
    const unsigned short* __restrict__ in, const unsigned short* __restrict__ wb,
    const float* __restrict__ bias, const float* __restrict__ mid,
    unsigned short* __restrict__ out, int b0) {
    const int GROUPS = COUT / 32;
    __shared__ __align__(16) unsigned short in_t[10 * 34 * 40];  // 80B pixel stride
    __shared__ __align__(16) unsigned short w_t[9 * 32 * 40];
    int tid = threadIdx.x;
    int bx = blockIdx.x, by = blockIdx.y;
    int bl = blockIdx.z / GROUPS, g = blockIdx.z % GROUPS;
    int bg = b0 + bl;
    int co0 = g * 32;
    int lane = tid & 63, wv = tid >> 6;
    int l15 = lane & 15, ch = lane >> 4;

    f32x4 acc[2][2][2];
    f32x4 zf = {0.f, 0.f, 0.f, 0.f};
#pragma unroll
    for (int a = 0; a < 2; ++a)
#pragma unroll
        for (int bq = 0; bq < 2; ++bq)
#pragma unroll
            for (int c = 0; c < 2; ++c) acc[a][bq][c] = zf;

    for (int cs = 0; cs < CIN / 32; ++cs) {
        if (cs) __syncthreads();
        // stage input tile (10 x 34 px x 32 ci)
        for (int c = tid; c < 10 * 34 * 4; c += 256) {
            int cc = c & 3, pix = c >> 2;
            int xx = pix % 34, yy = pix / 34;
            int gy = by * 8 + yy - 1, gx = bx * 32 + xx - 1;
            bf16x8 v = {0, 0, 0, 0, 0, 0, 0, 0};
            if (gy >= 0 && gy < 128 && gx >= 0 && gx < 128)
                v = *(const bf16x8*)(in + (((size_t)bl * 128 + gy) * 128 + gx) * CIN + cs * 32 + cc * 8);
            *(bf16x8*)(in_t + pix * 40 + cc * 8) = v;
        }
        // stage weights (9 taps x 32 co x 32 ci)
        for (int c = tid; c < 9 * 32 * 4; c += 256) {
            int cc = c & 3, row = c >> 2;   // row = tap*32 + co
            int tap = row >> 5, co = row & 31;
            bf16x8 v = *(const bf16x8*)(wb + ((size_t)(tap * COUT + co0 + co)) * CIN + cs * 32 + cc * 8);
            *(bf16x8*)(w_t + row * 40 + cc * 8) = v;
        }
        __syncthreads();
#pragma unroll
        for (int ky = 0; ky < 3; ++ky)
#pragma unroll
            for (int kx = 0; kx < 3; ++kx) {
                int tap = ky * 3 + kx;
                bf16x8 af[2];
#pragma unroll
                for (int cb = 0; cb < 2; ++cb)
                    af[cb] = *(const bf16x8*)(w_t + (tap * 32 + cb * 16 + l15) * 40 + ch * 8);
#pragma unroll
                for (int yl = 0; yl < 2; ++yl) {
                    int yloc = 2 * wv + yl + ky;
#pragma unroll
                    for (int xt = 0; xt < 2; ++xt) {
                        int xloc = xt * 16 + l15 + kx;
                        bf16x8 bfv = *(const bf16x8*)(in_t + (yloc * 34 + xloc) * 40 + ch * 8);
#pragma unroll
                        for (int cb = 0; cb < 2; ++cb)
                            acc[yl][xt][cb] = __builtin_amdgcn_mfma_f32_16x16x32_bf16(
                                af[cb], bfv, acc[yl][xt][cb], 0, 0, 0);
                    }
                }
            }
    }
    // epilogue: lane holds px = l15, co = co0 + cb*16 + ch*4 + r
#pragma unroll
    for (int yl = 0; yl < 2; ++yl) {
        int gy = by * 8 + 2 * wv + yl;
#pragma unroll
        for (int xt = 0; xt < 2; ++xt) {
            int gx = bx * 32 + xt * 16 + l15;
            size_t pixo = (((size_t)bl * 128 + gy) * 128 + gx) * COUT;
#pragma unroll
            for (int cb = 0; cb < 2; ++cb) {
                int co = co0 + cb * 16 + ch * 4;
                ushort4 o;
#pragma unroll
                for (int r = 0; r < 4; ++r) {
                    float v = acc[yl][xt][cb][r] + bias[co + r];
                    v = fmaxf(v, 0.f);
                    if (MOUT == 2) v += mid[bg * 64 + co + r];
                    ((unsigned short*)&o)[r] = f2bf(v);
                }
                *(ushort4*)(out + pixo + co) = o;
            }
        }
    }
}

// ---------------- u2: 32->3 direct (bf16 NHWC in), fused MSE partial ----------------
__global__ __launch_bounds__(256, 4) void k_u2(
    const unsigned short* __restrict__ h3, const float* __restrict__ noise,
    const float* __restrict__ wgt, const float* __restrict__ bias,
    float* __restrict__ partial, int b0) {
    __shared__ __align__(16) unsigned short in_t[18 * 18 * 40];
    __shared__ float wl[864];
    __shared__ float rs[256];
    int tid = threadIdx.x;
    int px = tid & 15, py = tid >> 4;
    int bx = blockIdx.x, by = blockIdx.y, bl = blockIdx.z;
    int bg = b0 + bl;
    for (int c = tid; c < 18 * 18 * 4; c += 256) {
        int cc = c & 3, pix = c >> 2;
        int xx = pix % 18, yy = pix / 18;
        int gy = by * 16 + yy - 1, gx = bx * 16 + xx - 1;
        bf16x8 v = {0, 0, 0, 0, 0, 0, 0, 0};
        if (gy >= 0 && gy < 128 && gx >= 0 && gx < 128)
            v = *(const bf16x8*)(h3 + (((size_t)bl * 128 + gy) * 128 + gx) * 32 + cc * 8);
        *(bf16x8*)(in_t + pix * 40 + cc * 8) = v;
    }
    for (int c = tid; c < 864; c += 256) wl[c] = wgt[c];
    __syncthreads();
    float a0 = bias[0], a1 = bias[1], a2 = bias[2];
#pragma unroll
    for (int ky = 0; ky < 3; ++ky)
#pragma unroll
        for (int kx = 0; kx < 3; ++kx) {
            int tap = ky * 3 + kx;
            int pix = (py + ky) * 18 + (px + kx);
#pragma unroll
            for (int cc = 0; cc < 4; ++cc) {
                bf16x8 v8 = *(const bf16x8*)(in_t + pix * 40 + cc * 8);
#pragma unroll
                for (int jj = 0; jj < 8; ++jj) {
                    float xv = bf2f((unsigned short)v8[jj]);
                    int ci = cc * 8 + jj;
                    a0 += xv * wl[ci * 9 + tap];
                    a1 += xv * wl[(32 + ci) * 9 + tap];
                    a2 += xv * wl[(64 + ci) * 9 + tap];
                }
            }
        }
    int gy = by * 16 + py, gx = bx * 16 + px;
    size_t base = ((size_t)bg * 3 * 128 + gy) * 128 + gx;
    float d0 = a0 - noise[base];
    float d1 = a1 - noise[base + 16384];
    float d2 = a2 - noise[base + 32768];
    rs[tid] = d0 * d0 + d1 * d1 + d2 * d2;
    __syncthreads();
    for (int s = 128; s > 0; s >>= 1) {
        if (tid < s) rs[tid] += rs[tid + s];
        __syncthreads();
    }
    if (tid == 0) partial[bg * 64 + by * 8 + bx] = rs[0];
}

// ---------------- final MSE reduction ----------------
__global__ void k_final(const float* __restrict__ partial, float* __restrict__ out) {
    __shared__ float rs[256];
    int tid = threadIdx.x;
    float s = 0.f;
    for (int i = tid; i < 4096; i += 256) s += partial[i];
    rs[tid] = s;
    __syncthreads();
    for (int st = 128; st > 0; st >>= 1) {
        if (tid < st) rs[tid] += rs[tid + st];
        __syncthreads();
    }
    if (tid == 0) out[0] = rs[0] / 3145728.0f;
}

extern "C" void kernel_launch(void* const* d_in, const int* in_sizes, int n_in,
                              void* d_out, int out_size, void* d_ws, size_t ws_size,
                              hipStream_t stream) {
    const float* cond   = (const float*)d_in[0];
    const float* tgt    = (const float*)d_in[1];
    const float* noise  = (const float*)d_in[2];
    const int*   t      = (const int*)d_in[3];
    const float* enc_w  = (const float*)d_in[4];
    const float* enc_b  = (const float*)d_in[5];
    const float* in_w   = (const float*)d_in[6];
    const float* in_b   = (const float*)d_in[7];
    const float* out_w  = (const float*)d_in[8];
    const float* out_b  = (const float*)d_in[9];
    const float* ff1_w  = (const float*)d_in[10];
    const float* ff1_b  = (const float*)d_in[11];
    const float* ff2_w  = (const float*)d_in[12];
    const float* ff2_b  = (const float*)d_in[13];
    const float* ln1_g  = (const float*)d_in[14];
    const float* ln1_b  = (const float*)d_in[15];
    const float* ln2_g  = (const float*)d_in[16];
    const float* ln2_b  = (const float*)d_in[17];
    const float* d1_w   = (const float*)d_in[18];
    const float* d1_b   = (const float*)d_in[19];
    const float* d2_w   = (const float*)d_in[20];
    const float* d2_b   = (const float*)d_in[21];
    const float* mid_w  = (const float*)d_in[22];
    const float* mid_b  = (const float*)d_in[23];
    const float* u1_w   = (const float*)d_in[24];
    const float* u1_b   = (const float*)d_in[25];
    const float* u2_w   = (const float*)d_in[26];
    const float* u2_b   = (const float*)d_in[27];

    float* ws = (float*)d_ws;
    // control region: 131072 floats
    float* sab     = ws;                    // 64
    float* snab    = ws + 64;               // 64
    float* x0      = ws + 128;              // 8192
    float* mid     = ws + 16512;            // 4096
    float* encpart = ws + 20608;            // 65536
    float* msepart = ws + 86144;            // 4096
    unsigned short* wb2  = (unsigned short*)(ws + 90240);  // 18432 bf16 = 9216 f32
    unsigned short* wbu1 = (unsigned short*)(ws + 99456);  // 18432 bf16

    // ws-adaptive batch chunk: NB images of bf16 h1(32ch)+h2(64ch)+h3(32ch)
    // = NB * (262144 + 524288 + 262144) f32-slots = NB * 1048576 floats
    const size_t SMALL = 131072;
    size_t avail = (ws_size / 4 > SMALL) ? (ws_size / 4 - SMALL) : 0;
    int NB = 1;
    const int cands[7] = {64, 32, 16, 8, 4, 2, 1};
    for (int ci = 0; ci < 7; ++ci) {
        if ((size_t)cands[ci] * 1048576ull <= avail) { NB = cands[ci]; break; }
    }
    unsigned short* hb1 = (unsigned short*)(ws + SMALL);
    unsigned short* hb2 = (unsigned short*)(ws + SMALL + (size_t)NB * 262144ull);
    unsigned short* hb3 = (unsigned short*)(ws + SMALL + (size_t)NB * 786432ull);

    k_alpha<<<1, 64, 0, stream>>>(t, sab, snab);
    k_prep_cw<<<72, 256, 0, stream>>>(d2_w, wb2, 64, 32);
    k_prep_cw<<<72, 256, 0, stream>>>(u1_w, wbu1, 32, 64);
    k_enc_gemm<<<dim3(8, 4, KSEG), 256, 0, stream>>>(cond, enc_w, encpart);
    k_enc_reduce<<<32, 256, 0, stream>>>(encpart, enc_b, x0);
    k_tf_layer<<<64, 1024, 0, stream>>>(x0, in_w, in_b, out_w, out_b, ff1_w, ff1_b,
                                        ff2_w, ff2_b, ln1_g, ln1_b, ln2_g, ln2_b, 0);
    k_tf_layer<<<64, 1024, 0, stream>>>(x0, in_w, in_b, out_w, out_b, ff1_w, ff1_b,
                                        ff2_w, ff2_b, ln1_g, ln1_b, ln2_g, ln2_b, 1);
    k_mid<<<64, 64, 0, stream>>>(x0, mid_w, mid_b, mid);

    for (int cb = 0; cb < 64; cb += NB) {
        k_conv1<<<dim3(4, 4, NB * 4), 256, 0, stream>>>(
            tgt, noise, sab, snab, d1_w, d1_b, hb1, cb);
        k_convM<32, 64, 2><<<dim3(4, 16, NB * 2), 256, 0, stream>>>(
            hb1, wb2, d2_b, mid, hb2, cb);
        k_convM<64, 32, 1><<<dim3(4, 16, NB), 256, 0, stream>>>(
            hb2, wbu1, u1_b, nullptr, hb3, cb);
        k_u2<<<dim3(8, 8, NB), 256, 0, stream>>>(
            hb3, noise, u2_w, u2_b, msepart, cb);
    }

    k_final<<<1, 256, 0, stream>>>(msepart, (float*)d_out);
}

// Round 6
// 791.282 us; speedup vs baseline: 4.7350x; 1.6915x over previous
//
#include <hip/hip_runtime.h>
#include <math.h>

#define ENC_K 49152
#define KSEG 8
#define KLEN (ENC_K / KSEG)   // 6144

typedef __attribute__((ext_vector_type(8))) short bf16x8;
typedef __attribute__((ext_vector_type(4))) float f32x4;

__device__ inline unsigned short f2bf(float f) {
    unsigned int u = __builtin_bit_cast(unsigned int, f);
    unsigned int r = u + 0x7fffu + ((u >> 16) & 1u);
    return (unsigned short)(r >> 16);
}
__device__ inline float bf2f(unsigned short h) {
    return __builtin_bit_cast(float, ((unsigned int)h) << 16);
}
__device__ inline float dot4(const float4 a, const float4 b) {
    return a.x * b.x + a.y * b.y + a.z * b.z + a.w * b.w;
}

// ---------------- alpha_bar per batch ----------------
__global__ void k_alpha(const int* __restrict__ t, float* __restrict__ sab, float* __restrict__ snab) {
    int b = threadIdx.x;
    if (b < 64) {
        int tb = t[b];
        const float step = (0.02f - 1e-4f) / 999.0f;
        float ab = 1.0f;
        for (int i = 0; i <= tb; ++i) {
            float beta = 1e-4f + step * (float)i;
            ab *= (1.0f - beta);
        }
        sab[b] = sqrtf(ab);
        snab[b] = sqrtf(1.0f - ab);
    }
}

// ---------------- conv weight prep: f32 [CO][CI][3][3] -> bf16 [tap][CO][CI] ----------------
__global__ void k_prep_cw(const float* __restrict__ w, unsigned short* __restrict__ out, int CO, int CI) {
    int idx = blockIdx.x * 256 + threadIdx.x;
    int total = CO * CI * 9;
    if (idx < total) {
        int tap = idx / (CO * CI);
        int rem = idx % (CO * CI);
        int co = rem / CI, ci = rem % CI;
        out[idx] = f2bf(w[((size_t)co * CI + ci) * 9 + tap]);
    }
}

// u2 weights: f32 [3][32][3][3] -> bf16 [tap][16 co(pad)][32 ci], co>=3 zero
__global__ void k_prep_u2(const float* __restrict__ w, unsigned short* __restrict__ out) {
    int idx = blockIdx.x * 256 + threadIdx.x;
    if (idx < 9 * 16 * 32) {
        int tap = idx / 512;
        int rem = idx % 512;
        int co = rem / 32, ci = rem % 32;
        out[idx] = (co < 3) ? f2bf(w[((size_t)co * 32 + ci) * 9 + tap]) : (unsigned short)0;
    }
}

// ---------------- encoder GEMM: x0 = cond @ W^T (K-split partials) ----------------
__global__ void k_enc_gemm(const float* __restrict__ cond, const float* __restrict__ w,
                           float* __restrict__ partial) {
    __shared__ float As[16][68];
    __shared__ float Ws[16][68];
    int tid = threadIdx.x;
    int j = tid & 15, i = tid >> 4;
    int d0 = blockIdx.x * 16, b0 = blockIdx.y * 16;
    int k0 = blockIdx.z * KLEN;
    float acc = 0.f;
    for (int kk = 0; kk < KLEN; kk += 64) {
        for (int idx = tid; idx < 1024; idx += 256) {
            int r = idx >> 6, c = idx & 63;
            As[r][c] = cond[(size_t)(b0 + r) * ENC_K + k0 + kk + c];
            Ws[r][c] = w[(size_t)(d0 + r) * ENC_K + k0 + kk + c];
        }
        __syncthreads();
        const float4* a4 = (const float4*)&As[i][0];
        const float4* w4 = (const float4*)&Ws[j][0];
#pragma unroll
        for (int k = 0; k < 16; ++k) acc += dot4(a4[k], w4[k]);
        __syncthreads();
    }
    partial[((size_t)blockIdx.z * 64 + b0 + i) * 128 + d0 + j] = acc;
}

__global__ void k_enc_reduce(const float* __restrict__ partial, const float* __restrict__ bias,
                             float* __restrict__ x0) {
    int idx = blockIdx.x * 256 + threadIdx.x;  // 8192 total
    float s = bias[idx & 127];
    for (int ks = 0; ks < KSEG; ++ks) s += partial[(size_t)ks * 8192 + idx];
    x0[idx] = s;
}

// ---------------- transformer layer (seq_len 1), one block per batch row ----------------
__device__ float sum128(float v, int tid, float* red) {
    if (tid < 128) red[tid] = v;
    __syncthreads();
    if (tid < 64) red[tid] += red[tid + 64]; __syncthreads();
    if (tid < 32) red[tid] += red[tid + 32]; __syncthreads();
    if (tid < 16) red[tid] += red[tid + 16]; __syncthreads();
    if (tid < 8)  red[tid] += red[tid + 8];  __syncthreads();
    if (tid < 4)  red[tid] += red[tid + 4];  __syncthreads();
    if (tid < 2)  red[tid] += red[tid + 2];  __syncthreads();
    if (tid < 1)  red[tid] += red[tid + 1];  __syncthreads();
    float s = red[0];
    __syncthreads();
    return s;
}

__global__ __launch_bounds__(1024) void k_tf_layer(
    float* __restrict__ xs,
    const float* __restrict__ in_w, const float* __restrict__ in_b,
    const float* __restrict__ out_w, const float* __restrict__ out_b,
    const float* __restrict__ ff1_w, const float* __restrict__ ff1_b,
    const float* __restrict__ ff2_w, const float* __restrict__ ff2_b,
    const float* __restrict__ ln1_g, const float* __restrict__ ln1_b,
    const float* __restrict__ ln2_g, const float* __restrict__ ln2_b, int L) {
    __shared__ float xr[128], vr[128], tp[8][128], f1s[2048], red[128];
    int b = blockIdx.x, tid = threadIdx.x;
    if (tid < 128) xr[tid] = xs[b * 128 + tid];
    __syncthreads();
    if (tid < 512) {
        int d = tid & 127, s = tid >> 7;
        const float4* w = (const float4*)(in_w + ((size_t)L * 384 + 256 + d) * 128) + s * 8;
        const float4* x4 = (const float4*)xr + s * 8;
        float p = 0.f;
#pragma unroll
        for (int k = 0; k < 8; ++k) p += dot4(x4[k], w[k]);
        tp[s][d] = p;
    }
    __syncthreads();
    if (tid < 128) vr[tid] = in_b[L * 384 + 256 + tid] + tp[0][tid] + tp[1][tid] + tp[2][tid] + tp[3][tid];
    __syncthreads();
    if (tid < 512) {
        int d = tid & 127, s = tid >> 7;
        const float4* w = (const float4*)(out_w + ((size_t)L * 128 + d) * 128) + s * 8;
        const float4* v4 = (const float4*)vr + s * 8;
        float p = 0.f;
#pragma unroll
        for (int k = 0; k < 8; ++k) p += dot4(v4[k], w[k]);
        tp[s][d] = p;
    }
    __syncthreads();
    float y = 0.f;
    if (tid < 128) y = xr[tid] + out_b[L * 128 + tid] + tp[0][tid] + tp[1][tid] + tp[2][tid] + tp[3][tid];
    float m1 = sum128(y, tid, red) * (1.f / 128.f);
    float c1 = y - m1;
    float v1 = sum128(c1 * c1, tid, red) * (1.f / 128.f);
    __syncthreads();
    if (tid < 128) xr[tid] = c1 * rsqrtf(v1 + 1e-5f) * ln1_g[L * 128 + tid] + ln1_b[L * 128 + tid];
    __syncthreads();
    {
        const float4* x4 = (const float4*)xr;
#pragma unroll
        for (int jj = 0; jj < 2; ++jj) {
            int j = tid + jj * 1024;
            const float4* w = (const float4*)(ff1_w + ((size_t)L * 2048 + j) * 128);
            float p = ff1_b[L * 2048 + j];
#pragma unroll 8
            for (int k = 0; k < 32; ++k) p += dot4(x4[k], w[k]);
            f1s[j] = fmaxf(p, 0.f);
        }
    }
    __syncthreads();
    {
        int d = tid & 127, s = tid >> 7;
        const float4* w = (const float4*)(ff2_w + ((size_t)L * 128 + d) * 2048 + s * 256);
        const float4* f4 = (const float4*)f1s + s * 64;
        float p = 0.f;
#pragma unroll 8
        for (int k = 0; k < 64; ++k) p += dot4(f4[k], w[k]);
        tp[s][d] = p;
    }
    __syncthreads();
    float y2 = 0.f;
    if (tid < 128) {
        y2 = xr[tid] + ff2_b[L * 128 + tid];
#pragma unroll
        for (int s = 0; s < 8; ++s) y2 += tp[s][tid];
    }
    float m2 = sum128(y2, tid, red) * (1.f / 128.f);
    float c2 = y2 - m2;
    float v2 = sum128(c2 * c2, tid, red) * (1.f / 128.f);
    if (tid < 128) xs[b * 128 + tid] = c2 * rsqrtf(v2 + 1e-5f) * ln2_g[L * 128 + tid] + ln2_b[L * 128 + tid];
}

// ---------------- mid projection ----------------
__global__ void k_mid(const float* __restrict__ xe, const float* __restrict__ mid_w,
                      const float* __restrict__ mid_b, float* __restrict__ mid) {
    int b = blockIdx.x, c = threadIdx.x;  // 64 threads
    float s = mid_b[c];
    const float* xr = xe + b * 128;
    const float* wr = mid_w + c * 128;
    for (int k = 0; k < 128; ++k) s += xr[k] * wr[k];
    mid[b * 64 + c] = s;
}

// ---------------- fused q_sample + conv1 + conv2 + mid -> h2 (bf16 NHWC) ----------------
// Block: 32x x 8y output px, 32 of 64 out-chans (g). conv1 computed in-block on the
// 34x10 halo tile via per-wave im2col MFMA (K=27 pad 32); h1 lives only in LDS.
__global__ __launch_bounds__(256, 2) void k_fuseA(
    const float* __restrict__ tgt, const float* __restrict__ noise,
    const float* __restrict__ sab, const float* __restrict__ snab,
    const float* __restrict__ d1_w, const float* __restrict__ d1_b,
    const unsigned short* __restrict__ wb2, const float* __restrict__ d2_b,
    const float* __restrict__ mid, unsigned short* __restrict__ h2, int b0) {
    __shared__ float qs[3][12][37];
    __shared__ __align__(16) unsigned short w1t[32 * 40];
    __shared__ __align__(16) unsigned short w2t[9 * 32 * 40];
    __shared__ __align__(16) unsigned short ic[64 * 40];
    __shared__ __align__(16) unsigned short h1t[352 * 40];
    int tid = threadIdx.x;
    int bx = blockIdx.x, by = blockIdx.y;
    int bl = blockIdx.z >> 1, g = blockIdx.z & 1;
    int bg = b0 + bl;
    int lane = tid & 63, wv = tid >> 6, l15 = lane & 15, ch = lane >> 4;
    float za = sab[bg], zb = snab[bg];

    // stage q_sample tile 3ci x 12 x 36 (f32)
    for (int idx = tid; idx < 1296; idx += 256) {
        int c = idx / 432, rem = idx % 432;
        int r2 = rem / 36, c2 = rem % 36;
        int gy = by * 8 + r2 - 2, gx = bx * 32 + c2 - 2;
        float v = 0.f;
        if (gy >= 0 && gy < 128 && gx >= 0 && gx < 128) {
            size_t off = (((size_t)bg * 3 + c) * 128 + gy) * 128 + gx;
            v = za * tgt[off] + zb * noise[off];
        }
        qs[c][r2][c2] = v;
    }
    // stage conv1 weights [32co][32k] (k = ci*9+tap, pad >=27 with 0)
    for (int idx = tid; idx < 1024; idx += 256) {
        int co = idx >> 5, k = idx & 31;
        w1t[co * 40 + k] = (k < 27) ? f2bf(d1_w[co * 27 + k]) : (unsigned short)0;
    }
    // stage conv2 weights for group g: [9tap][32co][32ci]
    for (int c = tid; c < 9 * 32 * 4; c += 256) {
        int cc = c & 3, row = c >> 2;
        int tap = row >> 5, co = row & 31;
        bf16x8 v = *(const bf16x8*)(wb2 + ((size_t)(tap * 64 + g * 32 + co)) * 32 + cc * 8);
        *(bf16x8*)(w2t + row * 40 + cc * 8) = v;
    }
    __syncthreads();

    // ---- conv1: 22 groups of 16 px, 4 at a time (one per wave) ----
    for (int pgb = 0; pgb < 24; pgb += 4) {
        for (int e = tid; e < 2048; e += 256) {
            int w = e >> 9, inner = e & 511;
            int pxl = inner >> 5, k = inner & 31;
            int px = (pgb + w) * 16 + pxl;
            unsigned short val = 0;
            if (k < 27 && px < 340) {
                int ci = k / 9, tap = k % 9;
                int ky = tap / 3, kx = tap % 3;
                int r1 = px / 34, c1 = px % 34;
                val = f2bf(qs[ci][r1 + ky][c1 + kx]);
            }
            ic[(w * 16 + pxl) * 40 + k] = val;
        }
        __syncthreads();
        int pg = pgb + wv;
        bf16x8 bfv = *(const bf16x8*)(ic + (wv * 16 + l15) * 40 + ch * 8);
        if (pg < 22) {
            int px = pg * 16 + l15;
            int r1 = px / 34, c1 = px % 34;
            int gy1 = by * 8 + r1 - 1, gx1 = bx * 32 + c1 - 1;
            bool inimg = (gy1 >= 0 && gy1 < 128 && gx1 >= 0 && gx1 < 128);
            f32x4 zf = {0.f, 0.f, 0.f, 0.f};
#pragma unroll
            for (int cb = 0; cb < 2; ++cb) {
                bf16x8 af = *(const bf16x8*)(w1t + (cb * 16 + l15) * 40 + ch * 8);
                f32x4 a = __builtin_amdgcn_mfma_f32_16x16x32_bf16(af, bfv, zf, 0, 0, 0);
                ushort4 o;
#pragma unroll
                for (int r = 0; r < 4; ++r) {
                    float v = inimg ? fmaxf(a[r] + d1_b[cb * 16 + ch * 4 + r], 0.f) : 0.f;
                    ((unsigned short*)&o)[r] = f2bf(v);
                }
                *(ushort4*)(h1t + px * 40 + cb * 16 + ch * 4) = o;
            }
        }
        __syncthreads();
    }

    // ---- conv2 (convM-style) from h1t ----
    f32x4 acc[2][2][2];
    f32x4 zf = {0.f, 0.f, 0.f, 0.f};
#pragma unroll
    for (int yl = 0; yl < 2; ++yl)
#pragma unroll
        for (int xt = 0; xt < 2; ++xt)
#pragma unroll
            for (int cb = 0; cb < 2; ++cb) acc[yl][xt][cb] = zf;
#pragma unroll
    for (int ky = 0; ky < 3; ++ky)
#pragma unroll
        for (int kx = 0; kx < 3; ++kx) {
            int tap = ky * 3 + kx;
            bf16x8 af[2];
#pragma unroll
            for (int cb = 0; cb < 2; ++cb)
                af[cb] = *(const bf16x8*)(w2t + (tap * 32 + cb * 16 + l15) * 40 + ch * 8);
#pragma unroll
            for (int yl = 0; yl < 2; ++yl) {
                int yloc = 2 * wv + yl + ky;
#pragma unroll
                for (int xt = 0; xt < 2; ++xt) {
                    int xloc = xt * 16 + l15 + kx;
                    bf16x8 bv = *(const bf16x8*)(h1t + (yloc * 34 + xloc) * 40 + ch * 8);
#pragma unroll
                    for (int cb = 0; cb < 2; ++cb)
                        acc[yl][xt][cb] = __builtin_amdgcn_mfma_f32_16x16x32_bf16(
                            af[cb], bv, acc[yl][xt][cb], 0, 0, 0);
                }
            }
        }
#pragma unroll
    for (int yl = 0; yl < 2; ++yl) {
        int gy = by * 8 + 2 * wv + yl;
#pragma unroll
        for (int xt = 0; xt < 2; ++xt) {
            int gx = bx * 32 + xt * 16 + l15;
            size_t pixo = (((size_t)bl * 128 + gy) * 128 + gx) * 64;
#pragma unroll
            for (int cb = 0; cb < 2; ++cb) {
                int co = g * 32 + cb * 16 + ch * 4;
                ushort4 o;
#pragma unroll
                for (int r = 0; r < 4; ++r) {
                    float v = acc[yl][xt][cb][r] + d2_b[co + r];
                    v = fmaxf(v, 0.f);
                    v += mid[bg * 64 + co + r];
                    ((unsigned short*)&o)[r] = f2bf(v);
                }
                *(ushort4*)(h2 + pixo + co) = o;
            }
        }
    }
}

// ---------------- MFMA 3x3 conv (u1): bf16 NHWC in/out ----------------
template <int CIN, int COUT, int MOUT>
__global__ __launch_bounds__(256, 2) void k_convM(
    const unsigned short* __restrict__ in, const unsigned short* __restrict__ wb,
    const float* __restrict__ bias, const float* __restrict__ mid,
    unsigned short* __restrict__ out, int b0) {
    const int GROUPS = COUT / 32;
    __shared__ __align__(16) unsigned short in_t[10 * 34 * 40];
    __shared__ __align__(16) unsigned short w_t[9 * 32 * 40];
    int tid = threadIdx.x;
    int bx = blockIdx.x, by = blockIdx.y;
    int bl = blockIdx.z / GROUPS, g = blockIdx.z % GROUPS;
    int bg = b0 + bl;
    int co0 = g * 32;
    int lane = tid & 63, wv = tid >> 6;
    int l15 = lane & 15, ch = lane >> 4;

    f32x4 acc[2][2][2];
    f32x4 zf = {0.f, 0.f, 0.f, 0.f};
#pragma unroll
    for (int a = 0; a < 2; ++a)
#pragma unroll
        for (int bq = 0; bq < 2; ++bq)
#pragma unroll
            for (int c = 0; c < 2; ++c) acc[a][bq][c] = zf;

    for (int cs = 0; cs < CIN / 32; ++cs) {
        if (cs) __syncthreads();
        for (int c = tid; c < 10 * 34 * 4; c += 256) {
            int cc = c & 3, pix = c >> 2;
            int xx = pix % 34, yy = pix / 34;
            int gy = by * 8 + yy - 1, gx = bx * 32 + xx - 1;
            bf16x8 v = {0, 0, 0, 0, 0, 0, 0, 0};
            if (gy >= 0 && gy < 128 && gx >= 0 && gx < 128)
                v = *(const bf16x8*)(in + (((size_t)bl * 128 + gy) * 128 + gx) * CIN + cs * 32 + cc * 8);
            *(bf16x8*)(in_t + pix * 40 + cc * 8) = v;
        }
        for (int c = tid; c < 9 * 32 * 4; c += 256) {
            int cc = c & 3, row = c >> 2;
            int tap = row >> 5, co = row & 31;
            bf16x8 v = *(const bf16x8*)(wb + ((size_t)(tap * COUT + co0 + co)) * CIN + cs * 32 + cc * 8);
            *(bf16x8*)(w_t + row * 40 + cc * 8) = v;
        }
        __syncthreads();
#pragma unroll
        for (int ky = 0; ky < 3; ++ky)
#pragma unroll
            for (int kx = 0; kx < 3; ++kx) {
                int tap = ky * 3 + kx;
                bf16x8 af[2];
#pragma unroll
                for (int cb = 0; cb < 2; ++cb)
                    af[cb] = *(const bf16x8*)(w_t + (tap * 32 + cb * 16 + l15) * 40 + ch * 8);
#pragma unroll
                for (int yl = 0; yl < 2; ++yl) {
                    int yloc = 2 * wv + yl + ky;
#pragma unroll
                    for (int xt = 0; xt < 2; ++xt) {
                        int xloc = xt * 16 + l15 + kx;
                        bf16x8 bfv = *(const bf16x8*)(in_t + (yloc * 34 + xloc) * 40 + ch * 8);
#pragma unroll
                        for (int cb = 0; cb < 2; ++cb)
                            acc[yl][xt][cb] = __builtin_amdgcn_mfma_f32_16x16x32_bf16(
                                af[cb], bfv, acc[yl][xt][cb], 0, 0, 0);
                    }
                }
            }
    }
#pragma unroll
    for (int yl = 0; yl < 2; ++yl) {
        int gy = by * 8 + 2 * wv + yl;
#pragma unroll
        for (int xt = 0; xt < 2; ++xt) {
            int gx = bx * 32 + xt * 16 + l15;
            size_t pixo = (((size_t)bl * 128 + gy) * 128 + gx) * COUT;
#pragma unroll
            for (int cb = 0; cb < 2; ++cb) {
                int co = co0 + cb * 16 + ch * 4;
                ushort4 o;
#pragma unroll
                for (int r = 0; r < 4; ++r) {
                    float v = acc[yl][xt][cb][r] + bias[co + r];
                    v = fmaxf(v, 0.f);
                    if (MOUT == 2) v += mid[bg * 64 + co + r];
                    ((unsigned short*)&o)[r] = f2bf(v);
                }
                *(ushort4*)(out + pixo + co) = o;
            }
        }
    }
}

// ---------------- u2 via MFMA (co 0..2 of 16-pad) + fused MSE ----------------
__global__ __launch_bounds__(256, 3) void k_u2m(
    const unsigned short* __restrict__ h3, const unsigned short* __restrict__ wbu2,
    const float* __restrict__ u2_b, const float* __restrict__ noise,
    float* __restrict__ partial, int b0) {
    __shared__ __align__(16) unsigned short in_t[340 * 40];
    __shared__ __align__(16) unsigned short w_t[9 * 16 * 40];
    __shared__ float rs[256];
    int tid = threadIdx.x;
    int bx = blockIdx.x, by = blockIdx.y, bl = blockIdx.z;
    int bg = b0 + bl;
    int lane = tid & 63, wv = tid >> 6, l15 = lane & 15, ch = lane >> 4;

    for (int c = tid; c < 340 * 4; c += 256) {
        int cc = c & 3, pix = c >> 2;
        int xx = pix % 34, yy = pix / 34;
        int gy = by * 8 + yy - 1, gx = bx * 32 + xx - 1;
        bf16x8 v = {0, 0, 0, 0, 0, 0, 0, 0};
        if (gy >= 0 && gy < 128 && gx >= 0 && gx < 128)
            v = *(const bf16x8*)(h3 + (((size_t)bl * 128 + gy) * 128 + gx) * 32 + cc * 8);
        *(bf16x8*)(in_t + pix * 40 + cc * 8) = v;
    }
    for (int c = tid; c < 9 * 16 * 4; c += 256) {
        int cc = c & 3, row = c >> 2;
        bf16x8 v = *(const bf16x8*)(wbu2 + (size_t)row * 32 + cc * 8);
        *(bf16x8*)(w_t + row * 40 + cc * 8) = v;
    }
    __syncthreads();

    f32x4 acc[2][2];
    f32x4 zf = {0.f, 0.f, 0.f, 0.f};
    acc[0][0] = zf; acc[0][1] = zf; acc[1][0] = zf; acc[1][1] = zf;
#pragma unroll
    for (int ky = 0; ky < 3; ++ky)
#pragma unroll
        for (int kx = 0; kx < 3; ++kx) {
            int tap = ky * 3 + kx;
            bf16x8 af = *(const bf16x8*)(w_t + (tap * 16 + l15) * 40 + ch * 8);
#pragma unroll
            for (int yl = 0; yl < 2; ++yl) {
                int yloc = 2 * wv + yl + ky;
#pragma unroll
                for (int xt = 0; xt < 2; ++xt) {
                    int xloc = xt * 16 + l15 + kx;
                    bf16x8 bfv = *(const bf16x8*)(in_t + (yloc * 34 + xloc) * 40 + ch * 8);
                    acc[yl][xt] = __builtin_amdgcn_mfma_f32_16x16x32_bf16(af, bfv, acc[yl][xt], 0, 0, 0);
                }
            }
        }
    // lane (l15, ch) holds px col=l15, rows co = ch*4+r; only co<3 valid
    float ss = 0.f;
    if (ch == 0) {
#pragma unroll
        for (int yl = 0; yl < 2; ++yl) {
            int gy = by * 8 + 2 * wv + yl;
#pragma unroll
            for (int xt = 0; xt < 2; ++xt) {
                int gx = bx * 32 + xt * 16 + l15;
#pragma unroll
                for (int r = 0; r < 3; ++r) {
                    float v = acc[yl][xt][r] + u2_b[r];
                    float d = v - noise[(((size_t)bg * 3 + r) * 128 + gy) * 128 + gx];
                    ss += d * d;
                }
            }
        }
    }
    rs[tid] = ss;
    __syncthreads();
    for (int s = 128; s > 0; s >>= 1) {
        if (tid < s) rs[tid] += rs[tid + s];
        __syncthreads();
    }
    if (tid == 0) partial[bg * 64 + by * 4 + bx] = rs[0];
}

// ---------------- final MSE reduction ----------------
__global__ void k_final(const float* __restrict__ partial, float* __restrict__ out) {
    __shared__ float rs[256];
    int tid = threadIdx.x;
    float s = 0.f;
    for (int i = tid; i < 4096; i += 256) s += partial[i];
    rs[tid] = s;
    __syncthreads();
    for (int st = 128; st > 0; st >>= 1) {
        if (tid < st) rs[tid] += rs[tid + st];
        __syncthreads();
    }
    if (tid == 0) out[0] = rs[0] / 3145728.0f;
}

extern "C" void kernel_launch(void* const* d_in, const int* in_sizes, int n_in,
                              void* d_out, int out_size, void* d_ws, size_t ws_size,
                              hipStream_t stream) {
    const float* cond   = (const float*)d_in[0];
    const float* tgt    = (const float*)d_in[1];
    const float* noise  = (const float*)d_in[2];
    const int*   t      = (const int*)d_in[3];
    const float* enc_w  = (const float*)d_in[4];
    const float* enc_b  = (const float*)d_in[5];
    const float* in_w   = (const float*)d_in[6];
    const float* in_b   = (const float*)d_in[7];
    const float* out_w  = (const float*)d_in[8];
    const float* out_b  = (const float*)d_in[9];
    const float* ff1_w  = (const float*)d_in[10];
    const float* ff1_b  = (const float*)d_in[11];
    const float* ff2_w  = (const float*)d_in[12];
    const float* ff2_b  = (const float*)d_in[13];
    const float* ln1_g  = (const float*)d_in[14];
    const float* ln1_b  = (const float*)d_in[15];
    const float* ln2_g  = (const float*)d_in[16];
    const float* ln2_b  = (const float*)d_in[17];
    const float* d1_w   = (const float*)d_in[18];
    const float* d1_b   = (const float*)d_in[19];
    const float* d2_w   = (const float*)d_in[20];
    const float* d2_b   = (const float*)d_in[21];
    const float* mid_w  = (const float*)d_in[22];
    const float* mid_b  = (const float*)d_in[23];
    const float* u1_w   = (const float*)d_in[24];
    const float* u1_b   = (const float*)d_in[25];
    const float* u2_w   = (const float*)d_in[26];
    const float* u2_b   = (const float*)d_in[27];

    float* ws = (float*)d_ws;
    // control region: 131072 floats
    float* sab     = ws;                    // 64
    float* snab    = ws + 64;               // 64
    float* x0      = ws + 128;              // 8192
    float* mid     = ws + 16512;            // 4096
    float* encpart = ws + 20608;            // 65536
    float* msepart = ws + 86144;            // 4096
    unsigned short* wb2  = (unsigned short*)(ws + 90240);   // 18432 bf16
    unsigned short* wbu1 = (unsigned short*)(ws + 99456);   // 18432 bf16
    unsigned short* wbu2 = (unsigned short*)(ws + 108672);  // 4608 bf16

    // chunk: NB images of bf16 h2(64ch) + h3(32ch) = NB*786432 f32-slots
    const size_t SMALL = 131072;
    size_t avail = (ws_size / 4 > SMALL) ? (ws_size / 4 - SMALL) : 0;
    int NB = 1;
    const int cands[7] = {64, 32, 16, 8, 4, 2, 1};
    for (int ci = 0; ci < 7; ++ci) {
        if ((size_t)cands[ci] * 786432ull <= avail) { NB = cands[ci]; break; }
    }
    unsigned short* hb2 = (unsigned short*)(ws + SMALL);
    unsigned short* hb3 = (unsigned short*)(ws + SMALL + (size_t)NB * 524288ull);

    k_alpha<<<1, 64, 0, stream>>>(t, sab, snab);
    k_prep_cw<<<72, 256, 0, stream>>>(d2_w, wb2, 64, 32);
    k_prep_cw<<<72, 256, 0, stream>>>(u1_w, wbu1, 32, 64);
    k_prep_u2<<<18, 256, 0, stream>>>(u2_w, wbu2);
    k_enc_gemm<<<dim3(8, 4, KSEG), 256, 0, stream>>>(cond, enc_w, encpart);
    k_enc_reduce<<<32, 256, 0, stream>>>(encpart, enc_b, x0);
    k_tf_layer<<<64, 1024, 0, stream>>>(x0, in_w, in_b, out_w, out_b, ff1_w, ff1_b,
                                        ff2_w, ff2_b, ln1_g, ln1_b, ln2_g, ln2_b, 0);
    k_tf_layer<<<64, 1024, 0, stream>>>(x0, in_w, in_b, out_w, out_b, ff1_w, ff1_b,
                                        ff2_w, ff2_b, ln1_g, ln1_b, ln2_g, ln2_b, 1);
    k_mid<<<64, 64, 0, stream>>>(x0, mid_w, mid_b, mid);

    for (int cb = 0; cb < 64; cb += NB) {
        k_fuseA<<<dim3(4, 16, NB * 2), 256, 0, stream>>>(
            tgt, noise, sab, snab, d1_w, d1_b, wb2, d2_b, mid, hb2, cb);
        k_convM<64, 32, 1><<<dim3(4, 16, NB), 256, 0, stream>>>(
            hb2, wbu1, u1_b, nullptr, hb3, cb);
        k_u2m<<<dim3(4, 16, NB), 256, 0, stream>>>(
            hb3, wbu2, u2_b, noise, msepart, cb);
    }

    k_final<<<1, 256, 0, stream>>>(msepart, (float*)d_out);
}

// Round 7
// 622.751 us; speedup vs baseline: 6.0164x; 1.2706x over previous
//
#include <hip/hip_runtime.h>
#include <math.h>

#define ENC_K 49152
#define KSEG 8
#define KLEN (ENC_K / KSEG)   // 6144

typedef __attribute__((ext_vector_type(8))) short bf16x8;
typedef __attribute__((ext_vector_type(4))) float f32x4;

__device__ inline unsigned short f2bf(float f) {
    unsigned int u = __builtin_bit_cast(unsigned int, f);
    unsigned int r = u + 0x7fffu + ((u >> 16) & 1u);
    return (unsigned short)(r >> 16);
}
__device__ inline float bf2f(unsigned short h) {
    return __builtin_bit_cast(float, ((unsigned int)h) << 16);
}
__device__ inline float dot4(const float4 a, const float4 b) {
    return a.x * b.x + a.y * b.y + a.z * b.z + a.w * b.w;
}

// ---------------- alpha_bar per batch ----------------
__global__ void k_alpha(const int* __restrict__ t, float* __restrict__ sab, float* __restrict__ snab) {
    int b = threadIdx.x;
    if (b < 64) {
        int tb = t[b];
        const float step = (0.02f - 1e-4f) / 999.0f;
        float ab = 1.0f;
        for (int i = 0; i <= tb; ++i) {
            float beta = 1e-4f + step * (float)i;
            ab *= (1.0f - beta);
        }
        sab[b] = sqrtf(ab);
        snab[b] = sqrtf(1.0f - ab);
    }
}

// ---------------- conv weight prep: f32 [CO][CI][3][3] -> bf16 [tap][CO][CI] ----------------
__global__ void k_prep_cw(const float* __restrict__ w, unsigned short* __restrict__ out, int CO, int CI) {
    int idx = blockIdx.x * 256 + threadIdx.x;
    int total = CO * CI * 9;
    if (idx < total) {
        int tap = idx / (CO * CI);
        int rem = idx % (CO * CI);
        int co = rem / CI, ci = rem % CI;
        out[idx] = f2bf(w[((size_t)co * CI + ci) * 9 + tap]);
    }
}

// u2 weights: f32 [3][32][3][3] -> bf16 [tap][16 co(pad)][32 ci], co>=3 zero
__global__ void k_prep_u2(const float* __restrict__ w, unsigned short* __restrict__ out) {
    int idx = blockIdx.x * 256 + threadIdx.x;
    if (idx < 9 * 16 * 32) {
        int tap = idx / 512;
        int rem = idx % 512;
        int co = rem / 32, ci = rem % 32;
        out[idx] = (co < 3) ? f2bf(w[((size_t)co * 32 + ci) * 9 + tap]) : (unsigned short)0;
    }
}

// ---------------- encoder GEMM: x0 = cond @ W^T (K-split partials) ----------------
__global__ void k_enc_gemm(const float* __restrict__ cond, const float* __restrict__ w,
                           float* __restrict__ partial) {
    __shared__ float As[16][68];
    __shared__ float Ws[16][68];
    int tid = threadIdx.x;
    int j = tid & 15, i = tid >> 4;
    int d0 = blockIdx.x * 16, b0 = blockIdx.y * 16;
    int k0 = blockIdx.z * KLEN;
    float acc = 0.f;
    for (int kk = 0; kk < KLEN; kk += 64) {
        for (int idx = tid; idx < 1024; idx += 256) {
            int r = idx >> 6, c = idx & 63;
            As[r][c] = cond[(size_t)(b0 + r) * ENC_K + k0 + kk + c];
            Ws[r][c] = w[(size_t)(d0 + r) * ENC_K + k0 + kk + c];
        }
        __syncthreads();
        const float4* a4 = (const float4*)&As[i][0];
        const float4* w4 = (const float4*)&Ws[j][0];
#pragma unroll
        for (int k = 0; k < 16; ++k) acc += dot4(a4[k], w4[k]);
        __syncthreads();
    }
    partial[((size_t)blockIdx.z * 64 + b0 + i) * 128 + d0 + j] = acc;
}

__global__ void k_enc_reduce(const float* __restrict__ partial, const float* __restrict__ bias,
                             float* __restrict__ x0) {
    int idx = blockIdx.x * 256 + threadIdx.x;  // 8192 total
    float s = bias[idx & 127];
    for (int ks = 0; ks < KSEG; ++ks) s += partial[(size_t)ks * 8192 + idx];
    x0[idx] = s;
}

// ---------------- transformer layer (seq_len 1), one block per batch row ----------------
__device__ float sum128(float v, int tid, float* red) {
    if (tid < 128) red[tid] = v;
    __syncthreads();
    if (tid < 64) red[tid] += red[tid + 64]; __syncthreads();
    if (tid < 32) red[tid] += red[tid + 32]; __syncthreads();
    if (tid < 16) red[tid] += red[tid + 16]; __syncthreads();
    if (tid < 8)  red[tid] += red[tid + 8];  __syncthreads();
    if (tid < 4)  red[tid] += red[tid + 4];  __syncthreads();
    if (tid < 2)  red[tid] += red[tid + 2];  __syncthreads();
    if (tid < 1)  red[tid] += red[tid + 1];  __syncthreads();
    float s = red[0];
    __syncthreads();
    return s;
}

__global__ __launch_bounds__(1024) void k_tf_layer(
    float* __restrict__ xs,
    const float* __restrict__ in_w, const float* __restrict__ in_b,
    const float* __restrict__ out_w, const float* __restrict__ out_b,
    const float* __restrict__ ff1_w, const float* __restrict__ ff1_b,
    const float* __restrict__ ff2_w, const float* __restrict__ ff2_b,
    const float* __restrict__ ln1_g, const float* __restrict__ ln1_b,
    const float* __restrict__ ln2_g, const float* __restrict__ ln2_b, int L) {
    __shared__ float xr[128], vr[128], tp[8][128], f1s[2048], red[128];
    int b = blockIdx.x, tid = threadIdx.x;
    if (tid < 128) xr[tid] = xs[b * 128 + tid];
    __syncthreads();
    if (tid < 512) {
        int d = tid & 127, s = tid >> 7;
        const float4* w = (const float4*)(in_w + ((size_t)L * 384 + 256 + d) * 128) + s * 8;
        const float4* x4 = (const float4*)xr + s * 8;
        float p = 0.f;
#pragma unroll
        for (int k = 0; k < 8; ++k) p += dot4(x4[k], w[k]);
        tp[s][d] = p;
    }
    __syncthreads();
    if (tid < 128) vr[tid] = in_b[L * 384 + 256 + tid] + tp[0][tid] + tp[1][tid] + tp[2][tid] + tp[3][tid];
    __syncthreads();
    if (tid < 512) {
        int d = tid & 127, s = tid >> 7;
        const float4* w = (const float4*)(out_w + ((size_t)L * 128 + d) * 128) + s * 8;
        const float4* v4 = (const float4*)vr + s * 8;
        float p = 0.f;
#pragma unroll
        for (int k = 0; k < 8; ++k) p += dot4(v4[k], w[k]);
        tp[s][d] = p;
    }
    __syncthreads();
    float y = 0.f;
    if (tid < 128) y = xr[tid] + out_b[L * 128 + tid] + tp[0][tid] + tp[1][tid] + tp[2][tid] + tp[3][tid];
    float m1 = sum128(y, tid, red) * (1.f / 128.f);
    float c1 = y - m1;
    float v1 = sum128(c1 * c1, tid, red) * (1.f / 128.f);
    __syncthreads();
    if (tid < 128) xr[tid] = c1 * rsqrtf(v1 + 1e-5f) * ln1_g[L * 128 + tid] + ln1_b[L * 128 + tid];
    __syncthreads();
    {
        const float4* x4 = (const float4*)xr;
#pragma unroll
        for (int jj = 0; jj < 2; ++jj) {
            int j = tid + jj * 1024;
            const float4* w = (const float4*)(ff1_w + ((size_t)L * 2048 + j) * 128);
            float p = ff1_b[L * 2048 + j];
#pragma unroll 8
            for (int k = 0; k < 32; ++k) p += dot4(x4[k], w[k]);
            f1s[j] = fmaxf(p, 0.f);
        }
    }
    __syncthreads();
    {
        int d = tid & 127, s = tid >> 7;
        const float4* w = (const float4*)(ff2_w + ((size_t)L * 128 + d) * 2048 + s * 256);
        const float4* f4 = (const float4*)f1s + s * 64;
        float p = 0.f;
#pragma unroll 8
        for (int k = 0; k < 64; ++k) p += dot4(f4[k], w[k]);
        tp[s][d] = p;
    }
    __syncthreads();
    float y2 = 0.f;
    if (tid < 128) {
        y2 = xr[tid] + ff2_b[L * 128 + tid];
#pragma unroll
        for (int s = 0; s < 8; ++s) y2 += tp[s][tid];
    }
    float m2 = sum128(y2, tid, red) * (1.f / 128.f);
    float c2 = y2 - m2;
    float v2 = sum128(c2 * c2, tid, red) * (1.f / 128.f);
    if (tid < 128) xs[b * 128 + tid] = c2 * rsqrtf(v2 + 1e-5f) * ln2_g[L * 128 + tid] + ln2_b[L * 128 + tid];
}

// ---------------- mid projection ----------------
__global__ void k_mid(const float* __restrict__ xe, const float* __restrict__ mid_w,
                      const float* __restrict__ mid_b, float* __restrict__ mid) {
    int b = blockIdx.x, c = threadIdx.x;  // 64 threads
    float s = mid_b[c];
    const float* xr = xe + b * 128;
    const float* wr = mid_w + c * 128;
    for (int k = 0; k < 128; ++k) s += xr[k] * wr[k];
    mid[b * 64 + c] = s;
}

// ---------------- conv1: 3->32 direct f32, fused q_sample, relu, out bf16 NHWC ----------------
__global__ __launch_bounds__(256, 4) void k_conv1(
    const float* __restrict__ tgt, const float* __restrict__ noise,
    const float* __restrict__ sab, const float* __restrict__ snab,
    const float* __restrict__ wgt, const float* __restrict__ bias,
    unsigned short* __restrict__ h1, int b0) {
    __shared__ float it[3][34][35];
    __shared__ float wt[8][3][9];
    int tid = threadIdx.x;
    int tx = tid & 7, ty = tid >> 3;
    int bx = blockIdx.x, by = blockIdx.y;
    int bl = blockIdx.z >> 2, g = blockIdx.z & 3;
    int bg = b0 + bl, co0 = g * 8;
    float za = sab[bg], zb = snab[bg];
    for (int idx = tid; idx < 3 * 34 * 34; idx += 256) {
        int c = idx / 1156, rem = idx % 1156;
        int yy = rem / 34, xx = rem % 34;
        int gy = by * 32 + yy - 1, gx = bx * 32 + xx - 1;
        float v = 0.f;
        if (gy >= 0 && gy < 128 && gx >= 0 && gx < 128) {
            size_t off = (((size_t)bg * 3 + c) * 128 + gy) * 128 + gx;
            v = za * tgt[off] + zb * noise[off];
        }
        it[c][yy][xx] = v;
    }
    for (int idx = tid; idx < 8 * 27; idx += 256) {
        int co = idx / 27, rem = idx % 27;
        wt[co][rem / 9][rem % 9] = wgt[(size_t)(co0 + co) * 27 + rem];
    }
    __syncthreads();
    float acc[8][4];
#pragma unroll
    for (int co = 0; co < 8; ++co)
#pragma unroll
        for (int p = 0; p < 4; ++p) acc[co][p] = 0.f;
#pragma unroll
    for (int c = 0; c < 3; ++c)
#pragma unroll
        for (int ky = 0; ky < 3; ++ky) {
            float win[6];
#pragma unroll
            for (int i = 0; i < 6; ++i) win[i] = it[c][ty + ky][tx * 4 + i];
#pragma unroll
            for (int kx = 0; kx < 3; ++kx)
#pragma unroll
                for (int co = 0; co < 8; ++co) {
                    float w = wt[co][c][ky * 3 + kx];
#pragma unroll
                    for (int p = 0; p < 4; ++p) acc[co][p] += win[kx + p] * w;
                }
        }
    int gy = by * 32 + ty, gx0 = bx * 32 + tx * 4;
#pragma unroll
    for (int p = 0; p < 4; ++p) {
        ushort4 oa, ob;
#pragma unroll
        for (int co = 0; co < 4; ++co)
            ((unsigned short*)&oa)[co] = f2bf(fmaxf(acc[co][p] + bias[co0 + co], 0.f));
#pragma unroll
        for (int co = 0; co < 4; ++co)
            ((unsigned short*)&ob)[co] = f2bf(fmaxf(acc[co + 4][p] + bias[co0 + co + 4], 0.f));
        size_t o = (((size_t)bl * 128 + gy) * 128 + gx0 + p) * 32 + co0;
        *(ushort4*)(h1 + o) = oa;
        *(ushort4*)(h1 + o + 4) = ob;
    }
}

// ---------------- MFMA 3x3 conv: bf16 NHWC in/out, f32 accum ----------------
// Block: 32x x 8y output px, COB*16 out-chans per block. 256 thr = 4 waves.
// MOUT: 1 = relu; 2 = relu then +mid
template <int CIN, int COB, int COUT, int MOUT>
__global__ __launch_bounds__(256, 2) void k_convMg(
    const unsigned short* __restrict__ in, const unsigned short* __restrict__ wb,
    const float* __restrict__ bias, const float* __restrict__ mid,
    unsigned short* __restrict__ out, int b0) {
    const int GROUPS = COUT / (16 * COB);
    __shared__ __align__(16) unsigned short in_t[10 * 34 * 40];
    __shared__ __align__(16) unsigned short w_t[9 * COB * 16 * 40];
    int tid = threadIdx.x;
    int bx = blockIdx.x, by = blockIdx.y;
    int bl = blockIdx.z / GROUPS, g = blockIdx.z % GROUPS;
    int bg = b0 + bl;
    int co0 = g * COB * 16;
    int lane = tid & 63, wv = tid >> 6;
    int l15 = lane & 15, ch = lane >> 4;

    f32x4 acc[2][2][COB];
    f32x4 zf = {0.f, 0.f, 0.f, 0.f};
#pragma unroll
    for (int a = 0; a < 2; ++a)
#pragma unroll
        for (int bq = 0; bq < 2; ++bq)
#pragma unroll
            for (int c = 0; c < COB; ++c) acc[a][bq][c] = zf;

    for (int cs = 0; cs < CIN / 32; ++cs) {
        if (cs) __syncthreads();
        for (int c = tid; c < 10 * 34 * 4; c += 256) {
            int cc = c & 3, pix = c >> 2;
            int xx = pix % 34, yy = pix / 34;
            int gy = by * 8 + yy - 1, gx = bx * 32 + xx - 1;
            bf16x8 v = {0, 0, 0, 0, 0, 0, 0, 0};
            if (gy >= 0 && gy < 128 && gx >= 0 && gx < 128)
                v = *(const bf16x8*)(in + (((size_t)bl * 128 + gy) * 128 + gx) * CIN + cs * 32 + cc * 8);
            *(bf16x8*)(in_t + pix * 40 + cc * 8) = v;
        }
        for (int c = tid; c < 9 * COB * 16 * 4; c += 256) {
            int cc = c & 3, row = c >> 2;
            int tap = row / (COB * 16), co = row % (COB * 16);
            bf16x8 v = *(const bf16x8*)(wb + ((size_t)(tap * COUT + co0 + co)) * CIN + cs * 32 + cc * 8);
            *(bf16x8*)(w_t + row * 40 + cc * 8) = v;
        }
        __syncthreads();
#pragma unroll
        for (int ky = 0; ky < 3; ++ky)
#pragma unroll
            for (int kx = 0; kx < 3; ++kx) {
                int tap = ky * 3 + kx;
                bf16x8 af[COB];
#pragma unroll
                for (int cb = 0; cb < COB; ++cb)
                    af[cb] = *(const bf16x8*)(w_t + (tap * COB * 16 + cb * 16 + l15) * 40 + ch * 8);
#pragma unroll
                for (int yl = 0; yl < 2; ++yl) {
                    int yloc = 2 * wv + yl + ky;
#pragma unroll
                    for (int xt = 0; xt < 2; ++xt) {
                        int xloc = xt * 16 + l15 + kx;
                        bf16x8 bfv = *(const bf16x8*)(in_t + (yloc * 34 + xloc) * 40 + ch * 8);
#pragma unroll
                        for (int cb = 0; cb < COB; ++cb)
                            acc[yl][xt][cb] = __builtin_amdgcn_mfma_f32_16x16x32_bf16(
                                af[cb], bfv, acc[yl][xt][cb], 0, 0, 0);
                    }
                }
            }
    }
#pragma unroll
    for (int yl = 0; yl < 2; ++yl) {
        int gy = by * 8 + 2 * wv + yl;
#pragma unroll
        for (int xt = 0; xt < 2; ++xt) {
            int gx = bx * 32 + xt * 16 + l15;
            size_t pixo = (((size_t)bl * 128 + gy) * 128 + gx) * COUT;
#pragma unroll
            for (int cb = 0; cb < COB; ++cb) {
                int co = co0 + cb * 16 + ch * 4;
                ushort4 o;
#pragma unroll
                for (int r = 0; r < 4; ++r) {
                    float v = acc[yl][xt][cb][r] + bias[co + r];
                    v = fmaxf(v, 0.f);
                    if (MOUT == 2) v += mid[bg * 64 + co + r];
                    ((unsigned short*)&o)[r] = f2bf(v);
                }
                *(ushort4*)(out + pixo + co) = o;
            }
        }
    }
}

// ---------------- u2 via MFMA (co 0..2 of 16-pad) + fused MSE ----------------
__global__ __launch_bounds__(256, 3) void k_u2m(
    const unsigned short* __restrict__ h3, const unsigned short* __restrict__ wbu2,
    const float* __restrict__ u2_b, const float* __restrict__ noise,
    float* __restrict__ partial, int b0) {
    __shared__ __align__(16) unsigned short in_t[340 * 40];
    __shared__ __align__(16) unsigned short w_t[9 * 16 * 40];
    __shared__ float rs[256];
    int tid = threadIdx.x;
    int bx = blockIdx.x, by = blockIdx.y, bl = blockIdx.z;
    int bg = b0 + bl;
    int lane = tid & 63, wv = tid >> 6, l15 = lane & 15, ch = lane >> 4;

    for (int c = tid; c < 340 * 4; c += 256) {
        int cc = c & 3, pix = c >> 2;
        int xx = pix % 34, yy = pix / 34;
        int gy = by * 8 + yy - 1, gx = bx * 32 + xx - 1;
        bf16x8 v = {0, 0, 0, 0, 0, 0, 0, 0};
        if (gy >= 0 && gy < 128 && gx >= 0 && gx < 128)
            v = *(const bf16x8*)(h3 + (((size_t)bl * 128 + gy) * 128 + gx) * 32 + cc * 8);
        *(bf16x8*)(in_t + pix * 40 + cc * 8) = v;
    }
    for (int c = tid; c < 9 * 16 * 4; c += 256) {
        int cc = c & 3, row = c >> 2;
        bf16x8 v = *(const bf16x8*)(wbu2 + (size_t)row * 32 + cc * 8);
        *(bf16x8*)(w_t + row * 40 + cc * 8) = v;
    }
    __syncthreads();

    f32x4 acc[2][2];
    f32x4 zf = {0.f, 0.f, 0.f, 0.f};
    acc[0][0] = zf; acc[0][1] = zf; acc[1][0] = zf; acc[1][1] = zf;
#pragma unroll
    for (int ky = 0; ky < 3; ++ky)
#pragma unroll
        for (int kx = 0; kx < 3; ++kx) {
            int tap = ky * 3 + kx;
            bf16x8 af = *(const bf16x8*)(w_t + (tap * 16 + l15) * 40 + ch * 8);
#pragma unroll
            for (int yl = 0; yl < 2; ++yl) {
                int yloc = 2 * wv + yl + ky;
#pragma unroll
                for (int xt = 0; xt < 2; ++xt) {
                    int xloc = xt * 16 + l15 + kx;
                    bf16x8 bfv = *(const bf16x8*)(in_t + (yloc * 34 + xloc) * 40 + ch * 8);
                    acc[yl][xt] = __builtin_amdgcn_mfma_f32_16x16x32_bf16(af, bfv, acc[yl][xt], 0, 0, 0);
                }
            }
        }
    float ss = 0.f;
    if (ch == 0) {
#pragma unroll
        for (int yl = 0; yl < 2; ++yl) {
            int gy = by * 8 + 2 * wv + yl;
#pragma unroll
            for (int xt = 0; xt < 2; ++xt) {
                int gx = bx * 32 + xt * 16 + l15;
#pragma unroll
                for (int r = 0; r < 3; ++r) {
                    float v = acc[yl][xt][r] + u2_b[r];
                    float d = v - noise[(((size_t)bg * 3 + r) * 128 + gy) * 128 + gx];
                    ss += d * d;
                }
            }
        }
    }
    rs[tid] = ss;
    __syncthreads();
    for (int s = 128; s > 0; s >>= 1) {
        if (tid < s) rs[tid] += rs[tid + s];
        __syncthreads();
    }
    if (tid == 0) partial[bg * 64 + by * 4 + bx] = rs[0];
}

// ---------------- final MSE reduction ----------------
__global__ void k_final(const float* __restrict__ partial, float* __restrict__ out) {
    __shared__ float rs[256];
    int tid = threadIdx.x;
    float s = 0.f;
    for (int i = tid; i < 4096; i += 256) s += partial[i];
    rs[tid] = s;
    __syncthreads();
    for (int st = 128; st > 0; st >>= 1) {
        if (tid < st) rs[tid] += rs[tid + st];
        __syncthreads();
    }
    if (tid == 0) out[0] = rs[0] / 3145728.0f;
}

extern "C" void kernel_launch(void* const* d_in, const int* in_sizes, int n_in,
                              void* d_out, int out_size, void* d_ws, size_t ws_size,
                              hipStream_t stream) {
    const float* cond   = (const float*)d_in[0];
    const float* tgt    = (const float*)d_in[1];
    const float* noise  = (const float*)d_in[2];
    const int*   t      = (const int*)d_in[3];
    const float* enc_w  = (const float*)d_in[4];
    const float* enc_b  = (const float*)d_in[5];
    const float* in_w   = (const float*)d_in[6];
    const float* in_b   = (const float*)d_in[7];
    const float* out_w  = (const float*)d_in[8];
    const float* out_b  = (const float*)d_in[9];
    const float* ff1_w  = (const float*)d_in[10];
    const float* ff1_b  = (const float*)d_in[11];
    const float* ff2_w  = (const float*)d_in[12];
    const float* ff2_b  = (const float*)d_in[13];
    const float* ln1_g  = (const float*)d_in[14];
    const float* ln1_b  = (const float*)d_in[15];
    const float* ln2_g  = (const float*)d_in[16];
    const float* ln2_b  = (const float*)d_in[17];
    const float* d1_w   = (const float*)d_in[18];
    const float* d1_b   = (const float*)d_in[19];
    const float* d2_w   = (const float*)d_in[20];
    const float* d2_b   = (const float*)d_in[21];
    const float* mid_w  = (const float*)d_in[22];
    const float* mid_b  = (const float*)d_in[23];
    const float* u1_w   = (const float*)d_in[24];
    const float* u1_b   = (const float*)d_in[25];
    const float* u2_w   = (const float*)d_in[26];
    const float* u2_b   = (const float*)d_in[27];

    float* ws = (float*)d_ws;
    // control region: 131072 floats
    float* sab     = ws;                    // 64
    float* snab    = ws + 64;               // 64
    float* x0      = ws + 128;              // 8192
    float* mid     = ws + 16512;            // 4096
    float* encpart = ws + 20608;            // 65536
    float* msepart = ws + 86144;            // 4096
    unsigned short* wb2  = (unsigned short*)(ws + 90240);   // 18432 bf16
    unsigned short* wbu1 = (unsigned short*)(ws + 99456);   // 18432 bf16
    unsigned short* wbu2 = (unsigned short*)(ws + 108672);  // 4608 bf16

    // chunk: NB images of bf16 h1(32) + h2(64) + h3(32) = NB*1048576 f32-slots
    const size_t SMALL = 131072;
    size_t avail = (ws_size / 4 > SMALL) ? (ws_size / 4 - SMALL) : 0;
    int NB = 1;
    const int cands[7] = {64, 32, 16, 8, 4, 2, 1};
    for (int ci = 0; ci < 7; ++ci) {
        if ((size_t)cands[ci] * 1048576ull <= avail) { NB = cands[ci]; break; }
    }
    unsigned short* hb1 = (unsigned short*)(ws + SMALL);
    unsigned short* hb2 = (unsigned short*)(ws + SMALL + (size_t)NB * 262144ull);
    unsigned short* hb3 = (unsigned short*)(ws + SMALL + (size_t)NB * 786432ull);

    k_alpha<<<1, 64, 0, stream>>>(t, sab, snab);
    k_prep_cw<<<72, 256, 0, stream>>>(d2_w, wb2, 64, 32);
    k_prep_cw<<<72, 256, 0, stream>>>(u1_w, wbu1, 32, 64);
    k_prep_u2<<<18, 256, 0, stream>>>(u2_w, wbu2);
    k_enc_gemm<<<dim3(8, 4, KSEG), 256, 0, stream>>>(cond, enc_w, encpart);
    k_enc_reduce<<<32, 256, 0, stream>>>(encpart, enc_b, x0);
    k_tf_layer<<<64, 1024, 0, stream>>>(x0, in_w, in_b, out_w, out_b, ff1_w, ff1_b,
                                        ff2_w, ff2_b, ln1_g, ln1_b, ln2_g, ln2_b, 0);
    k_tf_layer<<<64, 1024, 0, stream>>>(x0, in_w, in_b, out_w, out_b, ff1_w, ff1_b,
                                        ff2_w, ff2_b, ln1_g, ln1_b, ln2_g, ln2_b, 1);
    k_mid<<<64, 64, 0, stream>>>(x0, mid_w, mid_b, mid);

    for (int cb = 0; cb < 64; cb += NB) {
        // conv1: 3->32 direct f32, q_sample fused, out bf16 NHWC
        k_conv1<<<dim3(4, 4, NB * 4), 256, 0, stream>>>(
            tgt, noise, sab, snab, d1_w, d1_b, hb1, cb);
        // conv2: 32->64 MFMA, all 64 co per block, relu + mid
        k_convMg<32, 4, 64, 2><<<dim3(4, 16, NB), 256, 0, stream>>>(
            hb1, wb2, d2_b, mid, hb2, cb);
        // u1: 64->32 MFMA, relu
        k_convMg<64, 2, 32, 1><<<dim3(4, 16, NB), 256, 0, stream>>>(
            hb2, wbu1, u1_b, nullptr, hb3, cb);
        // u2: 32->3 MFMA + fused MSE
        k_u2m<<<dim3(4, 16, NB), 256, 0, stream>>>(
            hb3, wbu2, u2_b, noise, msepart, cb);
    }

    k_final<<<1, 256, 0, stream>>>(msepart, (float*)d_out);
}

// Round 8
// 509.339 us; speedup vs baseline: 7.3560x; 1.2227x over previous
//
#include <hip/hip_runtime.h>
#include <math.h>

#define ENC_K 49152
#define KSEG 64
#define KLEN (ENC_K / KSEG)   // 768

typedef __attribute__((ext_vector_type(8))) short bf16x8;
typedef __attribute__((ext_vector_type(4))) float f32x4;

__device__ inline unsigned short f2bf(float f) {
    unsigned int u = __builtin_bit_cast(unsigned int, f);
    unsigned int r = u + 0x7fffu + ((u >> 16) & 1u);
    return (unsigned short)(r >> 16);
}
__device__ inline float bf2f(unsigned short h) {
    return __builtin_bit_cast(float, ((unsigned int)h) << 16);
}
__device__ inline float dot4(const float4 a, const float4 b) {
    return a.x * b.x + a.y * b.y + a.z * b.z + a.w * b.w;
}

// ---------------- alpha_bar per batch ----------------
__global__ void k_alpha(const int* __restrict__ t, float* __restrict__ sab, float* __restrict__ snab) {
    int b = threadIdx.x;
    if (b < 64) {
        int tb = t[b];
        const float step = (0.02f - 1e-4f) / 999.0f;
        float ab = 1.0f;
        for (int i = 0; i <= tb; ++i) {
            float beta = 1e-4f + step * (float)i;
            ab *= (1.0f - beta);
        }
        sab[b] = sqrtf(ab);
        snab[b] = sqrtf(1.0f - ab);
    }
}

// ---------------- conv weight prep: f32 [CO][CI][3][3] -> bf16 [tap][CO][CI] ----------------
__global__ void k_prep_cw(const float* __restrict__ w, unsigned short* __restrict__ out, int CO, int CI) {
    int idx = blockIdx.x * 256 + threadIdx.x;
    int total = CO * CI * 9;
    if (idx < total) {
        int tap = idx / (CO * CI);
        int rem = idx % (CO * CI);
        int co = rem / CI, ci = rem % CI;
        out[idx] = f2bf(w[((size_t)co * CI + ci) * 9 + tap]);
    }
}

// u2 weights: f32 [3][32][3][3] -> bf16 [tap][16 co(pad)][32 ci], co>=3 zero
__global__ void k_prep_u2(const float* __restrict__ w, unsigned short* __restrict__ out) {
    int idx = blockIdx.x * 256 + threadIdx.x;
    if (idx < 9 * 16 * 32) {
        int tap = idx / 512;
        int rem = idx % 512;
        int co = rem / 32, ci = rem % 32;
        out[idx] = (co < 3) ? f2bf(w[((size_t)co * 32 + ci) * 9 + tap]) : (unsigned short)0;
    }
}

// ---------------- encoder GEMM: x0 = cond @ W^T (K-split partials) ----------------
__global__ void k_enc_gemm(const float* __restrict__ cond, const float* __restrict__ w,
                           float* __restrict__ partial) {
    __shared__ float As[16][68];
    __shared__ float Ws[16][68];
    int tid = threadIdx.x;
    int j = tid & 15, i = tid >> 4;
    int d0 = blockIdx.x * 16, b0 = blockIdx.y * 16;
    int k0 = blockIdx.z * KLEN;
    float a0 = 0.f, a1 = 0.f, a2 = 0.f, a3 = 0.f;
    for (int kk = 0; kk < KLEN; kk += 64) {
        for (int idx = tid; idx < 1024; idx += 256) {
            int r = idx >> 6, c = idx & 63;
            As[r][c] = cond[(size_t)(b0 + r) * ENC_K + k0 + kk + c];
            Ws[r][c] = w[(size_t)(d0 + r) * ENC_K + k0 + kk + c];
        }
        __syncthreads();
        const float4* a4 = (const float4*)&As[i][0];
        const float4* w4 = (const float4*)&Ws[j][0];
#pragma unroll
        for (int k = 0; k < 4; ++k) {
            a0 += dot4(a4[k], w4[k]);
            a1 += dot4(a4[k + 4], w4[k + 4]);
            a2 += dot4(a4[k + 8], w4[k + 8]);
            a3 += dot4(a4[k + 12], w4[k + 12]);
        }
        __syncthreads();
    }
    partial[((size_t)blockIdx.z * 64 + b0 + i) * 128 + d0 + j] = (a0 + a1) + (a2 + a3);
}

__global__ void k_enc_reduce(const float* __restrict__ partial, const float* __restrict__ bias,
                             float* __restrict__ x0) {
    int idx = blockIdx.x * 256 + threadIdx.x;  // 8192 total
    float s = bias[idx & 127];
    for (int ks = 0; ks < KSEG; ++ks) s += partial[(size_t)ks * 8192 + idx];
    x0[idx] = s;
}

// ---------------- transformer layer (seq_len 1), one block per batch row ----------------
__device__ float sum128(float v, int tid, float* red) {
    if (tid < 128) red[tid] = v;
    __syncthreads();
    if (tid < 64) red[tid] += red[tid + 64]; __syncthreads();
    if (tid < 32) red[tid] += red[tid + 32]; __syncthreads();
    if (tid < 16) red[tid] += red[tid + 16]; __syncthreads();
    if (tid < 8)  red[tid] += red[tid + 8];  __syncthreads();
    if (tid < 4)  red[tid] += red[tid + 4];  __syncthreads();
    if (tid < 2)  red[tid] += red[tid + 2];  __syncthreads();
    if (tid < 1)  red[tid] += red[tid + 1];  __syncthreads();
    float s = red[0];
    __syncthreads();
    return s;
}

__global__ __launch_bounds__(1024) void k_tf_layer(
    float* __restrict__ xs,
    const float* __restrict__ in_w, const float* __restrict__ in_b,
    const float* __restrict__ out_w, const float* __restrict__ out_b,
    const float* __restrict__ ff1_w, const float* __restrict__ ff1_b,
    const float* __restrict__ ff2_w, const float* __restrict__ ff2_b,
    const float* __restrict__ ln1_g, const float* __restrict__ ln1_b,
    const float* __restrict__ ln2_g, const float* __restrict__ ln2_b, int L) {
    __shared__ float xr[128], vr[128], tp[8][128], f1s[2048], red[128];
    int b = blockIdx.x, tid = threadIdx.x;
    if (tid < 128) xr[tid] = xs[b * 128 + tid];
    __syncthreads();
    if (tid < 512) {
        int d = tid & 127, s = tid >> 7;
        const float4* w = (const float4*)(in_w + ((size_t)L * 384 + 256 + d) * 128) + s * 8;
        const float4* x4 = (const float4*)xr + s * 8;
        float p = 0.f;
#pragma unroll
        for (int k = 0; k < 8; ++k) p += dot4(x4[k], w[k]);
        tp[s][d] = p;
    }
    __syncthreads();
    if (tid < 128) vr[tid] = in_b[L * 384 + 256 + tid] + tp[0][tid] + tp[1][tid] + tp[2][tid] + tp[3][tid];
    __syncthreads();
    if (tid < 512) {
        int d = tid & 127, s = tid >> 7;
        const float4* w = (const float4*)(out_w + ((size_t)L * 128 + d) * 128) + s * 8;
        const float4* v4 = (const float4*)vr + s * 8;
        float p = 0.f;
#pragma unroll
        for (int k = 0; k < 8; ++k) p += dot4(v4[k], w[k]);
        tp[s][d] = p;
    }
    __syncthreads();
    float y = 0.f;
    if (tid < 128) y = xr[tid] + out_b[L * 128 + tid] + tp[0][tid] + tp[1][tid] + tp[2][tid] + tp[3][tid];
    float m1 = sum128(y, tid, red) * (1.f / 128.f);
    float c1 = y - m1;
    float v1 = sum128(c1 * c1, tid, red) * (1.f / 128.f);
    __syncthreads();
    if (tid < 128) xr[tid] = c1 * rsqrtf(v1 + 1e-5f) * ln1_g[L * 128 + tid] + ln1_b[L * 128 + tid];
    __syncthreads();
    {
        const float4* x4 = (const float4*)xr;
#pragma unroll
        for (int jj = 0; jj < 2; ++jj) {
            int j = tid + jj * 1024;
            const float4* w = (const float4*)(ff1_w + ((size_t)L * 2048 + j) * 128);
            float p = ff1_b[L * 2048 + j];
#pragma unroll 8
            for (int k = 0; k < 32; ++k) p += dot4(x4[k], w[k]);
            f1s[j] = fmaxf(p, 0.f);
        }
    }
    __syncthreads();
    {
        int d = tid & 127, s = tid >> 7;
        const float4* w = (const float4*)(ff2_w + ((size_t)L * 128 + d) * 2048 + s * 256);
        const float4* f4 = (const float4*)f1s + s * 64;
        float p = 0.f;
#pragma unroll 8
        for (int k = 0; k < 64; ++k) p += dot4(f4[k], w[k]);
        tp[s][d] = p;
    }
    __syncthreads();
    float y2 = 0.f;
    if (tid < 128) {
        y2 = xr[tid] + ff2_b[L * 128 + tid];
#pragma unroll
        for (int s = 0; s < 8; ++s) y2 += tp[s][tid];
    }
    float m2 = sum128(y2, tid, red) * (1.f / 128.f);
    float c2 = y2 - m2;
    float v2 = sum128(c2 * c2, tid, red) * (1.f / 128.f);
    if (tid < 128) xs[b * 128 + tid] = c2 * rsqrtf(v2 + 1e-5f) * ln2_g[L * 128 + tid] + ln2_b[L * 128 + tid];
}

// ---------------- mid projection ----------------
__global__ void k_mid(const float* __restrict__ xe, const float* __restrict__ mid_w,
                      const float* __restrict__ mid_b, float* __restrict__ mid) {
    int b = blockIdx.x, c = threadIdx.x;  // 64 threads
    float s = mid_b[c];
    const float* xr = xe + b * 128;
    const float* wr = mid_w + c * 128;
    for (int k = 0; k < 128; ++k) s += xr[k] * wr[k];
    mid[b * 64 + c] = s;
}

// ---------------- conv1: 3->32 direct f32, fused q_sample, relu, out bf16 NHWC ----------------
__global__ __launch_bounds__(256, 4) void k_conv1(
    const float* __restrict__ tgt, const float* __restrict__ noise,
    const float* __restrict__ sab, const float* __restrict__ snab,
    const float* __restrict__ wgt, const float* __restrict__ bias,
    unsigned short* __restrict__ h1, int b0) {
    __shared__ float it[3][34][35];
    __shared__ float wt[8][3][9];
    int tid = threadIdx.x;
    int tx = tid & 7, ty = tid >> 3;
    int bx = blockIdx.x, by = blockIdx.y;
    int bl = blockIdx.z >> 2, g = blockIdx.z & 3;
    int bg = b0 + bl, co0 = g * 8;
    float za = sab[bg], zb = snab[bg];
    for (int idx = tid; idx < 3 * 34 * 34; idx += 256) {
        int c = idx / 1156, rem = idx % 1156;
        int yy = rem / 34, xx = rem % 34;
        int gy = by * 32 + yy - 1, gx = bx * 32 + xx - 1;
        float v = 0.f;
        if (gy >= 0 && gy < 128 && gx >= 0 && gx < 128) {
            size_t off = (((size_t)bg * 3 + c) * 128 + gy) * 128 + gx;
            v = za * tgt[off] + zb * noise[off];
        }
        it[c][yy][xx] = v;
    }
    for (int idx = tid; idx < 8 * 27; idx += 256) {
        int co = idx / 27, rem = idx % 27;
        wt[co][rem / 9][rem % 9] = wgt[(size_t)(co0 + co) * 27 + rem];
    }
    __syncthreads();
    float acc[8][4];
#pragma unroll
    for (int co = 0; co < 8; ++co)
#pragma unroll
        for (int p = 0; p < 4; ++p) acc[co][p] = 0.f;
#pragma unroll
    for (int c = 0; c < 3; ++c)
#pragma unroll
        for (int ky = 0; ky < 3; ++ky) {
            float win[6];
#pragma unroll
            for (int i = 0; i < 6; ++i) win[i] = it[c][ty + ky][tx * 4 + i];
#pragma unroll
            for (int kx = 0; kx < 3; ++kx)
#pragma unroll
                for (int co = 0; co < 8; ++co) {
                    float w = wt[co][c][ky * 3 + kx];
#pragma unroll
                    for (int p = 0; p < 4; ++p) acc[co][p] += win[kx + p] * w;
                }
        }
    int gy = by * 32 + ty, gx0 = bx * 32 + tx * 4;
#pragma unroll
    for (int p = 0; p < 4; ++p) {
        ushort4 oa, ob;
#pragma unroll
        for (int co = 0; co < 4; ++co)
            ((unsigned short*)&oa)[co] = f2bf(fmaxf(acc[co][p] + bias[co0 + co], 0.f));
#pragma unroll
        for (int co = 0; co < 4; ++co)
            ((unsigned short*)&ob)[co] = f2bf(fmaxf(acc[co + 4][p] + bias[co0 + co + 4], 0.f));
        size_t o = (((size_t)bl * 128 + gy) * 128 + gx0 + p) * 32 + co0;
        *(ushort4*)(h1 + o) = oa;
        *(ushort4*)(h1 + o + 4) = ob;
    }
}

// ---------------- MFMA 3x3 conv: bf16 NHWC in/out, f32 accum ----------------
// Block: 32x x 8y output px, COB*16 out-chans per block. 256 thr = 4 waves.
// MOUT: 1 = relu; 2 = relu then +mid
template <int CIN, int COB, int COUT, int MOUT>
__global__ __launch_bounds__(256, 2) void k_convMg(
    const unsigned short* __restrict__ in, const unsigned short* __restrict__ wb,
    const float* __restrict__ bias, const float* __restrict__ mid,
    unsigned short* __restrict__ out, int b0) {
    const int GROUPS = COUT / (16 * COB);
    __shared__ __align__(16) unsigned short in_t[10 * 34 * 40];
    __shared__ __align__(16) unsigned short w_t[9 * COB * 16 * 40];
    int tid = threadIdx.x;
    int bx = blockIdx.x, by = blockIdx.y;
    int bl = blockIdx.z / GROUPS, g = blockIdx.z % GROUPS;
    int bg = b0 + bl;
    int co0 = g * COB * 16;
    int lane = tid & 63, wv = tid >> 6;
    int l15 = lane & 15, ch = lane >> 4;

    f32x4 acc[2][2][COB];
    f32x4 zf = {0.f, 0.f, 0.f, 0.f};
#pragma unroll
    for (int a = 0; a < 2; ++a)
#pragma unroll
        for (int bq = 0; bq < 2; ++bq)
#pragma unroll
            for (int c = 0; c < COB; ++c) acc[a][bq][c] = zf;

    for (int cs = 0; cs < CIN / 32; ++cs) {
        if (cs) __syncthreads();
        for (int c = tid; c < 10 * 34 * 4; c += 256) {
            int cc = c & 3, pix = c >> 2;
            int xx = pix % 34, yy = pix / 34;
            int gy = by * 8 + yy - 1, gx = bx * 32 + xx - 1;
            bf16x8 v = {0, 0, 0, 0, 0, 0, 0, 0};
            if (gy >= 0 && gy < 128 && gx >= 0 && gx < 128)
                v = *(const bf16x8*)(in + (((size_t)bl * 128 + gy) * 128 + gx) * CIN + cs * 32 + cc * 8);
            *(bf16x8*)(in_t + pix * 40 + cc * 8) = v;
        }
        for (int c = tid; c < 9 * COB * 16 * 4; c += 256) {
            int cc = c & 3, row = c >> 2;
            int tap = row / (COB * 16), co = row % (COB * 16);
            bf16x8 v = *(const bf16x8*)(wb + ((size_t)(tap * COUT + co0 + co)) * CIN + cs * 32 + cc * 8);
            *(bf16x8*)(w_t + row * 40 + cc * 8) = v;
        }
        __syncthreads();
#pragma unroll
        for (int ky = 0; ky < 3; ++ky)
#pragma unroll
            for (int kx = 0; kx < 3; ++kx) {
                int tap = ky * 3 + kx;
                bf16x8 af[COB];
#pragma unroll
                for (int cb = 0; cb < COB; ++cb)
                    af[cb] = *(const bf16x8*)(w_t + (tap * COB * 16 + cb * 16 + l15) * 40 + ch * 8);
#pragma unroll
                for (int yl = 0; yl < 2; ++yl) {
                    int yloc = 2 * wv + yl + ky;
#pragma unroll
                    for (int xt = 0; xt < 2; ++xt) {
                        int xloc = xt * 16 + l15 + kx;
                        bf16x8 bfv = *(const bf16x8*)(in_t + (yloc * 34 + xloc) * 40 + ch * 8);
#pragma unroll
                        for (int cb = 0; cb < COB; ++cb)
                            acc[yl][xt][cb] = __builtin_amdgcn_mfma_f32_16x16x32_bf16(
                                af[cb], bfv, acc[yl][xt][cb], 0, 0, 0);
                    }
                }
            }
    }
#pragma unroll
    for (int yl = 0; yl < 2; ++yl) {
        int gy = by * 8 + 2 * wv + yl;
#pragma unroll
        for (int xt = 0; xt < 2; ++xt) {
            int gx = bx * 32 + xt * 16 + l15;
            size_t pixo = (((size_t)bl * 128 + gy) * 128 + gx) * COUT;
#pragma unroll
            for (int cb = 0; cb < COB; ++cb) {
                int co = co0 + cb * 16 + ch * 4;
                ushort4 o;
#pragma unroll
                for (int r = 0; r < 4; ++r) {
                    float v = acc[yl][xt][cb][r] + bias[co + r];
                    v = fmaxf(v, 0.f);
                    if (MOUT == 2) v += mid[bg * 64 + co + r];
                    ((unsigned short*)&o)[r] = f2bf(v);
                }
                *(ushort4*)(out + pixo + co) = o;
            }
        }
    }
}

// ---------------- u2 via MFMA (co 0..2 of 16-pad) + fused MSE ----------------
__global__ __launch_bounds__(256, 3) void k_u2m(
    const unsigned short* __restrict__ h3, const unsigned short* __restrict__ wbu2,
    const float* __restrict__ u2_b, const float* __restrict__ noise,
    float* __restrict__ partial, int b0) {
    __shared__ __align__(16) unsigned short in_t[340 * 40];
    __shared__ __align__(16) unsigned short w_t[9 * 16 * 40];
    __shared__ float rs[256];
    int tid = threadIdx.x;
    int bx = blockIdx.x, by = blockIdx.y, bl = blockIdx.z;
    int bg = b0 + bl;
    int lane = tid & 63, wv = tid >> 6, l15 = lane & 15, ch = lane >> 4;

    for (int c = tid; c < 340 * 4; c += 256) {
        int cc = c & 3, pix = c >> 2;
        int xx = pix % 34, yy = pix / 34;
        int gy = by * 8 + yy - 1, gx = bx * 32 + xx - 1;
        bf16x8 v = {0, 0, 0, 0, 0, 0, 0, 0};
        if (gy >= 0 && gy < 128 && gx >= 0 && gx < 128)
            v = *(const bf16x8*)(h3 + (((size_t)bl * 128 + gy) * 128 + gx) * 32 + cc * 8);
        *(bf16x8*)(in_t + pix * 40 + cc * 8) = v;
    }
    for (int c = tid; c < 9 * 16 * 4; c += 256) {
        int cc = c & 3, row = c >> 2;
        bf16x8 v = *(const bf16x8*)(wbu2 + (size_t)row * 32 + cc * 8);
        *(bf16x8*)(w_t + row * 40 + cc * 8) = v;
    }
    __syncthreads();

    f32x4 acc[2][2];
    f32x4 zf = {0.f, 0.f, 0.f, 0.f};
    acc[0][0] = zf; acc[0][1] = zf; acc[1][0] = zf; acc[1][1] = zf;
#pragma unroll
    for (int ky = 0; ky < 3; ++ky)
#pragma unroll
        for (int kx = 0; kx < 3; ++kx) {
            int tap = ky * 3 + kx;
            bf16x8 af = *(const bf16x8*)(w_t + (tap * 16 + l15) * 40 + ch * 8);
#pragma unroll
            for (int yl = 0; yl < 2; ++yl) {
                int yloc = 2 * wv + yl + ky;
#pragma unroll
                for (int xt = 0; xt < 2; ++xt) {
                    int xloc = xt * 16 + l15 + kx;
                    bf16x8 bfv = *(const bf16x8*)(in_t + (yloc * 34 + xloc) * 40 + ch * 8);
                    acc[yl][xt] = __builtin_amdgcn_mfma_f32_16x16x32_bf16(af, bfv, acc[yl][xt], 0, 0, 0);
                }
            }
        }
    float ss = 0.f;
    if (ch == 0) {
#pragma unroll
        for (int yl = 0; yl < 2; ++yl) {
            int gy = by * 8 + 2 * wv + yl;
#pragma unroll
            for (int xt = 0; xt < 2; ++xt) {
                int gx = bx * 32 + xt * 16 + l15;
#pragma unroll
                for (int r = 0; r < 3; ++r) {
                    float v = acc[yl][xt][r] + u2_b[r];
                    float d = v - noise[(((size_t)bg * 3 + r) * 128 + gy) * 128 + gx];
                    ss += d * d;
                }
            }
        }
    }
    rs[tid] = ss;
    __syncthreads();
    for (int s = 128; s > 0; s >>= 1) {
        if (tid < s) rs[tid] += rs[tid + s];
        __syncthreads();
    }
    if (tid == 0) partial[bg * 64 + by * 4 + bx] = rs[0];
}

// ---------------- final MSE reduction ----------------
__global__ void k_final(const float* __restrict__ partial, float* __restrict__ out) {
    __shared__ float rs[256];
    int tid = threadIdx.x;
    float s = 0.f;
    for (int i = tid; i < 4096; i += 256) s += partial[i];
    rs[tid] = s;
    __syncthreads();
    for (int st = 128; st > 0; st >>= 1) {
        if (tid < st) rs[tid] += rs[tid + st];
        __syncthreads();
    }
    if (tid == 0) out[0] = rs[0] / 3145728.0f;
}

extern "C" void kernel_launch(void* const* d_in, const int* in_sizes, int n_in,
                              void* d_out, int out_size, void* d_ws, size_t ws_size,
                              hipStream_t stream) {
    const float* cond   = (const float*)d_in[0];
    const float* tgt    = (const float*)d_in[1];
    const float* noise  = (const float*)d_in[2];
    const int*   t      = (const int*)d_in[3];
    const float* enc_w  = (const float*)d_in[4];
    const float* enc_b  = (const float*)d_in[5];
    const float* in_w   = (const float*)d_in[6];
    const float* in_b   = (const float*)d_in[7];
    const float* out_w  = (const float*)d_in[8];
    const float* out_b  = (const float*)d_in[9];
    const float* ff1_w  = (const float*)d_in[10];
    const float* ff1_b  = (const float*)d_in[11];
    const float* ff2_w  = (const float*)d_in[12];
    const float* ff2_b  = (const float*)d_in[13];
    const float* ln1_g  = (const float*)d_in[14];
    const float* ln1_b  = (const float*)d_in[15];
    const float* ln2_g  = (const float*)d_in[16];
    const float* ln2_b  = (const float*)d_in[17];
    const float* d1_w   = (const float*)d_in[18];
    const float* d1_b   = (const float*)d_in[19];
    const float* d2_w   = (const float*)d_in[20];
    const float* d2_b   = (const float*)d_in[21];
    const float* mid_w  = (const float*)d_in[22];
    const float* mid_b  = (const float*)d_in[23];
    const float* u1_w   = (const float*)d_in[24];
    const float* u1_b   = (const float*)d_in[25];
    const float* u2_w   = (const float*)d_in[26];
    const float* u2_b   = (const float*)d_in[27];

    float* ws = (float*)d_ws;
    // control region: 131072 floats
    float* sab     = ws;                    // 64
    float* snab    = ws + 64;               // 64
    float* x0      = ws + 128;              // 8192
    float* mid     = ws + 16512;            // 4096
    float* msepart = ws + 86144;            // 4096
    unsigned short* wb2  = (unsigned short*)(ws + 90240);   // 18432 bf16
    unsigned short* wbu1 = (unsigned short*)(ws + 99456);   // 18432 bf16
    unsigned short* wbu2 = (unsigned short*)(ws + 108672);  // 4608 bf16

    // encpart: KSEG * 8192 floats, placed after control region
    const size_t SMALL = 131072;
    const size_t ENCP = (size_t)KSEG * 8192;   // 524288
    float* encpart = ws + SMALL;

    // chunk: NB images of bf16 h1(32) + h2(64) + h3(32) = NB*1048576 f32-slots
    size_t fixed = SMALL + ENCP;
    size_t avail = (ws_size / 4 > fixed) ? (ws_size / 4 - fixed) : 0;
    int NB = 1;
    const int cands[7] = {64, 32, 16, 8, 4, 2, 1};
    for (int ci = 0; ci < 7; ++ci) {
        if ((size_t)cands[ci] * 1048576ull <= avail) { NB = cands[ci]; break; }
    }
    unsigned short* hb1 = (unsigned short*)(ws + fixed);
    unsigned short* hb2 = (unsigned short*)(ws + fixed + (size_t)NB * 262144ull);
    unsigned short* hb3 = (unsigned short*)(ws + fixed + (size_t)NB * 786432ull);

    k_alpha<<<1, 64, 0, stream>>>(t, sab, snab);
    k_prep_cw<<<72, 256, 0, stream>>>(d2_w, wb2, 64, 32);
    k_prep_cw<<<72, 256, 0, stream>>>(u1_w, wbu1, 32, 64);
    k_prep_u2<<<18, 256, 0, stream>>>(u2_w, wbu2);
    k_enc_gemm<<<dim3(8, 4, KSEG), 256, 0, stream>>>(cond, enc_w, encpart);
    k_enc_reduce<<<32, 256, 0, stream>>>(encpart, enc_b, x0);
    k_tf_layer<<<64, 1024, 0, stream>>>(x0, in_w, in_b, out_w, out_b, ff1_w, ff1_b,
                                        ff2_w, ff2_b, ln1_g, ln1_b, ln2_g, ln2_b, 0);
    k_tf_layer<<<64, 1024, 0, stream>>>(x0, in_w, in_b, out_w, out_b, ff1_w, ff1_b,
                                        ff2_w, ff2_b, ln1_g, ln1_b, ln2_g, ln2_b, 1);
    k_mid<<<64, 64, 0, stream>>>(x0, mid_w, mid_b, mid);

    for (int cb = 0; cb < 64; cb += NB) {
        // conv1: 3->32 direct f32, q_sample fused, out bf16 NHWC
        k_conv1<<<dim3(4, 4, NB * 4), 256, 0, stream>>>(
            tgt, noise, sab, snab, d1_w, d1_b, hb1, cb);
        // conv2: 32->64 MFMA, all 64 co per block, relu + mid
        k_convMg<32, 4, 64, 2><<<dim3(4, 16, NB), 256, 0, stream>>>(
            hb1, wb2, d2_b, mid, hb2, cb);
        // u1: 64->32 MFMA, relu
        k_convMg<64, 2, 32, 1><<<dim3(4, 16, NB), 256, 0, stream>>>(
            hb2, wbu1, u1_b, nullptr, hb3, cb);
        // u2: 32->3 MFMA + fused MSE
        k_u2m<<<dim3(4, 16, NB), 256, 0, stream>>>(
            hb3, wbu2, u2_b, noise, msepart, cb);
    }

    k_final<<<1, 256, 0, stream>>>(msepart, (float*)d_out);
}

// Round 9
// 428.005 us; speedup vs baseline: 8.7539x; 1.1900x over previous
//
#include <hip/hip_runtime.h>
#include <math.h>

#define ENC_K 49152
#define KSEG 64
#define KLEN (ENC_K / KSEG)   // 768

typedef __attribute__((ext_vector_type(8))) short bf16x8;
typedef __attribute__((ext_vector_type(4))) float f32x4;

__device__ inline unsigned short f2bf(float f) {
    unsigned int u = __builtin_bit_cast(unsigned int, f);
    unsigned int r = u + 0x7fffu + ((u >> 16) & 1u);
    return (unsigned short)(r >> 16);
}
__device__ inline float bf2f(unsigned short h) {
    return __builtin_bit_cast(float, ((unsigned int)h) << 16);
}
__device__ inline float dot4(const float4 a, const float4 b) {
    return a.x * b.x + a.y * b.y + a.z * b.z + a.w * b.w;
}

// ---------------- alpha_bar per batch ----------------
__global__ void k_alpha(const int* __restrict__ t, float* __restrict__ sab, float* __restrict__ snab) {
    int b = threadIdx.x;
    if (b < 64) {
        int tb = t[b];
        const float step = (0.02f - 1e-4f) / 999.0f;
        float ab = 1.0f;
        for (int i = 0; i <= tb; ++i) {
            float beta = 1e-4f + step * (float)i;
            ab *= (1.0f - beta);
        }
        sab[b] = sqrtf(ab);
        snab[b] = sqrtf(1.0f - ab);
    }
}

// ---------------- conv weight prep: f32 [CO][CI][3][3] -> bf16 [tap][CO][CI] ----------------
__global__ void k_prep_cw(const float* __restrict__ w, unsigned short* __restrict__ out, int CO, int CI) {
    int idx = blockIdx.x * 256 + threadIdx.x;
    int total = CO * CI * 9;
    if (idx < total) {
        int tap = idx / (CO * CI);
        int rem = idx % (CO * CI);
        int co = rem / CI, ci = rem % CI;
        out[idx] = f2bf(w[((size_t)co * CI + ci) * 9 + tap]);
    }
}

// u2 weights: f32 [3][32][3][3] -> bf16 [tap][16 co(pad)][32 ci], co>=3 zero
__global__ void k_prep_u2(const float* __restrict__ w, unsigned short* __restrict__ out) {
    int idx = blockIdx.x * 256 + threadIdx.x;
    if (idx < 9 * 16 * 32) {
        int tap = idx / 512;
        int rem = idx % 512;
        int co = rem / 32, ci = rem % 32;
        out[idx] = (co < 3) ? f2bf(w[((size_t)co * 32 + ci) * 9 + tap]) : (unsigned short)0;
    }
}

// ---------------- encoder GEMM: x0 = cond @ W^T (K-split partials) ----------------
__global__ void k_enc_gemm(const float* __restrict__ cond, const float* __restrict__ w,
                           float* __restrict__ partial) {
    __shared__ float As[16][68];
    __shared__ float Ws[16][68];
    int tid = threadIdx.x;
    int j = tid & 15, i = tid >> 4;
    int d0 = blockIdx.x * 16, b0 = blockIdx.y * 16;
    int k0 = blockIdx.z * KLEN;
    float a0 = 0.f, a1 = 0.f, a2 = 0.f, a3 = 0.f;
    for (int kk = 0; kk < KLEN; kk += 64) {
        for (int idx = tid; idx < 1024; idx += 256) {
            int r = idx >> 6, c = idx & 63;
            As[r][c] = cond[(size_t)(b0 + r) * ENC_K + k0 + kk + c];
            Ws[r][c] = w[(size_t)(d0 + r) * ENC_K + k0 + kk + c];
        }
        __syncthreads();
        const float4* a4 = (const float4*)&As[i][0];
        const float4* w4 = (const float4*)&Ws[j][0];
#pragma unroll
        for (int k = 0; k < 4; ++k) {
            a0 += dot4(a4[k], w4[k]);
            a1 += dot4(a4[k + 4], w4[k + 4]);
            a2 += dot4(a4[k + 8], w4[k + 8]);
            a3 += dot4(a4[k + 12], w4[k + 12]);
        }
        __syncthreads();
    }
    partial[((size_t)blockIdx.z * 64 + b0 + i) * 128 + d0 + j] = (a0 + a1) + (a2 + a3);
}

__global__ void k_enc_reduce(const float* __restrict__ partial, const float* __restrict__ bias,
                             float* __restrict__ x0) {
    int idx = blockIdx.x * 256 + threadIdx.x;  // 8192 total
    float s = bias[idx & 127];
    for (int ks = 0; ks < KSEG; ++ks) s += partial[(size_t)ks * 8192 + idx];
    x0[idx] = s;
}

// ---------------- transformer, batched 4-kernel-per-layer form ----------------
__device__ float sum128(float v, int tid, float* red) {
    if (tid < 128) red[tid] = v;
    __syncthreads();
    if (tid < 64) red[tid] += red[tid + 64]; __syncthreads();
    if (tid < 32) red[tid] += red[tid + 32]; __syncthreads();
    if (tid < 16) red[tid] += red[tid + 16]; __syncthreads();
    if (tid < 8)  red[tid] += red[tid + 8];  __syncthreads();
    if (tid < 4)  red[tid] += red[tid + 4];  __syncthreads();
    if (tid < 2)  red[tid] += red[tid + 2];  __syncthreads();
    if (tid < 1)  red[tid] += red[tid + 1];  __syncthreads();
    float s = red[0];
    __syncthreads();
    return s;
}

// attn(v,out) + ln1: one block per batch row, 512 threads
__global__ __launch_bounds__(512) void k_tf_attn(
    const float* __restrict__ xs, float* __restrict__ yo,
    const float* __restrict__ in_w, const float* __restrict__ in_b,
    const float* __restrict__ out_w, const float* __restrict__ out_b,
    const float* __restrict__ ln1_g, const float* __restrict__ ln1_b, int L) {
    __shared__ float xr[128], vr[128], tp[4][128], red[128];
    int b = blockIdx.x, tid = threadIdx.x;
    if (tid < 128) xr[tid] = xs[b * 128 + tid];
    __syncthreads();
    int d = tid & 127, s = tid >> 7;   // s in 0..3
    {
        const float4* w = (const float4*)(in_w + ((size_t)L * 384 + 256 + d) * 128) + s * 8;
        const float4* x4 = (const float4*)xr + s * 8;
        float p = 0.f;
#pragma unroll
        for (int k = 0; k < 8; ++k) p += dot4(x4[k], w[k]);
        tp[s][d] = p;
    }
    __syncthreads();
    if (tid < 128) vr[tid] = in_b[L * 384 + 256 + tid] + tp[0][tid] + tp[1][tid] + tp[2][tid] + tp[3][tid];
    __syncthreads();
    {
        const float4* w = (const float4*)(out_w + ((size_t)L * 128 + d) * 128) + s * 8;
        const float4* v4 = (const float4*)vr + s * 8;
        float p = 0.f;
#pragma unroll
        for (int k = 0; k < 8; ++k) p += dot4(v4[k], w[k]);
        tp[s][d] = p;
    }
    __syncthreads();
    float y = 0.f;
    if (tid < 128) y = xr[tid] + out_b[L * 128 + tid] + tp[0][tid] + tp[1][tid] + tp[2][tid] + tp[3][tid];
    float m1 = sum128(y, tid, red) * (1.f / 128.f);
    float c1 = y - m1;
    float v1 = sum128(c1 * c1, tid, red) * (1.f / 128.f);
    if (tid < 128)
        yo[b * 128 + tid] = c1 * rsqrtf(v1 + 1e-5f) * ln1_g[L * 128 + tid] + ln1_b[L * 128 + tid];
}

// ff1: f1[r][j] = relu(y[r] . w1[j] + b1[j]); grid (16 neuron-tiles, 16 row-tiles), 256 thr
__global__ __launch_bounds__(256) void k_tf_ff1(
    const float* __restrict__ yo, float* __restrict__ f1,
    const float* __restrict__ ff1_w, const float* __restrict__ ff1_b, int L) {
    __shared__ float xr[4][128];
    int tid = threadIdx.x;
    int n0 = blockIdx.x * 128, r0 = blockIdx.y * 4;
    for (int e = tid; e < 512; e += 256)
        xr[e >> 7][e & 127] = yo[(r0 + (e >> 7)) * 128 + (e & 127)];
    __syncthreads();
    int j = n0 + (tid & 127);
    int rh = tid >> 7;                 // 0..1 -> rows rh*2, rh*2+1
    const float4* w = (const float4*)(ff1_w + ((size_t)L * 2048 + j) * 128);
    const float4* xa = (const float4*)xr[rh * 2];
    const float4* xb = (const float4*)xr[rh * 2 + 1];
    float a0 = 0.f, a1 = 0.f;
#pragma unroll 8
    for (int k = 0; k < 32; ++k) {
        float4 wv = w[k];
        a0 += dot4(xa[k], wv);
        a1 += dot4(xb[k], wv);
    }
    float bv = ff1_b[L * 2048 + j];
    f1[(size_t)(r0 + rh * 2) * 2048 + j] = fmaxf(a0 + bv, 0.f);
    f1[(size_t)(r0 + rh * 2 + 1) * 2048 + j] = fmaxf(a1 + bv, 0.f);
}

// ff2 partials: grid (8 ksegs, 64 rows), 128 thr; part[(ks*64+row)*128+d]
__global__ __launch_bounds__(128) void k_tf_ff2(
    const float* __restrict__ f1, float* __restrict__ part,
    const float* __restrict__ ff2_w, int L) {
    __shared__ float fr[256];
    int tid = threadIdx.x;
    int ks = blockIdx.x, row = blockIdx.y;
    int k0 = ks * 256;
    for (int e = tid; e < 256; e += 128) fr[e] = f1[(size_t)row * 2048 + k0 + e];
    __syncthreads();
    const float4* w = (const float4*)(ff2_w + ((size_t)L * 128 + tid) * 2048 + k0);
    const float4* f4 = (const float4*)fr;
    float p = 0.f;
#pragma unroll 8
    for (int k = 0; k < 64; ++k) p += dot4(f4[k], w[k]);
    part[((size_t)ks * 64 + row) * 128 + tid] = p;
}

// reduce partials + residual + ln2 -> xs; grid 64, 128 thr
__global__ __launch_bounds__(128) void k_tf_red(
    const float* __restrict__ part, const float* __restrict__ yo,
    float* __restrict__ xs, const float* __restrict__ ff2_b,
    const float* __restrict__ ln2_g, const float* __restrict__ ln2_b, int L) {
    __shared__ float red[128];
    int b = blockIdx.x, tid = threadIdx.x;
    float y2 = yo[b * 128 + tid] + ff2_b[L * 128 + tid];
#pragma unroll
    for (int ks = 0; ks < 8; ++ks) y2 += part[((size_t)ks * 64 + b) * 128 + tid];
    float m2 = sum128(y2, tid, red) * (1.f / 128.f);
    float c2 = y2 - m2;
    float v2 = sum128(c2 * c2, tid, red) * (1.f / 128.f);
    xs[b * 128 + tid] = c2 * rsqrtf(v2 + 1e-5f) * ln2_g[L * 128 + tid] + ln2_b[L * 128 + tid];
}

// ---------------- mid projection ----------------
__global__ void k_mid(const float* __restrict__ xe, const float* __restrict__ mid_w,
                      const float* __restrict__ mid_b, float* __restrict__ mid) {
    int b = blockIdx.x, c = threadIdx.x;  // 64 threads
    float s = mid_b[c];
    const float* xr = xe + b * 128;
    const float* wr = mid_w + c * 128;
    for (int k = 0; k < 128; ++k) s += xr[k] * wr[k];
    mid[b * 64 + c] = s;
}

// ---------------- conv1: 3->32 direct f32, fused q_sample, relu, out bf16 NHWC ----------------
__global__ __launch_bounds__(256, 4) void k_conv1(
    const float* __restrict__ tgt, const float* __restrict__ noise,
    const float* __restrict__ sab, const float* __restrict__ snab,
    const float* __restrict__ wgt, const float* __restrict__ bias,
    unsigned short* __restrict__ h1, int b0) {
    __shared__ float it[3][34][35];
    __shared__ float wt[8][3][9];
    int tid = threadIdx.x;
    int tx = tid & 7, ty = tid >> 3;
    int bx = blockIdx.x, by = blockIdx.y;
    int bl = blockIdx.z >> 2, g = blockIdx.z & 3;
    int bg = b0 + bl, co0 = g * 8;
    float za = sab[bg], zb = snab[bg];
    for (int idx = tid; idx < 3 * 34 * 34; idx += 256) {
        int c = idx / 1156, rem = idx % 1156;
        int yy = rem / 34, xx = rem % 34;
        int gy = by * 32 + yy - 1, gx = bx * 32 + xx - 1;
        float v = 0.f;
        if (gy >= 0 && gy < 128 && gx >= 0 && gx < 128) {
            size_t off = (((size_t)bg * 3 + c) * 128 + gy) * 128 + gx;
            v = za * tgt[off] + zb * noise[off];
        }
        it[c][yy][xx] = v;
    }
    for (int idx = tid; idx < 8 * 27; idx += 256) {
        int co = idx / 27, rem = idx % 27;
        wt[co][rem / 9][rem % 9] = wgt[(size_t)(co0 + co) * 27 + rem];
    }
    __syncthreads();
    float acc[8][4];
#pragma unroll
    for (int co = 0; co < 8; ++co)
#pragma unroll
        for (int p = 0; p < 4; ++p) acc[co][p] = 0.f;
#pragma unroll
    for (int c = 0; c < 3; ++c)
#pragma unroll
        for (int ky = 0; ky < 3; ++ky) {
            float win[6];
#pragma unroll
            for (int i = 0; i < 6; ++i) win[i] = it[c][ty + ky][tx * 4 + i];
#pragma unroll
            for (int kx = 0; kx < 3; ++kx)
#pragma unroll
                for (int co = 0; co < 8; ++co) {
                    float w = wt[co][c][ky * 3 + kx];
#pragma unroll
                    for (int p = 0; p < 4; ++p) acc[co][p] += win[kx + p] * w;
                }
        }
    int gy = by * 32 + ty, gx0 = bx * 32 + tx * 4;
#pragma unroll
    for (int p = 0; p < 4; ++p) {
        ushort4 oa, ob;
#pragma unroll
        for (int co = 0; co < 4; ++co)
            ((unsigned short*)&oa)[co] = f2bf(fmaxf(acc[co][p] + bias[co0 + co], 0.f));
#pragma unroll
        for (int co = 0; co < 4; ++co)
            ((unsigned short*)&ob)[co] = f2bf(fmaxf(acc[co + 4][p] + bias[co0 + co + 4], 0.f));
        size_t o = (((size_t)bl * 128 + gy) * 128 + gx0 + p) * 32 + co0;
        *(ushort4*)(h1 + o) = oa;
        *(ushort4*)(h1 + o + 4) = ob;
    }
}

// ---------------- MFMA 3x3 conv: bf16 NHWC in/out, f32 accum ----------------
// Block: 32x x 8y output px, COB*16 out-chans per block. 256 thr = 4 waves.
// MOUT: 1 = relu; 2 = relu then +mid
template <int CIN, int COB, int COUT, int MOUT>
__global__ __launch_bounds__(256, 2) void k_convMg(
    const unsigned short* __restrict__ in, const unsigned short* __restrict__ wb,
    const float* __restrict__ bias, const float* __restrict__ mid,
    unsigned short* __restrict__ out, int b0) {
    const int GROUPS = COUT / (16 * COB);
    __shared__ __align__(16) unsigned short in_t[10 * 34 * 40];
    __shared__ __align__(16) unsigned short w_t[9 * COB * 16 * 40];
    int tid = threadIdx.x;
    int bx = blockIdx.x, by = blockIdx.y;
    int bl = blockIdx.z / GROUPS, g = blockIdx.z % GROUPS;
    int bg = b0 + bl;
    int co0 = g * COB * 16;
    int lane = tid & 63, wv = tid >> 6;
    int l15 = lane & 15, ch = lane >> 4;

    f32x4 acc[2][2][COB];
    f32x4 zf = {0.f, 0.f, 0.f, 0.f};
#pragma unroll
    for (int a = 0; a < 2; ++a)
#pragma unroll
        for (int bq = 0; bq < 2; ++bq)
#pragma unroll
            for (int c = 0; c < COB; ++c) acc[a][bq][c] = zf;

    for (int cs = 0; cs < CIN / 32; ++cs) {
        if (cs) __syncthreads();
        for (int c = tid; c < 10 * 34 * 4; c += 256) {
            int cc = c & 3, pix = c >> 2;
            int xx = pix % 34, yy = pix / 34;
            int gy = by * 8 + yy - 1, gx = bx * 32 + xx - 1;
            bf16x8 v = {0, 0, 0, 0, 0, 0, 0, 0};
            if (gy >= 0 && gy < 128 && gx >= 0 && gx < 128)
                v = *(const bf16x8*)(in + (((size_t)bl * 128 + gy) * 128 + gx) * CIN + cs * 32 + cc * 8);
            *(bf16x8*)(in_t + pix * 40 + cc * 8) = v;
        }
        for (int c = tid; c < 9 * COB * 16 * 4; c += 256) {
            int cc = c & 3, row = c >> 2;
            int tap = row / (COB * 16), co = row % (COB * 16);
            bf16x8 v = *(const bf16x8*)(wb + ((size_t)(tap * COUT + co0 + co)) * CIN + cs * 32 + cc * 8);
            *(bf16x8*)(w_t + row * 40 + cc * 8) = v;
        }
        __syncthreads();
#pragma unroll
        for (int ky = 0; ky < 3; ++ky)
#pragma unroll
            for (int kx = 0; kx < 3; ++kx) {
                int tap = ky * 3 + kx;
                bf16x8 af[COB];
#pragma unroll
                for (int cb = 0; cb < COB; ++cb)
                    af[cb] = *(const bf16x8*)(w_t + (tap * COB * 16 + cb * 16 + l15) * 40 + ch * 8);
#pragma unroll
                for (int yl = 0; yl < 2; ++yl) {
                    int yloc = 2 * wv + yl + ky;
#pragma unroll
                    for (int xt = 0; xt < 2; ++xt) {
                        int xloc = xt * 16 + l15 + kx;
                        bf16x8 bfv = *(const bf16x8*)(in_t + (yloc * 34 + xloc) * 40 + ch * 8);
#pragma unroll
                        for (int cb = 0; cb < COB; ++cb)
                            acc[yl][xt][cb] = __builtin_amdgcn_mfma_f32_16x16x32_bf16(
                                af[cb], bfv, acc[yl][xt][cb], 0, 0, 0);
                    }
                }
            }
    }
#pragma unroll
    for (int yl = 0; yl < 2; ++yl) {
        int gy = by * 8 + 2 * wv + yl;
#pragma unroll
        for (int xt = 0; xt < 2; ++xt) {
            int gx = bx * 32 + xt * 16 + l15;
            size_t pixo = (((size_t)bl * 128 + gy) * 128 + gx) * COUT;
#pragma unroll
            for (int cb = 0; cb < COB; ++cb) {
                int co = co0 + cb * 16 + ch * 4;
                ushort4 o;
#pragma unroll
                for (int r = 0; r < 4; ++r) {
                    float v = acc[yl][xt][cb][r] + bias[co + r];
                    v = fmaxf(v, 0.f);
                    if (MOUT == 2) v += mid[bg * 64 + co + r];
                    ((unsigned short*)&o)[r] = f2bf(v);
                }
                *(ushort4*)(out + pixo + co) = o;
            }
        }
    }
}

// ---------------- u2 via MFMA (co 0..2 of 16-pad) + fused MSE ----------------
__global__ __launch_bounds__(256, 3) void k_u2m(
    const unsigned short* __restrict__ h3, const unsigned short* __restrict__ wbu2,
    const float* __restrict__ u2_b, const float* __restrict__ noise,
    float* __restrict__ partial, int b0) {
    __shared__ __align__(16) unsigned short in_t[340 * 40];
    __shared__ __align__(16) unsigned short w_t[9 * 16 * 40];
    __shared__ float rs[256];
    int tid = threadIdx.x;
    int bx = blockIdx.x, by = blockIdx.y, bl = blockIdx.z;
    int bg = b0 + bl;
    int lane = tid & 63, wv = tid >> 6, l15 = lane & 15, ch = lane >> 4;

    for (int c = tid; c < 340 * 4; c += 256) {
        int cc = c & 3, pix = c >> 2;
        int xx = pix % 34, yy = pix / 34;
        int gy = by * 8 + yy - 1, gx = bx * 32 + xx - 1;
        bf16x8 v = {0, 0, 0, 0, 0, 0, 0, 0};
        if (gy >= 0 && gy < 128 && gx >= 0 && gx < 128)
            v = *(const bf16x8*)(h3 + (((size_t)bl * 128 + gy) * 128 + gx) * 32 + cc * 8);
        *(bf16x8*)(in_t + pix * 40 + cc * 8) = v;
    }
    for (int c = tid; c < 9 * 16 * 4; c += 256) {
        int cc = c & 3, row = c >> 2;
        bf16x8 v = *(const bf16x8*)(wbu2 + (size_t)row * 32 + cc * 8);
        *(bf16x8*)(w_t + row * 40 + cc * 8) = v;
    }
    __syncthreads();

    f32x4 acc[2][2];
    f32x4 zf = {0.f, 0.f, 0.f, 0.f};
    acc[0][0] = zf; acc[0][1] = zf; acc[1][0] = zf; acc[1][1] = zf;
#pragma unroll
    for (int ky = 0; ky < 3; ++ky)
#pragma unroll
        for (int kx = 0; kx < 3; ++kx) {
            int tap = ky * 3 + kx;
            bf16x8 af = *(const bf16x8*)(w_t + (tap * 16 + l15) * 40 + ch * 8);
#pragma unroll
            for (int yl = 0; yl < 2; ++yl) {
                int yloc = 2 * wv + yl + ky;
#pragma unroll
                for (int xt = 0; xt < 2; ++xt) {
                    int xloc = xt * 16 + l15 + kx;
                    bf16x8 bfv = *(const bf16x8*)(in_t + (yloc * 34 + xloc) * 40 + ch * 8);
                    acc[yl][xt] = __builtin_amdgcn_mfma_f32_16x16x32_bf16(af, bfv, acc[yl][xt], 0, 0, 0);
                }
            }
        }
    float ss = 0.f;
    if (ch == 0) {
#pragma unroll
        for (int yl = 0; yl < 2; ++yl) {
            int gy = by * 8 + 2 * wv + yl;
#pragma unroll
            for (int xt = 0; xt < 2; ++xt) {
                int gx = bx * 32 + xt * 16 + l15;
#pragma unroll
                for (int r = 0; r < 3; ++r) {
                    float v = acc[yl][xt][r] + u2_b[r];
                    float d = v - noise[(((size_t)bg * 3 + r) * 128 + gy) * 128 + gx];
                    ss += d * d;
                }
            }
        }
    }
    rs[tid] = ss;
    __syncthreads();
    for (int s = 128; s > 0; s >>= 1) {
        if (tid < s) rs[tid] += rs[tid + s];
        __syncthreads();
    }
    if (tid == 0) partial[bg * 64 + by * 4 + bx] = rs[0];
}

// ---------------- final MSE reduction ----------------
__global__ void k_final(const float* __restrict__ partial, float* __restrict__ out) {
    __shared__ float rs[256];
    int tid = threadIdx.x;
    float s = 0.f;
    for (int i = tid; i < 4096; i += 256) s += partial[i];
    rs[tid] = s;
    __syncthreads();
    for (int st = 128; st > 0; st >>= 1) {
        if (tid < st) rs[tid] += rs[tid + st];
        __syncthreads();
    }
    if (tid == 0) out[0] = rs[0] / 3145728.0f;
}

extern "C" void kernel_launch(void* const* d_in, const int* in_sizes, int n_in,
                              void* d_out, int out_size, void* d_ws, size_t ws_size,
                              hipStream_t stream) {
    const float* cond   = (const float*)d_in[0];
    const float* tgt    = (const float*)d_in[1];
    const float* noise  = (const float*)d_in[2];
    const int*   t      = (const int*)d_in[3];
    const float* enc_w  = (const float*)d_in[4];
    const float* enc_b  = (const float*)d_in[5];
    const float* in_w   = (const float*)d_in[6];
    const float* in_b   = (const float*)d_in[7];
    const float* out_w  = (const float*)d_in[8];
    const float* out_b  = (const float*)d_in[9];
    const float* ff1_w  = (const float*)d_in[10];
    const float* ff1_b  = (const float*)d_in[11];
    const float* ff2_w  = (const float*)d_in[12];
    const float* ff2_b  = (const float*)d_in[13];
    const float* ln1_g  = (const float*)d_in[14];
    const float* ln1_b  = (const float*)d_in[15];
    const float* ln2_g  = (const float*)d_in[16];
    const float* ln2_b  = (const float*)d_in[17];
    const float* d1_w   = (const float*)d_in[18];
    const float* d1_b   = (const float*)d_in[19];
    const float* d2_w   = (const float*)d_in[20];
    const float* d2_b   = (const float*)d_in[21];
    const float* mid_w  = (const float*)d_in[22];
    const float* mid_b  = (const float*)d_in[23];
    const float* u1_w   = (const float*)d_in[24];
    const float* u1_b   = (const float*)d_in[25];
    const float* u2_w   = (const float*)d_in[26];
    const float* u2_b   = (const float*)d_in[27];

    float* ws = (float*)d_ws;
    // control region: 131072 floats
    float* sab     = ws;                    // 64
    float* snab    = ws + 64;               // 64
    float* x0      = ws + 128;              // 8192
    float* mid     = ws + 16512;            // 4096
    float* msepart = ws + 86144;            // 4096
    unsigned short* wb2  = (unsigned short*)(ws + 90240);   // 18432 bf16
    unsigned short* wbu1 = (unsigned short*)(ws + 99456);   // 18432 bf16
    unsigned short* wbu2 = (unsigned short*)(ws + 108672);  // 4608 bf16

    const size_t SMALL = 131072;
    const size_t ENCP = (size_t)KSEG * 8192;   // 524288
    float* encpart = ws + SMALL;
    float* tfy     = ws + SMALL + ENCP;                 // 8192
    float* tff1    = tfy + 8192;                        // 131072
    float* tfpart  = tff1 + 131072;                     // 65536

    size_t fixed = SMALL + ENCP + 8192 + 131072 + 65536;
    size_t avail = (ws_size / 4 > fixed) ? (ws_size / 4 - fixed) : 0;
    int NB = 1;
    const int cands[7] = {64, 32, 16, 8, 4, 2, 1};
    for (int ci = 0; ci < 7; ++ci) {
        if ((size_t)cands[ci] * 1048576ull <= avail) { NB = cands[ci]; break; }
    }
    unsigned short* hb1 = (unsigned short*)(ws + fixed);
    unsigned short* hb2 = (unsigned short*)(ws + fixed + (size_t)NB * 262144ull);
    unsigned short* hb3 = (unsigned short*)(ws + fixed + (size_t)NB * 786432ull);

    k_alpha<<<1, 64, 0, stream>>>(t, sab, snab);
    k_prep_cw<<<72, 256, 0, stream>>>(d2_w, wb2, 64, 32);
    k_prep_cw<<<72, 256, 0, stream>>>(u1_w, wbu1, 32, 64);
    k_prep_u2<<<18, 256, 0, stream>>>(u2_w, wbu2);
    k_enc_gemm<<<dim3(8, 4, KSEG), 256, 0, stream>>>(cond, enc_w, encpart);
    k_enc_reduce<<<32, 256, 0, stream>>>(encpart, enc_b, x0);
    for (int L = 0; L < 2; ++L) {
        k_tf_attn<<<64, 512, 0, stream>>>(x0, tfy, in_w, in_b, out_w, out_b, ln1_g, ln1_b, L);
        k_tf_ff1<<<dim3(16, 16), 256, 0, stream>>>(tfy, tff1, ff1_w, ff1_b, L);
        k_tf_ff2<<<dim3(8, 64), 128, 0, stream>>>(tff1, tfpart, ff2_w, L);
        k_tf_red<<<64, 128, 0, stream>>>(tfpart, tfy, x0, ff2_b, ln2_g, ln2_b, L);
    }
    k_mid<<<64, 64, 0, stream>>>(x0, mid_w, mid_b, mid);

    for (int cb = 0; cb < 64; cb += NB) {
        // conv1: 3->32 direct f32, q_sample fused, out bf16 NHWC
        k_conv1<<<dim3(4, 4, NB * 4), 256, 0, stream>>>(
            tgt, noise, sab, snab, d1_w, d1_b, hb1, cb);
        // conv2: 32->64 MFMA, all 64 co per block, relu + mid
        k_convMg<32, 4, 64, 2><<<dim3(4, 16, NB), 256, 0, stream>>>(
            hb1, wb2, d2_b, mid, hb2, cb);
        // u1: 64->32 MFMA, relu
        k_convMg<64, 2, 32, 1><<<dim3(4, 16, NB), 256, 0, stream>>>(
            hb2, wbu1, u1_b, nullptr, hb3, cb);
        // u2: 32->3 MFMA + fused MSE
        k_u2m<<<dim3(4, 16, NB), 256, 0, stream>>>(
            hb3, wbu2, u2_b, noise, msepart, cb);
    }

    k_final<<<1, 256, 0, stream>>>(msepart, (float*)d_out);
}

// Round 10
// 399.211 us; speedup vs baseline: 9.3853x; 1.0721x over previous
//
#include <hip/hip_runtime.h>
#include <math.h>

#define ENC_K 49152
#define KSEG 64
#define KLEN (ENC_K / KSEG)   // 768

typedef __attribute__((ext_vector_type(8))) short bf16x8;
typedef __attribute__((ext_vector_type(4))) float f32x4;

__device__ inline unsigned short f2bf(float f) {
    unsigned int u = __builtin_bit_cast(unsigned int, f);
    unsigned int r = u + 0x7fffu + ((u >> 16) & 1u);
    return (unsigned short)(r >> 16);
}
__device__ inline float bf2f(unsigned short h) {
    return __builtin_bit_cast(float, ((unsigned int)h) << 16);
}
__device__ inline float dot4(const float4 a, const float4 b) {
    return a.x * b.x + a.y * b.y + a.z * b.z + a.w * b.w;
}

// ---------------- alpha_bar per batch ----------------
__global__ void k_alpha(const int* __restrict__ t, float* __restrict__ sab, float* __restrict__ snab) {
    int b = threadIdx.x;
    if (b < 64) {
        int tb = t[b];
        const float step = (0.02f - 1e-4f) / 999.0f;
        float ab = 1.0f;
        for (int i = 0; i <= tb; ++i) {
            float beta = 1e-4f + step * (float)i;
            ab *= (1.0f - beta);
        }
        sab[b] = sqrtf(ab);
        snab[b] = sqrtf(1.0f - ab);
    }
}

// ---------------- conv weight prep: f32 [CO][CI][3][3] -> bf16 [tap][CO][CI] ----------------
__global__ void k_prep_cw(const float* __restrict__ w, unsigned short* __restrict__ out, int CO, int CI) {
    int idx = blockIdx.x * 256 + threadIdx.x;
    int total = CO * CI * 9;
    if (idx < total) {
        int tap = idx / (CO * CI);
        int rem = idx % (CO * CI);
        int co = rem / CI, ci = rem % CI;
        out[idx] = f2bf(w[((size_t)co * CI + ci) * 9 + tap]);
    }
}

// u2 weights: f32 [3][32][3][3] -> bf16 [tap][16 co(pad)][32 ci], co>=3 zero
__global__ void k_prep_u2(const float* __restrict__ w, unsigned short* __restrict__ out) {
    int idx = blockIdx.x * 256 + threadIdx.x;
    if (idx < 9 * 16 * 32) {
        int tap = idx / 512;
        int rem = idx % 512;
        int co = rem / 32, ci = rem % 32;
        out[idx] = (co < 3) ? f2bf(w[((size_t)co * 32 + ci) * 9 + tap]) : (unsigned short)0;
    }
}

// generic f32 -> bf16 flat conversion
__global__ void k_prep_bf(const float* __restrict__ in, unsigned short* __restrict__ out, int n) {
    int i = blockIdx.x * 256 + threadIdx.x;
    if (i < n) out[i] = f2bf(in[i]);
}

// ---------------- encoder GEMM: 32x32 tile, 2x2 micro-tile per thread ----------------
__global__ void k_enc_gemm(const float* __restrict__ cond, const float* __restrict__ w,
                           float* __restrict__ partial) {
    __shared__ float As[32][68];
    __shared__ float Ws[32][68];
    int tid = threadIdx.x;
    int j = tid & 15, i = tid >> 4;
    int d0 = blockIdx.x * 32, b0 = blockIdx.y * 32;
    int k0 = blockIdx.z * KLEN;
    float a00 = 0.f, a01 = 0.f, a10 = 0.f, a11 = 0.f;
    for (int kk = 0; kk < KLEN; kk += 64) {
        for (int idx = tid; idx < 512; idx += 256) {
            int r = idx >> 4, c = (idx & 15) << 2;
            *(float4*)&As[r][c] = *(const float4*)&cond[(size_t)(b0 + r) * ENC_K + k0 + kk + c];
            *(float4*)&Ws[r][c] = *(const float4*)&w[(size_t)(d0 + r) * ENC_K + k0 + kk + c];
        }
        __syncthreads();
        const float4* aA = (const float4*)&As[i][0];
        const float4* aB = (const float4*)&As[i + 16][0];
        const float4* wA = (const float4*)&Ws[j][0];
        const float4* wB = (const float4*)&Ws[j + 16][0];
#pragma unroll
        for (int k = 0; k < 16; ++k) {
            float4 av0 = aA[k], av1 = aB[k], wv0 = wA[k], wv1 = wB[k];
            a00 += dot4(av0, wv0); a01 += dot4(av0, wv1);
            a10 += dot4(av1, wv0); a11 += dot4(av1, wv1);
        }
        __syncthreads();
    }
    size_t base = (size_t)blockIdx.z * 64;
    partial[(base + b0 + i) * 128 + d0 + j] = a00;
    partial[(base + b0 + i) * 128 + d0 + j + 16] = a01;
    partial[(base + b0 + i + 16) * 128 + d0 + j] = a10;
    partial[(base + b0 + i + 16) * 128 + d0 + j + 16] = a11;
}

__global__ void k_enc_reduce(const float* __restrict__ partial, const float* __restrict__ bias,
                             float* __restrict__ x0) {
    int idx = blockIdx.x * 256 + threadIdx.x;  // 8192 total
    float s = bias[idx & 127];
    for (int ks = 0; ks < KSEG; ++ks) s += partial[(size_t)ks * 8192 + idx];
    x0[idx] = s;
}

// ---------------- transformer ----------------
__device__ float sum128(float v, int tid, float* red) {
    if (tid < 128) red[tid] = v;
    __syncthreads();
    if (tid < 64) red[tid] += red[tid + 64]; __syncthreads();
    if (tid < 32) red[tid] += red[tid + 32]; __syncthreads();
    if (tid < 16) red[tid] += red[tid + 16]; __syncthreads();
    if (tid < 8)  red[tid] += red[tid + 8];  __syncthreads();
    if (tid < 4)  red[tid] += red[tid + 4];  __syncthreads();
    if (tid < 2)  red[tid] += red[tid + 2];  __syncthreads();
    if (tid < 1)  red[tid] += red[tid + 1];  __syncthreads();
    float s = red[0];
    __syncthreads();
    return s;
}

// attn(v,out) + ln1: one block per batch row, 512 threads
__global__ __launch_bounds__(512) void k_tf_attn(
    const float* __restrict__ xs, float* __restrict__ yo,
    const float* __restrict__ in_w, const float* __restrict__ in_b,
    const float* __restrict__ out_w, const float* __restrict__ out_b,
    const float* __restrict__ ln1_g, const float* __restrict__ ln1_b, int L) {
    __shared__ float xr[128], vr[128], tp[4][128], red[128];
    int b = blockIdx.x, tid = threadIdx.x;
    if (tid < 128) xr[tid] = xs[b * 128 + tid];
    __syncthreads();
    int d = tid & 127, s = tid >> 7;   // s in 0..3
    {
        const float4* w = (const float4*)(in_w + ((size_t)L * 384 + 256 + d) * 128) + s * 8;
        const float4* x4 = (const float4*)xr + s * 8;
        float p = 0.f;
#pragma unroll
        for (int k = 0; k < 8; ++k) p += dot4(x4[k], w[k]);
        tp[s][d] = p;
    }
    __syncthreads();
    if (tid < 128) vr[tid] = in_b[L * 384 + 256 + tid] + tp[0][tid] + tp[1][tid] + tp[2][tid] + tp[3][tid];
    __syncthreads();
    {
        const float4* w = (const float4*)(out_w + ((size_t)L * 128 + d) * 128) + s * 8;
        const float4* v4 = (const float4*)vr + s * 8;
        float p = 0.f;
#pragma unroll
        for (int k = 0; k < 8; ++k) p += dot4(v4[k], w[k]);
        tp[s][d] = p;
    }
    __syncthreads();
    float y = 0.f;
    if (tid < 128) y = xr[tid] + out_b[L * 128 + tid] + tp[0][tid] + tp[1][tid] + tp[2][tid] + tp[3][tid];
    float m1 = sum128(y, tid, red) * (1.f / 128.f);
    float c1 = y - m1;
    float v1 = sum128(c1 * c1, tid, red) * (1.f / 128.f);
    if (tid < 128)
        yo[b * 128 + tid] = c1 * rsqrtf(v1 + 1e-5f) * ln1_g[L * 128 + tid] + ln1_b[L * 128 + tid];
}

// ff1 via MFMA bf16: f1[row][j] = relu(y[row] . w1[j] + b1[j]), f1 bf16 [64][2056]
__global__ __launch_bounds__(256, 2) void k_ff1m(
    const float* __restrict__ yo, const unsigned short* __restrict__ w1b,
    const float* __restrict__ ff1_b, unsigned short* __restrict__ f1, int L) {
    __shared__ __align__(16) unsigned short xs[64 * 136];
    int tid = threadIdx.x;
    int lane = tid & 63, wv = tid >> 6, l15 = lane & 15, ch = lane >> 4;
    int n0 = blockIdx.x * 64 + wv * 16;
    for (int e = tid; e < 8192; e += 256)
        xs[(e >> 7) * 136 + (e & 127)] = f2bf(yo[e]);
    __syncthreads();
    f32x4 acc[4];
    f32x4 zf = {0.f, 0.f, 0.f, 0.f};
#pragma unroll
    for (int rg = 0; rg < 4; ++rg) acc[rg] = zf;
    const unsigned short* wrow = w1b + ((size_t)L * 2048 + n0 + l15) * 128 + ch * 8;
#pragma unroll
    for (int ks = 0; ks < 4; ++ks) {
        bf16x8 af = *(const bf16x8*)(wrow + ks * 32);
#pragma unroll
        for (int rg = 0; rg < 4; ++rg) {
            bf16x8 bv = *(const bf16x8*)(xs + (rg * 16 + l15) * 136 + ks * 32 + ch * 8);
            acc[rg] = __builtin_amdgcn_mfma_f32_16x16x32_bf16(af, bv, acc[rg], 0, 0, 0);
        }
    }
#pragma unroll
    for (int rg = 0; rg < 4; ++rg) {
        ushort4 o;
#pragma unroll
        for (int r = 0; r < 4; ++r)
            ((unsigned short*)&o)[r] =
                f2bf(fmaxf(acc[rg][r] + ff1_b[L * 2048 + n0 + ch * 4 + r], 0.f));
        *(ushort4*)(f1 + (size_t)(rg * 16 + l15) * 2056 + n0 + ch * 4) = o;
    }
}

// ff2 via MFMA bf16, K split 4x512: part[(ks*64+row)*128+d]
__global__ __launch_bounds__(256, 2) void k_ff2m(
    const unsigned short* __restrict__ f1, const unsigned short* __restrict__ w2b,
    float* __restrict__ part, int L) {
    int tid = threadIdx.x;
    int lane = tid & 63, wv = tid >> 6, l15 = lane & 15, ch = lane >> 4;
    int ks = blockIdx.x;               // 0..3 -> K slice 512
    int dw = blockIdx.y * 64 + wv * 16;
    f32x4 acc[4];
    f32x4 zf = {0.f, 0.f, 0.f, 0.f};
#pragma unroll
    for (int rg = 0; rg < 4; ++rg) acc[rg] = zf;
    const unsigned short* wrow = w2b + ((size_t)L * 128 + dw + l15) * 2048 + ks * 512 + ch * 8;
    const unsigned short* frow = f1 + ks * 512 + ch * 8;
#pragma unroll
    for (int kst = 0; kst < 16; ++kst) {
        bf16x8 af = *(const bf16x8*)(wrow + kst * 32);
#pragma unroll
        for (int rg = 0; rg < 4; ++rg) {
            bf16x8 bv = *(const bf16x8*)(frow + (size_t)(rg * 16 + l15) * 2056 + kst * 32);
            acc[rg] = __builtin_amdgcn_mfma_f32_16x16x32_bf16(af, bv, acc[rg], 0, 0, 0);
        }
    }
#pragma unroll
    for (int rg = 0; rg < 4; ++rg)
        *(float4*)&part[((size_t)ks * 64 + rg * 16 + l15) * 128 + dw + ch * 4] = *(float4*)&acc[rg];
}

// reduce partials + residual + ln2 -> xs; grid 64, 128 thr
__global__ __launch_bounds__(128) void k_tf_red(
    const float* __restrict__ part, const float* __restrict__ yo,
    float* __restrict__ xs, const float* __restrict__ ff2_b,
    const float* __restrict__ ln2_g, const float* __restrict__ ln2_b, int L) {
    __shared__ float red[128];
    int b = blockIdx.x, tid = threadIdx.x;
    float y2 = yo[b * 128 + tid] + ff2_b[L * 128 + tid];
#pragma unroll
    for (int ks = 0; ks < 4; ++ks) y2 += part[((size_t)ks * 64 + b) * 128 + tid];
    float m2 = sum128(y2, tid, red) * (1.f / 128.f);
    float c2 = y2 - m2;
    float v2 = sum128(c2 * c2, tid, red) * (1.f / 128.f);
    xs[b * 128 + tid] = c2 * rsqrtf(v2 + 1e-5f) * ln2_g[L * 128 + tid] + ln2_b[L * 128 + tid];
}

// ---------------- mid projection ----------------
__global__ void k_mid(const float* __restrict__ xe, const float* __restrict__ mid_w,
                      const float* __restrict__ mid_b, float* __restrict__ mid) {
    int b = blockIdx.x, c = threadIdx.x;  // 64 threads
    float s = mid_b[c];
    const float* xr = xe + b * 128;
    const float* wr = mid_w + c * 128;
    for (int k = 0; k < 128; ++k) s += xr[k] * wr[k];
    mid[b * 64 + c] = s;
}

// ---------------- conv1: 3->32 direct f32, fused q_sample, relu, out bf16 NHWC ----------------
__global__ __launch_bounds__(256, 4) void k_conv1(
    const float* __restrict__ tgt, const float* __restrict__ noise,
    const float* __restrict__ sab, const float* __restrict__ snab,
    const float* __restrict__ wgt, const float* __restrict__ bias,
    unsigned short* __restrict__ h1, int b0) {
    __shared__ float it[3][34][35];
    __shared__ float wt[8][3][9];
    int tid = threadIdx.x;
    int tx = tid & 7, ty = tid >> 3;
    int bx = blockIdx.x, by = blockIdx.y;
    int bl = blockIdx.z >> 2, g = blockIdx.z & 3;
    int bg = b0 + bl, co0 = g * 8;
    float za = sab[bg], zb = snab[bg];
    for (int idx = tid; idx < 3 * 34 * 34; idx += 256) {
        int c = idx / 1156, rem = idx % 1156;
        int yy = rem / 34, xx = rem % 34;
        int gy = by * 32 + yy - 1, gx = bx * 32 + xx - 1;
        float v = 0.f;
        if (gy >= 0 && gy < 128 && gx >= 0 && gx < 128) {
            size_t off = (((size_t)bg * 3 + c) * 128 + gy) * 128 + gx;
            v = za * tgt[off] + zb * noise[off];
        }
        it[c][yy][xx] = v;
    }
    for (int idx = tid; idx < 8 * 27; idx += 256) {
        int co = idx / 27, rem = idx % 27;
        wt[co][rem / 9][rem % 9] = wgt[(size_t)(co0 + co) * 27 + rem];
    }
    __syncthreads();
    float acc[8][4];
#pragma unroll
    for (int co = 0; co < 8; ++co)
#pragma unroll
        for (int p = 0; p < 4; ++p) acc[co][p] = 0.f;
#pragma unroll
    for (int c = 0; c < 3; ++c)
#pragma unroll
        for (int ky = 0; ky < 3; ++ky) {
            float win[6];
#pragma unroll
            for (int i = 0; i < 6; ++i) win[i] = it[c][ty + ky][tx * 4 + i];
#pragma unroll
            for (int kx = 0; kx < 3; ++kx)
#pragma unroll
                for (int co = 0; co < 8; ++co) {
                    float w = wt[co][c][ky * 3 + kx];
#pragma unroll
                    for (int p = 0; p < 4; ++p) acc[co][p] += win[kx + p] * w;
                }
        }
    int gy = by * 32 + ty, gx0 = bx * 32 + tx * 4;
#pragma unroll
    for (int p = 0; p < 4; ++p) {
        ushort4 oa, ob;
#pragma unroll
        for (int co = 0; co < 4; ++co)
            ((unsigned short*)&oa)[co] = f2bf(fmaxf(acc[co][p] + bias[co0 + co], 0.f));
#pragma unroll
        for (int co = 0; co < 4; ++co)
            ((unsigned short*)&ob)[co] = f2bf(fmaxf(acc[co + 4][p] + bias[co0 + co + 4], 0.f));
        size_t o = (((size_t)bl * 128 + gy) * 128 + gx0 + p) * 32 + co0;
        *(ushort4*)(h1 + o) = oa;
        *(ushort4*)(h1 + o + 4) = ob;
    }
}

// ---------------- MFMA 3x3 conv: bf16 NHWC in/out, f32 accum ----------------
template <int CIN, int COB, int COUT, int MOUT>
__global__ __launch_bounds__(256, 2) void k_convMg(
    const unsigned short* __restrict__ in, const unsigned short* __restrict__ wb,
    const float* __restrict__ bias, const float* __restrict__ mid,
    unsigned short* __restrict__ out, int b0) {
    const int GROUPS = COUT / (16 * COB);
    __shared__ __align__(16) unsigned short in_t[10 * 34 * 40];
    __shared__ __align__(16) unsigned short w_t[9 * COB * 16 * 40];
    int tid = threadIdx.x;
    int bx = blockIdx.x, by = blockIdx.y;
    int bl = blockIdx.z / GROUPS, g = blockIdx.z % GROUPS;
    int bg = b0 + bl;
    int co0 = g * COB * 16;
    int lane = tid & 63, wv = tid >> 6;
    int l15 = lane & 15, ch = lane >> 4;

    f32x4 acc[2][2][COB];
    f32x4 zf = {0.f, 0.f, 0.f, 0.f};
#pragma unroll
    for (int a = 0; a < 2; ++a)
#pragma unroll
        for (int bq = 0; bq < 2; ++bq)
#pragma unroll
            for (int c = 0; c < COB; ++c) acc[a][bq][c] = zf;

    for (int cs = 0; cs < CIN / 32; ++cs) {
        if (cs) __syncthreads();
        for (int c = tid; c < 10 * 34 * 4; c += 256) {
            int cc = c & 3, pix = c >> 2;
            int xx = pix % 34, yy = pix / 34;
            int gy = by * 8 + yy - 1, gx = bx * 32 + xx - 1;
            bf16x8 v = {0, 0, 0, 0, 0, 0, 0, 0};
            if (gy >= 0 && gy < 128 && gx >= 0 && gx < 128)
                v = *(const bf16x8*)(in + (((size_t)bl * 128 + gy) * 128 + gx) * CIN + cs * 32 + cc * 8);
            *(bf16x8*)(in_t + pix * 40 + cc * 8) = v;
        }
        for (int c = tid; c < 9 * COB * 16 * 4; c += 256) {
            int cc = c & 3, row = c >> 2;
            int tap = row / (COB * 16), co = row % (COB * 16);
            bf16x8 v = *(const bf16x8*)(wb + ((size_t)(tap * COUT + co0 + co)) * CIN + cs * 32 + cc * 8);
            *(bf16x8*)(w_t + row * 40 + cc * 8) = v;
        }
        __syncthreads();
#pragma unroll
        for (int ky = 0; ky < 3; ++ky)
#pragma unroll
            for (int kx = 0; kx < 3; ++kx) {
                int tap = ky * 3 + kx;
                bf16x8 af[COB];
#pragma unroll
                for (int cb = 0; cb < COB; ++cb)
                    af[cb] = *(const bf16x8*)(w_t + (tap * COB * 16 + cb * 16 + l15) * 40 + ch * 8);
#pragma unroll
                for (int yl = 0; yl < 2; ++yl) {
                    int yloc = 2 * wv + yl + ky;
#pragma unroll
                    for (int xt = 0; xt < 2; ++xt) {
                        int xloc = xt * 16 + l15 + kx;
                        bf16x8 bfv = *(const bf16x8*)(in_t + (yloc * 34 + xloc) * 40 + ch * 8);
#pragma unroll
                        for (int cb = 0; cb < COB; ++cb)
                            acc[yl][xt][cb] = __builtin_amdgcn_mfma_f32_16x16x32_bf16(
                                af[cb], bfv, acc[yl][xt][cb], 0, 0, 0);
                    }
                }
            }
    }
#pragma unroll
    for (int yl = 0; yl < 2; ++yl) {
        int gy = by * 8 + 2 * wv + yl;
#pragma unroll
        for (int xt = 0; xt < 2; ++xt) {
            int gx = bx * 32 + xt * 16 + l15;
            size_t pixo = (((size_t)bl * 128 + gy) * 128 + gx) * COUT;
#pragma unroll
            for (int cb = 0; cb < COB; ++cb) {
                int co = co0 + cb * 16 + ch * 4;
                ushort4 o;
#pragma unroll
                for (int r = 0; r < 4; ++r) {
                    float v = acc[yl][xt][cb][r] + bias[co + r];
                    v = fmaxf(v, 0.f);
                    if (MOUT == 2) v += mid[bg * 64 + co + r];
                    ((unsigned short*)&o)[r] = f2bf(v);
                }
                *(ushort4*)(out + pixo + co) = o;
            }
        }
    }
}

// ---------------- u2 via MFMA (co 0..2 of 16-pad) + fused MSE ----------------
__global__ __launch_bounds__(256, 3) void k_u2m(
    const unsigned short* __restrict__ h3, const unsigned short* __restrict__ wbu2,
    const float* __restrict__ u2_b, const float* __restrict__ noise,
    float* __restrict__ partial, int b0) {
    __shared__ __align__(16) unsigned short in_t[340 * 40];
    __shared__ __align__(16) unsigned short w_t[9 * 16 * 40];
    __shared__ float rs[256];
    int tid = threadIdx.x;
    int bx = blockIdx.x, by = blockIdx.y, bl = blockIdx.z;
    int bg = b0 + bl;
    int lane = tid & 63, wv = tid >> 6, l15 = lane & 15, ch = lane >> 4;

    for (int c = tid; c < 340 * 4; c += 256) {
        int cc = c & 3, pix = c >> 2;
        int xx = pix % 34, yy = pix / 34;
        int gy = by * 8 + yy - 1, gx = bx * 32 + xx - 1;
        bf16x8 v = {0, 0, 0, 0, 0, 0, 0, 0};
        if (gy >= 0 && gy < 128 && gx >= 0 && gx < 128)
            v = *(const bf16x8*)(h3 + (((size_t)bl * 128 + gy) * 128 + gx) * 32 + cc * 8);
        *(bf16x8*)(in_t + pix * 40 + cc * 8) = v;
    }
    for (int c = tid; c < 9 * 16 * 4; c += 256) {
        int cc = c & 3, row = c >> 2;
        bf16x8 v = *(const bf16x8*)(wbu2 + (size_t)row * 32 + cc * 8);
        *(bf16x8*)(w_t + row * 40 + cc * 8) = v;
    }
    __syncthreads();

    f32x4 acc[2][2];
    f32x4 zf = {0.f, 0.f, 0.f, 0.f};
    acc[0][0] = zf; acc[0][1] = zf; acc[1][0] = zf; acc[1][1] = zf;
#pragma unroll
    for (int ky = 0; ky < 3; ++ky)
#pragma unroll
        for (int kx = 0; kx < 3; ++kx) {
            int tap = ky * 3 + kx;
            bf16x8 af = *(const bf16x8*)(w_t + (tap * 16 + l15) * 40 + ch * 8);
#pragma unroll
            for (int yl = 0; yl < 2; ++yl) {
                int yloc = 2 * wv + yl + ky;
#pragma unroll
                for (int xt = 0; xt < 2; ++xt) {
                    int xloc = xt * 16 + l15 + kx;
                    bf16x8 bfv = *(const bf16x8*)(in_t + (yloc * 34 + xloc) * 40 + ch * 8);
                    acc[yl][xt] = __builtin_amdgcn_mfma_f32_16x16x32_bf16(af, bfv, acc[yl][xt], 0, 0, 0);
                }
            }
        }
    float ss = 0.f;
    if (ch == 0) {
#pragma unroll
        for (int yl = 0; yl < 2; ++yl) {
            int gy = by * 8 + 2 * wv + yl;
#pragma unroll
            for (int xt = 0; xt < 2; ++xt) {
                int gx = bx * 32 + xt * 16 + l15;
#pragma unroll
                for (int r = 0; r < 3; ++r) {
                    float v = acc[yl][xt][r] + u2_b[r];
                    float d = v - noise[(((size_t)bg * 3 + r) * 128 + gy) * 128 + gx];
                    ss += d * d;
                }
            }
        }
    }
    rs[tid] = ss;
    __syncthreads();
    for (int s = 128; s > 0; s >>= 1) {
        if (tid < s) rs[tid] += rs[tid + s];
        __syncthreads();
    }
    if (tid == 0) partial[bg * 64 + by * 4 + bx] = rs[0];
}

// ---------------- final MSE reduction ----------------
__global__ void k_final(const float* __restrict__ partial, float* __restrict__ out) {
    __shared__ float rs[256];
    int tid = threadIdx.x;
    float s = 0.f;
    for (int i = tid; i < 4096; i += 256) s += partial[i];
    rs[tid] = s;
    __syncthreads();
    for (int st = 128; st > 0; st >>= 1) {
        if (tid < st) rs[tid] += rs[tid + st];
        __syncthreads();
    }
    if (tid == 0) out[0] = rs[0] / 3145728.0f;
}

extern "C" void kernel_launch(void* const* d_in, const int* in_sizes, int n_in,
                              void* d_out, int out_size, void* d_ws, size_t ws_size,
                              hipStream_t stream) {
    const float* cond   = (const float*)d_in[0];
    const float* tgt    = (const float*)d_in[1];
    const float* noise  = (const float*)d_in[2];
    const int*   t      = (const int*)d_in[3];
    const float* enc_w  = (const float*)d_in[4];
    const float* enc_b  = (const float*)d_in[5];
    const float* in_w   = (const float*)d_in[6];
    const float* in_b   = (const float*)d_in[7];
    const float* out_w  = (const float*)d_in[8];
    const float* out_b  = (const float*)d_in[9];
    const float* ff1_w  = (const float*)d_in[10];
    const float* ff1_b  = (const float*)d_in[11];
    const float* ff2_w  = (const float*)d_in[12];
    const float* ff2_b  = (const float*)d_in[13];
    const float* ln1_g  = (const float*)d_in[14];
    const float* ln1_b  = (const float*)d_in[15];
    const float* ln2_g  = (const float*)d_in[16];
    const float* ln2_b  = (const float*)d_in[17];
    const float* d1_w   = (const float*)d_in[18];
    const float* d1_b   = (const float*)d_in[19];
    const float* d2_w   = (const float*)d_in[20];
    const float* d2_b   = (const float*)d_in[21];
    const float* mid_w  = (const float*)d_in[22];
    const float* mid_b  = (const float*)d_in[23];
    const float* u1_w   = (const float*)d_in[24];
    const float* u1_b   = (const float*)d_in[25];
    const float* u2_w   = (const float*)d_in[26];
    const float* u2_b   = (const float*)d_in[27];

    float* ws = (float*)d_ws;
    // control region: 131072 floats
    float* sab     = ws;                    // 64
    float* snab    = ws + 64;               // 64
    float* x0      = ws + 128;              // 8192
    float* mid     = ws + 16512;            // 4096
    float* msepart = ws + 86144;            // 4096
    unsigned short* wb2  = (unsigned short*)(ws + 90240);   // 18432 bf16
    unsigned short* wbu1 = (unsigned short*)(ws + 99456);   // 18432 bf16
    unsigned short* wbu2 = (unsigned short*)(ws + 108672);  // 4608 bf16

    const size_t SMALL = 131072;
    const size_t ENCP = (size_t)KSEG * 8192;                // 524288
    float* encpart = ws + SMALL;
    float* tfy     = encpart + ENCP;                        // 8192
    unsigned short* tff1 = (unsigned short*)(tfy + 8192);   // 64*2056 bf16 = 65792 f32
    float* tfpart  = tfy + 8192 + 65792;                    // 4*64*128 = 32768
    unsigned short* wbf1 = (unsigned short*)(tfpart + 32768);          // 524288 bf16 = 262144 f32
    unsigned short* wbf2 = (unsigned short*)(tfpart + 32768 + 262144); // 524288 bf16

    size_t fixed = SMALL + ENCP + 8192 + 65792 + 32768 + 262144 + 262144;
    size_t avail = (ws_size / 4 > fixed) ? (ws_size / 4 - fixed) : 0;
    int NB = 1;
    const int cands[7] = {64, 32, 16, 8, 4, 2, 1};
    for (int ci = 0; ci < 7; ++ci) {
        if ((size_t)cands[ci] * 1048576ull <= avail) { NB = cands[ci]; break; }
    }
    unsigned short* hb1 = (unsigned short*)(ws + fixed);
    unsigned short* hb2 = (unsigned short*)(ws + fixed + (size_t)NB * 262144ull);
    unsigned short* hb3 = (unsigned short*)(ws + fixed + (size_t)NB * 786432ull);

    k_alpha<<<1, 64, 0, stream>>>(t, sab, snab);
    k_prep_cw<<<72, 256, 0, stream>>>(d2_w, wb2, 64, 32);
    k_prep_cw<<<72, 256, 0, stream>>>(u1_w, wbu1, 32, 64);
    k_prep_u2<<<18, 256, 0, stream>>>(u2_w, wbu2);
    k_prep_bf<<<2048, 256, 0, stream>>>(ff1_w, wbf1, 524288);
    k_prep_bf<<<2048, 256, 0, stream>>>(ff2_w, wbf2, 524288);
    k_enc_gemm<<<dim3(4, 2, KSEG), 256, 0, stream>>>(cond, enc_w, encpart);
    k_enc_reduce<<<32, 256, 0, stream>>>(encpart, enc_b, x0);
    for (int L = 0; L < 2; ++L) {
        k_tf_attn<<<64, 512, 0, stream>>>(x0, tfy, in_w, in_b, out_w, out_b, ln1_g, ln1_b, L);
        k_ff1m<<<32, 256, 0, stream>>>(tfy, wbf1, ff1_b, tff1, L);
        k_ff2m<<<dim3(4, 2), 256, 0, stream>>>(tff1, wbf2, tfpart, L);
        k_tf_red<<<64, 128, 0, stream>>>(tfpart, tfy, x0, ff2_b, ln2_g, ln2_b, L);
    }
    k_mid<<<64, 64, 0, stream>>>(x0, mid_w, mid_b, mid);

    for (int cb = 0; cb < 64; cb += NB) {
        k_conv1<<<dim3(4, 4, NB * 4), 256, 0, stream>>>(
            tgt, noise, sab, snab, d1_w, d1_b, hb1, cb);
        k_convMg<32, 4, 64, 2><<<dim3(4, 16, NB), 256, 0, stream>>>(
            hb1, wb2, d2_b, mid, hb2, cb);
        k_convMg<64, 2, 32, 1><<<dim3(4, 16, NB), 256, 0, stream>>>(
            hb2, wbu1, u1_b, nullptr, hb3, cb);
        k_u2m<<<dim3(4, 16, NB), 256, 0, stream>>>(
            hb3, wbu2, u2_b, noise, msepart, cb);
    }

    k_final<<<1, 256, 0, stream>>>(msepart, (float*)d_out);
}